// Round 18
// baseline (252.941 us; speedup 1.0000x reference)
//
#include <hip/hip_runtime.h>
#include <hip/hip_bf16.h>

typedef __bf16 bf16_t;
typedef __bf16 bf16x8 __attribute__((ext_vector_type(8)));
typedef float f32x4 __attribute__((ext_vector_type(4)));

constexpr int Bz = 8, Lseq = 1024, Dm = 512, Hh = 8, DKd = 64;
constexpr int MTOK = Bz * Lseq;   // 8192 tokens
constexpr int NREL = 201;
constexpr int PROW = 202;         // padded LDS row (bank stride 101%32=5, coprime)

// pos pre-scale: 0.125 (1/sqrt(dk)) * log2(e), folded so p = exp2(st*C + pos)
#define POS_C 0.18033688011112042f

__device__ inline float fexp2(float x) {
#if __has_builtin(__builtin_amdgcn_exp2f)
  return __builtin_amdgcn_exp2f(x);
#else
  return exp2f(x);
#endif
}
__device__ inline float b2f(unsigned short u) {
  return __builtin_bit_cast(float, (unsigned)u << 16);
}
__device__ inline unsigned pack2(float a, float b) {
  unsigned short ua = __builtin_bit_cast(unsigned short, (bf16_t)a);
  unsigned short ub = __builtin_bit_cast(unsigned short, (bf16_t)b);
  return (unsigned)ua | ((unsigned)ub << 16);
}

// ---------------- one-launch cast of Wq,Wk,Wv,Wfc + rel ----------------------
__global__ __launch_bounds__(256) void k_castw(
    const float* __restrict__ s0, const float* __restrict__ s1,
    const float* __restrict__ s2, const float* __restrict__ s3,
    const float* __restrict__ s4, bf16_t* __restrict__ d0,
    bf16_t* __restrict__ d1, bf16_t* __restrict__ d2, bf16_t* __restrict__ d3,
    bf16_t* __restrict__ d4) {
  const int y = blockIdx.y;
  const float* s = y == 0 ? s0 : y == 1 ? s1 : y == 2 ? s2 : y == 3 ? s3 : s4;
  bf16_t* d = y == 0 ? d0 : y == 1 ? d1 : y == 2 ? d2 : y == 3 ? d3 : d4;
  const int n = y < 4 ? Dm * Dm : NREL * DKd;
  int i = (blockIdx.x * 256 + threadIdx.x) * 4;
  if (i + 3 < n) {
    float4 v = *reinterpret_cast<const float4*>(s + i);
    d[i + 0] = (bf16_t)v.x;
    d[i + 1] = (bf16_t)v.y;
    d[i + 2] = (bf16_t)v.z;
    d[i + 3] = (bf16_t)v.w;
  } else if (i < n) {
    for (; i < n; ++i) d[i] = (bf16_t)s[i];
  }
}

// ---------------- one-launch cast of q,k,v: 8 elems/thread, 16B stores --------
__global__ __launch_bounds__(256) void k_castx(
    const float* __restrict__ s0, const float* __restrict__ s1,
    const float* __restrict__ s2, bf16_t* __restrict__ d0,
    bf16_t* __restrict__ d1, bf16_t* __restrict__ d2) {
  const int y = blockIdx.y;
  const float* s = y == 0 ? s0 : y == 1 ? s1 : s2;
  bf16_t* d = y == 0 ? d0 : y == 1 ? d1 : d2;
  const int i = (blockIdx.x * 256 + threadIdx.x) * 8;
  float4 a = *reinterpret_cast<const float4*>(s + i);
  float4 b = *reinterpret_cast<const float4*>(s + i + 4);
  bf16x8 r;
  r[0] = (bf16_t)a.x; r[1] = (bf16_t)a.y; r[2] = (bf16_t)a.z; r[3] = (bf16_t)a.w;
  r[4] = (bf16_t)b.x; r[5] = (bf16_t)b.y; r[6] = (bf16_t)b.z; r[7] = (bf16_t)b.w;
  *reinterpret_cast<bf16x8*>(d + i) = r;
}

// ---------------- y = A @ W^T  (A:[8192][512] bf16, W:[512][512] bf16) --------
// MODE 0: bf16 head-major; MODE 1: bf16 head-transposed.
template <int MODE>
__global__ __launch_bounds__(256) void k_gemm512(const bf16_t* __restrict__ A,
                                                 const bf16_t* __restrict__ W,
                                                 bf16_t* __restrict__ outb) {
  const int lane = threadIdx.x & 63, w = threadIdx.x >> 6;
  const int lr = lane & 15, lg = lane >> 4;
  // bijective chunked XCD swizzle (nwg=1024, chunk=128)
  const int orig = blockIdx.x + blockIdx.y * 8;
  const int swz = ((orig & 7) << 7) | (orig >> 3);
  const int Rbase = (swz >> 3) * 64 + (w >> 1) * 32;
  const int Cbase = (swz & 7) * 64 + (w & 1) * 32;

  f32x4 acc[2][2] = {};
  for (int k0 = 0; k0 < Dm; k0 += 32) {
    bf16x8 af[2], wf[2];
#pragma unroll
    for (int i = 0; i < 2; ++i)
      af[i] = *reinterpret_cast<const bf16x8*>(A + (size_t)(Rbase + i * 16 + lr) * Dm + k0 + lg * 8);
#pragma unroll
    for (int j = 0; j < 2; ++j)
      wf[j] = *reinterpret_cast<const bf16x8*>(W + (size_t)(Cbase + j * 16 + lr) * Dm + k0 + lg * 8);
#pragma unroll
    for (int i = 0; i < 2; ++i)
#pragma unroll
      for (int j = 0; j < 2; ++j)
        acc[i][j] = __builtin_amdgcn_mfma_f32_16x16x32_bf16(af[i], wf[j], acc[i][j], 0, 0, 0);
  }
#pragma unroll
  for (int i = 0; i < 2; ++i)
#pragma unroll
    for (int j = 0; j < 2; ++j)
#pragma unroll
      for (int r = 0; r < 4; ++r) {
        const int gr = Rbase + i * 16 + lg * 4 + r;  // token row
        const int gc = Cbase + j * 16 + lr;          // output col
        const int bb = gr >> 10, qq = gr & 1023, hh = gc >> 6, dd = gc & 63;
        const bf16_t vv = (bf16_t)acc[i][j][r];
        if (MODE == 0)
          outb[(((size_t)(bb * Hh + hh)) * Lseq + qq) * DKd + dd] = vv;
        else
          outb[(((size_t)(bb * Hh + hh)) * DKd + dd) * Lseq + qq] = vv;
      }
}

// ---------------- fc GEMM: yf = attnb @ Wfc^T + resid (fp32) ------------------
__global__ __launch_bounds__(256) void k_fc(const bf16_t* __restrict__ A,
                                            const bf16_t* __restrict__ W,
                                            float* __restrict__ outf,
                                            const float* __restrict__ resid) {
  const int lane = threadIdx.x & 63, w = threadIdx.x >> 6;
  const int lr = lane & 15, lg = lane >> 4;
  // bijective chunked XCD swizzle (nwg=1024, chunk=128)
  const int orig = blockIdx.x + blockIdx.y * 8;
  const int swz = ((orig & 7) << 7) | (orig >> 3);
  const int Rbase = (swz >> 3) * 64 + (w >> 1) * 32;
  const int Cbase = (swz & 7) * 64 + (w & 1) * 32;

  f32x4 acc[2][2] = {};
  for (int k0 = 0; k0 < Dm; k0 += 32) {
    bf16x8 af[2], wf[2];
#pragma unroll
    for (int i = 0; i < 2; ++i)
      af[i] = *reinterpret_cast<const bf16x8*>(A + (size_t)(Rbase + i * 16 + lr) * Dm + k0 + lg * 8);
#pragma unroll
    for (int j = 0; j < 2; ++j)
      wf[j] = *reinterpret_cast<const bf16x8*>(W + (size_t)(Cbase + j * 16 + lr) * Dm + k0 + lg * 8);
#pragma unroll
    for (int i = 0; i < 2; ++i)
#pragma unroll
      for (int j = 0; j < 2; ++j)
        acc[i][j] = __builtin_amdgcn_mfma_f32_16x16x32_bf16(af[i], wf[j], acc[i][j], 0, 0, 0);
  }
#pragma unroll
  for (int i = 0; i < 2; ++i)
#pragma unroll
    for (int j = 0; j < 2; ++j)
#pragma unroll
      for (int r = 0; r < 4; ++r) {
        const int gr = Rbase + i * 16 + lg * 4 + r;
        const int gc = Cbase + j * 16 + lr;
        const size_t idx = (size_t)gr * Dm + gc;
        outf[idx] = acc[i][j][r] + resid[idx];
      }
}

// ---------------- flash attention + fused posdot, LDS-slimmed -----------------
// LDS 26112 -> 18048B (pos 12928 + Pl 5120, Ml 17408 overlapped): 8 blocks/CU
// resident (entire 2048-block grid). Pl single-buffered over t (t-serialized
// QK->softmax->Pl->PV); two-stage k-quarter merge (waves 1,3 -> 0,2 -> 0).
__global__ __launch_bounds__(256, 4) void k_attn(const bf16_t* __restrict__ Qh,
                                                 const bf16_t* __restrict__ Kh,
                                                 const bf16_t* __restrict__ Vt,
                                                 const bf16_t* __restrict__ relb,
                                                 bf16_t* __restrict__ attnb) {
  __shared__ float smemf[4512];   // pos 12928B + Pl 5120B = 18048B; Ml 17408B

  const int tid = threadIdx.x;
  const int wv = tid >> 6, lane = tid & 63;
  const int lr = lane & 15, lg = lane >> 4;
  // bijective chunked XCD swizzle (nwg=2048, chunk=256)
  const int gid = ((blockIdx.x & 7) << 8) | (blockIdx.x >> 3);
  const int bh = gid >> 5;
  const int qb = (gid & 31) << 5;             // 32-row q tile

  unsigned short* pls = reinterpret_cast<unsigned short*>(smemf);      // [32][202]
  unsigned* Pw = reinterpret_cast<unsigned*>(smemf) + 3232 + wv * 320; // [16][20]

  const bf16_t* Qp = Qh + ((size_t)bh * Lseq + qb) * DKd;
  const bf16_t* Kp = Kh + (size_t)bh * Lseq * DKd;
  const bf16_t* Vp = Vt + (size_t)bh * DKd * Lseq;

  // Q fragments (dual-use: B-operand for swapped QK^T, A-operand for posdot)
  bf16x8 qf[2][2];
#pragma unroll
  for (int t = 0; t < 2; ++t)
#pragma unroll
    for (int h = 0; h < 2; ++h)
      qf[t][h] = *reinterpret_cast<const bf16x8*>(Qp + (size_t)(t * 16 + lr) * DKd + h * 32 + lg * 8);

  // ---- in-block posdot: pls[q][200-r] = POS_C * dot(Q[q], rel[r]) -----------
  for (int n = wv; n < 13; n += 4) {
    const int rr0 = n * 16 + lr;
    const int rclamp = rr0 > 200 ? 200 : rr0;
    bf16x8 rf0 = *reinterpret_cast<const bf16x8*>(relb + (size_t)rclamp * DKd + lg * 8);
    bf16x8 rf1 = *reinterpret_cast<const bf16x8*>(relb + (size_t)rclamp * DKd + 32 + lg * 8);
#pragma unroll
    for (int t = 0; t < 2; ++t) {
      f32x4 st = {};
      st = __builtin_amdgcn_mfma_f32_16x16x32_bf16(qf[t][0], rf0, st, 0, 0, 0);
      st = __builtin_amdgcn_mfma_f32_16x16x32_bf16(qf[t][1], rf1, st, 0, 0, 0);
      if (rr0 <= 200) {
#pragma unroll
        for (int r = 0; r < 4; ++r)
          pls[(t * 16 + lg * 4 + r) * PROW + (200 - rr0)] =
              __builtin_bit_cast(unsigned short, (bf16_t)(st[r] * POS_C));
      }
    }
  }
  __syncthreads();

  // per-lane pos row bases + band-edge constants (already scaled by POS_C)
  const unsigned short* prow[2] = {pls + (size_t)lr * PROW,
                                   pls + (size_t)(16 + lr) * PROW};
  float pe0[2], pe200[2];
#pragma unroll
  for (int t = 0; t < 2; ++t) {
    pe0[t] = b2f(prow[t][0]);       // k <= q-100 side
    pe200[t] = b2f(prow[t][200]);   // k >= q+100 side
  }

  f32x4 Oacc[2][4] = {};
  float psum[2] = {0.f, 0.f};
  const int ldelta = lg * 4 - lr;

  const int kbase = wv * 256;
#pragma unroll 2
  for (int k0 = kbase; k0 < kbase + 256; k0 += 32) {
    // K fragments (A-operand) + V fragments (hoisted; independent of QK chain)
    bf16x8 kf[2][2];
#pragma unroll
    for (int u = 0; u < 2; ++u)
#pragma unroll
      for (int h = 0; h < 2; ++h)
        kf[u][h] = *reinterpret_cast<const bf16x8*>(Kp + (size_t)(k0 + u * 16 + lr) * DKd + h * 32 + lg * 8);
    bf16x8 vf[4];
#pragma unroll
    for (int f = 0; f < 4; ++f)
      vf[f] = *reinterpret_cast<const bf16x8*>(Vp + (size_t)(f * 16 + lr) * Lseq + k0 + lg * 8);

#pragma unroll
    for (int t = 0; t < 2; ++t) {
      const int Qt = qb + t * 16;
      f32x4 st[2];
#pragma unroll
      for (int u = 0; u < 2; ++u) {
        f32x4 a = {};
        a = __builtin_amdgcn_mfma_f32_16x16x32_bf16(kf[u][0], qf[t][0], a, 0, 0, 0);
        a = __builtin_amdgcn_mfma_f32_16x16x32_bf16(kf[u][1], qf[t][1], a, 0, 0, 0);
        st[u] = a;  // element: q = Qt+lr (col), k = k0+u*16+lg*4+r (row)
      }
      float p[2][4];
      if (k0 + 131 <= Qt) {            // whole step below band: pos = pls[q][0]
#pragma unroll
        for (int u = 0; u < 2; ++u)
#pragma unroll
          for (int r = 0; r < 4; ++r)
            p[u][r] = fexp2(fmaf(st[u][r], POS_C, pe0[t]));
      } else if (k0 >= Qt + 115) {     // whole step above band: pos = pls[q][200]
#pragma unroll
        for (int u = 0; u < 2; ++u)
#pragma unroll
          for (int r = 0; r < 4; ++r)
            p[u][r] = fexp2(fmaf(st[u][r], POS_C, pe200[t]));
      } else {                         // in-band: clamped gather from LDS
#pragma unroll
        for (int u = 0; u < 2; ++u) {
          const int jb = k0 + u * 16 + 100 - Qt + ldelta;
#pragma unroll
          for (int r = 0; r < 4; ++r) {
            int j = jb + r;
            j = j < 0 ? 0 : (j > 200 ? 200 : j);
            p[u][r] = fexp2(fmaf(st[u][r], POS_C, b2f(prow[t][j])));
          }
        }
      }
#pragma unroll
      for (int u = 0; u < 2; ++u)
#pragma unroll
        for (int r = 0; r < 4; ++r) psum[t] += p[u][r];
      // pack to bf16, wave-private single-buffer LDS transpose
#pragma unroll
      for (int u = 0; u < 2; ++u) {
        uint2 pk;
        pk.x = pack2(p[u][0], p[u][1]);
        pk.y = pack2(p[u][2], p[u][3]);
        *reinterpret_cast<uint2*>(&Pw[lr * 20 + u * 8 + lg * 2]) = pk;
      }
      // PV for this t (in-wave LDS write->read ordering via lgkmcnt)
      bf16x8 pb = *reinterpret_cast<const bf16x8*>(&Pw[lr * 20 + lg * 4]);
#pragma unroll
      for (int f = 0; f < 4; ++f)
        Oacc[t][f] = __builtin_amdgcn_mfma_f32_16x16x32_bf16(vf[f], pb, Oacc[t][f], 0, 0, 0);
    }
  }

  // ---- two-stage merge of the four k-quarters (pure addition) ----------------
  __syncthreads();   // pos+Pl dead -> reuse smem as Ml[2][64][34]
  float* Ml = smemf;
  if (wv & 1) {       // waves 1,3 dump to slot (wv>>1)
    float* m = Ml + (((wv >> 1) * 64) + lane) * 34;
#pragma unroll
    for (int t = 0; t < 2; ++t)
#pragma unroll
      for (int f = 0; f < 4; ++f)
#pragma unroll
        for (int r = 0; r < 4; ++r) m[t * 16 + f * 4 + r] = Oacc[t][f][r];
    m[32] = psum[0];
    m[33] = psum[1];
  }
  __syncthreads();
  if (!(wv & 1)) {    // waves 0,2 accumulate partner
    const float* m = Ml + (((wv >> 1) * 64) + lane) * 34;
#pragma unroll
    for (int t = 0; t < 2; ++t) {
#pragma unroll
      for (int f = 0; f < 4; ++f)
#pragma unroll
        for (int r = 0; r < 4; ++r) Oacc[t][f][r] += m[t * 16 + f * 4 + r];
      psum[t] += m[32 + t];
    }
  }
  __syncthreads();
  if (wv == 2) {      // wave 2 dumps its merged half
    float* m = Ml + lane * 34;
#pragma unroll
    for (int t = 0; t < 2; ++t)
#pragma unroll
      for (int f = 0; f < 4; ++f)
#pragma unroll
        for (int r = 0; r < 4; ++r) m[t * 16 + f * 4 + r] = Oacc[t][f][r];
    m[32] = psum[0];
    m[33] = psum[1];
  }
  __syncthreads();
  if (wv == 0) {
    const float* m = Ml + lane * 34;
#pragma unroll
    for (int t = 0; t < 2; ++t) {
#pragma unroll
      for (int f = 0; f < 4; ++f)
#pragma unroll
        for (int r = 0; r < 4; ++r) Oacc[t][f][r] += m[t * 16 + f * 4 + r];
      psum[t] += m[32 + t];
    }
    const int gb = bh >> 3, hh = bh & 7;
#pragma unroll
    for (int t = 0; t < 2; ++t) {
      float s = psum[t];
      s += __shfl_xor(s, 16);
      s += __shfl_xor(s, 32);
      const float inv = 1.0f / s;
      const int qg = qb + t * 16 + lr;
#pragma unroll
      for (int f = 0; f < 4; ++f) {
        uint2 ov;
        ov.x = pack2(Oacc[t][f][0] * inv, Oacc[t][f][1] * inv);
        ov.y = pack2(Oacc[t][f][2] * inv, Oacc[t][f][3] * inv);
        *reinterpret_cast<uint2*>(attnb + ((size_t)(gb * Lseq + qg)) * Dm + hh * DKd + f * 16 + lg * 4) = ov;
      }
    }
  }
}

// ---------------- row LayerNorm over D=512 (near BW-roofline: ~4.9 TB/s) ------
__global__ __launch_bounds__(256) void k_ln(const float* __restrict__ y,
                                            const float* __restrict__ g,
                                            const float* __restrict__ be,
                                            float* __restrict__ out) {
  const int row = blockIdx.x * 4 + (threadIdx.x >> 6);
  const int lane = threadIdx.x & 63;
  const float* yp = y + (size_t)row * Dm + lane * 8;
  float4 v0 = *reinterpret_cast<const float4*>(yp);
  float4 v1 = *reinterpret_cast<const float4*>(yp + 4);
  float vv[8] = {v0.x, v0.y, v0.z, v0.w, v1.x, v1.y, v1.z, v1.w};
  float s = 0.f, s2 = 0.f;
#pragma unroll
  for (int j = 0; j < 8; ++j) { s += vv[j]; s2 += vv[j] * vv[j]; }
  for (int mk = 1; mk < 64; mk <<= 1) {
    s += __shfl_xor(s, mk, 64);
    s2 += __shfl_xor(s2, mk, 64);
  }
  const float mu = s * (1.0f / Dm);
  const float var = s2 * (1.0f / Dm) - mu * mu;
  const float inv = rsqrtf(var + 1e-6f);
  float* op = out + (size_t)row * Dm + lane * 8;
  const float* gp = g + lane * 8;
  const float* bp = be + lane * 8;
#pragma unroll
  for (int j = 0; j < 8; ++j) op[j] = (vv[j] - mu) * inv * gp[j] + bp[j];
}

// ------------------------------------------------------------------------------
extern "C" void kernel_launch(void* const* d_in, const int* in_sizes, int n_in,
                              void* d_out, int out_size, void* d_ws, size_t ws_size,
                              hipStream_t stream) {
  const float* q   = (const float*)d_in[0];
  const float* k   = (const float*)d_in[1];
  const float* v   = (const float*)d_in[2];
  const float* Wq  = (const float*)d_in[3];
  const float* Wk  = (const float*)d_in[4];
  const float* Wv  = (const float*)d_in[5];
  const float* Wfc = (const float*)d_in[6];
  const float* rel = (const float*)d_in[7];
  const float* gam = (const float*)d_in[8];
  const float* bet = (const float*)d_in[9];

  char* ws = (char*)d_ws;
  size_t off = 0;
  auto take = [&](size_t bytes) {
    char* p = ws + off;
    off += (bytes + 255) & ~(size_t)255;
    return p;
  };
  bf16_t* wqb  = (bf16_t*)take((size_t)Dm * Dm * 2);
  bf16_t* wkb  = (bf16_t*)take((size_t)Dm * Dm * 2);
  bf16_t* wvb  = (bf16_t*)take((size_t)Dm * Dm * 2);
  bf16_t* wfcb = (bf16_t*)take((size_t)Dm * Dm * 2);
  bf16_t* relb = (bf16_t*)take((size_t)NREL * DKd * 2);
  bf16_t* qb   = (bf16_t*)take((size_t)MTOK * Dm * 2);
  bf16_t* kb   = (bf16_t*)take((size_t)MTOK * Dm * 2);
  bf16_t* vb   = (bf16_t*)take((size_t)MTOK * Dm * 2);
  bf16_t* Qhp  = (bf16_t*)take((size_t)MTOK * Dm * 2);
  bf16_t* Khp  = (bf16_t*)take((size_t)MTOK * Dm * 2);
  bf16_t* Vtp  = (bf16_t*)take((size_t)MTOK * Dm * 2);
  bf16_t* attnb= (bf16_t*)take((size_t)MTOK * Dm * 2);
  float*  yf   = (float*)take((size_t)MTOK * Dm * 4);

  // 1) weights + rel cast (one launch)
  k_castw<<<dim3(Dm * Dm / 1024, 5), 256, 0, stream>>>(
      Wq, Wk, Wv, Wfc, rel, wqb, wkb, wvb, wfcb, relb);
  // 2) q/k/v cast (one launch, 8 elems/thread)
  k_castx<<<dim3(MTOK * Dm / 2048, 3), 256, 0, stream>>>(
      q, k, v, qb, kb, vb);
  // 3) projections (bf16 A path — proven fastest)
  dim3 gg(Dm / 64, MTOK / 64);
  k_gemm512<0><<<gg, 256, 0, stream>>>(qb, wqb, Qhp);
  k_gemm512<0><<<gg, 256, 0, stream>>>(kb, wkb, Khp);
  k_gemm512<1><<<gg, 256, 0, stream>>>(vb, wvb, Vtp);
  // 4) attention (posdot fused; LDS-slimmed for 8 blocks/CU)
  k_attn<<<dim3(2048), 256, 0, stream>>>(Qhp, Khp, Vtp, relb, attnb);
  // 5) output GEMM + residual (fp32 yf)
  k_fc<<<gg, 256, 0, stream>>>(attnb, wfcb, yf, q);
  // 6) LayerNorm
  k_ln<<<dim3(MTOK / 4), 256, 0, stream>>>(yf, gam, bet, (float*)d_out);
}

// Round 19
// 228.601 us; speedup vs baseline: 1.1065x; 1.1065x over previous
//
#include <hip/hip_runtime.h>
#include <hip/hip_bf16.h>

typedef __bf16 bf16_t;
typedef __bf16 bf16x8 __attribute__((ext_vector_type(8)));
typedef float f32x4 __attribute__((ext_vector_type(4)));

constexpr int Bz = 8, Lseq = 1024, Dm = 512, Hh = 8, DKd = 64;
constexpr int MTOK = Bz * Lseq;   // 8192 tokens
constexpr int NREL = 201;
constexpr int PROW = 202;         // padded LDS row (bank stride 101%32=5, coprime)

// pos pre-scale: 0.125 (1/sqrt(dk)) * log2(e), folded so p = exp2(st*C + pos)
#define POS_C 0.18033688011112042f

__device__ inline float fexp2(float x) {
#if __has_builtin(__builtin_amdgcn_exp2f)
  return __builtin_amdgcn_exp2f(x);
#else
  return exp2f(x);
#endif
}
__device__ inline float b2f(unsigned short u) {
  return __builtin_bit_cast(float, (unsigned)u << 16);
}
__device__ inline unsigned pack2(float a, float b) {
  unsigned short ua = __builtin_bit_cast(unsigned short, (bf16_t)a);
  unsigned short ub = __builtin_bit_cast(unsigned short, (bf16_t)b);
  return (unsigned)ua | ((unsigned)ub << 16);
}

// ---------------- one-launch cast of Wq,Wk,Wv,Wfc + rel ----------------------
__global__ __launch_bounds__(256) void k_castw(
    const float* __restrict__ s0, const float* __restrict__ s1,
    const float* __restrict__ s2, const float* __restrict__ s3,
    const float* __restrict__ s4, bf16_t* __restrict__ d0,
    bf16_t* __restrict__ d1, bf16_t* __restrict__ d2, bf16_t* __restrict__ d3,
    bf16_t* __restrict__ d4) {
  const int y = blockIdx.y;
  const float* s = y == 0 ? s0 : y == 1 ? s1 : y == 2 ? s2 : y == 3 ? s3 : s4;
  bf16_t* d = y == 0 ? d0 : y == 1 ? d1 : y == 2 ? d2 : y == 3 ? d3 : d4;
  const int n = y < 4 ? Dm * Dm : NREL * DKd;
  int i = (blockIdx.x * 256 + threadIdx.x) * 4;
  if (i + 3 < n) {
    float4 v = *reinterpret_cast<const float4*>(s + i);
    d[i + 0] = (bf16_t)v.x;
    d[i + 1] = (bf16_t)v.y;
    d[i + 2] = (bf16_t)v.z;
    d[i + 3] = (bf16_t)v.w;
  } else if (i < n) {
    for (; i < n; ++i) d[i] = (bf16_t)s[i];
  }
}

// ---------------- one-launch cast of q,k,v: 8 elems/thread, 16B stores --------
__global__ __launch_bounds__(256) void k_castx(
    const float* __restrict__ s0, const float* __restrict__ s1,
    const float* __restrict__ s2, bf16_t* __restrict__ d0,
    bf16_t* __restrict__ d1, bf16_t* __restrict__ d2) {
  const int y = blockIdx.y;
  const float* s = y == 0 ? s0 : y == 1 ? s1 : s2;
  bf16_t* d = y == 0 ? d0 : y == 1 ? d1 : d2;
  const int i = (blockIdx.x * 256 + threadIdx.x) * 8;
  float4 a = *reinterpret_cast<const float4*>(s + i);
  float4 b = *reinterpret_cast<const float4*>(s + i + 4);
  bf16x8 r;
  r[0] = (bf16_t)a.x; r[1] = (bf16_t)a.y; r[2] = (bf16_t)a.z; r[3] = (bf16_t)a.w;
  r[4] = (bf16_t)b.x; r[5] = (bf16_t)b.y; r[6] = (bf16_t)b.z; r[7] = (bf16_t)b.w;
  *reinterpret_cast<bf16x8*>(d + i) = r;
}

// ---------------- y = A @ W^T  (A:[8192][512] bf16, W:[512][512] bf16) --------
// MODE 0: bf16 head-major; MODE 1: bf16 head-transposed.
template <int MODE>
__global__ __launch_bounds__(256) void k_gemm512(const bf16_t* __restrict__ A,
                                                 const bf16_t* __restrict__ W,
                                                 bf16_t* __restrict__ outb) {
  const int lane = threadIdx.x & 63, w = threadIdx.x >> 6;
  const int lr = lane & 15, lg = lane >> 4;
  // bijective chunked XCD swizzle (nwg=1024, chunk=128)
  const int orig = blockIdx.x + blockIdx.y * 8;
  const int swz = ((orig & 7) << 7) | (orig >> 3);
  const int Rbase = (swz >> 3) * 64 + (w >> 1) * 32;
  const int Cbase = (swz & 7) * 64 + (w & 1) * 32;

  f32x4 acc[2][2] = {};
  for (int k0 = 0; k0 < Dm; k0 += 32) {
    bf16x8 af[2], wf[2];
#pragma unroll
    for (int i = 0; i < 2; ++i)
      af[i] = *reinterpret_cast<const bf16x8*>(A + (size_t)(Rbase + i * 16 + lr) * Dm + k0 + lg * 8);
#pragma unroll
    for (int j = 0; j < 2; ++j)
      wf[j] = *reinterpret_cast<const bf16x8*>(W + (size_t)(Cbase + j * 16 + lr) * Dm + k0 + lg * 8);
#pragma unroll
    for (int i = 0; i < 2; ++i)
#pragma unroll
      for (int j = 0; j < 2; ++j)
        acc[i][j] = __builtin_amdgcn_mfma_f32_16x16x32_bf16(af[i], wf[j], acc[i][j], 0, 0, 0);
  }
#pragma unroll
  for (int i = 0; i < 2; ++i)
#pragma unroll
    for (int j = 0; j < 2; ++j)
#pragma unroll
      for (int r = 0; r < 4; ++r) {
        const int gr = Rbase + i * 16 + lg * 4 + r;  // token row
        const int gc = Cbase + j * 16 + lr;          // output col
        const int bb = gr >> 10, qq = gr & 1023, hh = gc >> 6, dd = gc & 63;
        const bf16_t vv = (bf16_t)acc[i][j][r];
        if (MODE == 0)
          outb[(((size_t)(bb * Hh + hh)) * Lseq + qq) * DKd + dd] = vv;
        else
          outb[(((size_t)(bb * Hh + hh)) * DKd + dd) * Lseq + qq] = vv;
      }
}

// ---------------- fc GEMM: yb = bf16(attnb @ Wfc^T + resid) -------------------
// bf16 store halves fc-write + ln-read traffic (32MB saved); LN stats on
// bf16-rounded x adds <=~0.01 abs on normalized output (threshold 0.0988).
__global__ __launch_bounds__(256) void k_fc(const bf16_t* __restrict__ A,
                                            const bf16_t* __restrict__ W,
                                            bf16_t* __restrict__ yb,
                                            const float* __restrict__ resid) {
  const int lane = threadIdx.x & 63, w = threadIdx.x >> 6;
  const int lr = lane & 15, lg = lane >> 4;
  // bijective chunked XCD swizzle (nwg=1024, chunk=128)
  const int orig = blockIdx.x + blockIdx.y * 8;
  const int swz = ((orig & 7) << 7) | (orig >> 3);
  const int Rbase = (swz >> 3) * 64 + (w >> 1) * 32;
  const int Cbase = (swz & 7) * 64 + (w & 1) * 32;

  f32x4 acc[2][2] = {};
  for (int k0 = 0; k0 < Dm; k0 += 32) {
    bf16x8 af[2], wf[2];
#pragma unroll
    for (int i = 0; i < 2; ++i)
      af[i] = *reinterpret_cast<const bf16x8*>(A + (size_t)(Rbase + i * 16 + lr) * Dm + k0 + lg * 8);
#pragma unroll
    for (int j = 0; j < 2; ++j)
      wf[j] = *reinterpret_cast<const bf16x8*>(W + (size_t)(Cbase + j * 16 + lr) * Dm + k0 + lg * 8);
#pragma unroll
    for (int i = 0; i < 2; ++i)
#pragma unroll
      for (int j = 0; j < 2; ++j)
        acc[i][j] = __builtin_amdgcn_mfma_f32_16x16x32_bf16(af[i], wf[j], acc[i][j], 0, 0, 0);
  }
#pragma unroll
  for (int i = 0; i < 2; ++i)
#pragma unroll
    for (int j = 0; j < 2; ++j)
#pragma unroll
      for (int r = 0; r < 4; ++r) {
        const int gr = Rbase + i * 16 + lg * 4 + r;
        const int gc = Cbase + j * 16 + lr;
        const size_t idx = (size_t)gr * Dm + gc;
        yb[idx] = (bf16_t)(acc[i][j][r] + resid[idx]);
      }
}

// ---------------- flash attention + fused in-block posdot (r15/r17: 84us) -----
__global__ __launch_bounds__(256, 4) void k_attn(const bf16_t* __restrict__ Qh,
                                                 const bf16_t* __restrict__ Kh,
                                                 const bf16_t* __restrict__ Vt,
                                                 const bf16_t* __restrict__ relb,
                                                 bf16_t* __restrict__ attnb) {
  __shared__ float smemf[6528];   // pos 12928B + Pl 10240B = 23168B; Ml 26112B

  const int tid = threadIdx.x;
  const int wv = tid >> 6, lane = tid & 63;
  const int lr = lane & 15, lg = lane >> 4;
  // bijective chunked XCD swizzle (nwg=2048, chunk=256)
  const int gid = ((blockIdx.x & 7) << 8) | (blockIdx.x >> 3);
  const int bh = gid >> 5;
  const int qb = (gid & 31) << 5;             // 32-row q tile

  unsigned short* pls = reinterpret_cast<unsigned short*>(smemf);     // [32][202]
  unsigned* Pw = reinterpret_cast<unsigned*>(smemf) + 3232 + wv * 640; // [2][16][20]

  const bf16_t* Qp = Qh + ((size_t)bh * Lseq + qb) * DKd;
  const bf16_t* Kp = Kh + (size_t)bh * Lseq * DKd;
  const bf16_t* Vp = Vt + (size_t)bh * DKd * Lseq;

  // Q fragments (dual-use: B-operand for swapped QK^T, A-operand for posdot)
  bf16x8 qf[2][2];
#pragma unroll
  for (int t = 0; t < 2; ++t)
#pragma unroll
    for (int h = 0; h < 2; ++h)
      qf[t][h] = *reinterpret_cast<const bf16x8*>(Qp + (size_t)(t * 16 + lr) * DKd + h * 32 + lg * 8);

  // ---- in-block posdot: pls[q][200-r] = POS_C * dot(Q[q], rel[r]) -----------
  for (int n = wv; n < 13; n += 4) {
    const int rr0 = n * 16 + lr;
    const int rclamp = rr0 > 200 ? 200 : rr0;
    bf16x8 rf0 = *reinterpret_cast<const bf16x8*>(relb + (size_t)rclamp * DKd + lg * 8);
    bf16x8 rf1 = *reinterpret_cast<const bf16x8*>(relb + (size_t)rclamp * DKd + 32 + lg * 8);
#pragma unroll
    for (int t = 0; t < 2; ++t) {
      f32x4 st = {};
      st = __builtin_amdgcn_mfma_f32_16x16x32_bf16(qf[t][0], rf0, st, 0, 0, 0);
      st = __builtin_amdgcn_mfma_f32_16x16x32_bf16(qf[t][1], rf1, st, 0, 0, 0);
      if (rr0 <= 200) {
#pragma unroll
        for (int r = 0; r < 4; ++r)
          pls[(t * 16 + lg * 4 + r) * PROW + (200 - rr0)] =
              __builtin_bit_cast(unsigned short, (bf16_t)(st[r] * POS_C));
      }
    }
  }
  __syncthreads();

  // per-lane pos row bases + band-edge constants (already scaled by POS_C)
  const unsigned short* prow[2] = {pls + (size_t)lr * PROW,
                                   pls + (size_t)(16 + lr) * PROW};
  float pe0[2], pe200[2];
#pragma unroll
  for (int t = 0; t < 2; ++t) {
    pe0[t] = b2f(prow[t][0]);       // k <= q-100 side
    pe200[t] = b2f(prow[t][200]);   // k >= q+100 side
  }

  f32x4 Oacc[2][4] = {};
  float psum[2] = {0.f, 0.f};
  const int ldelta = lg * 4 - lr;

  const int kbase = wv * 256;
#pragma unroll 2
  for (int k0 = kbase; k0 < kbase + 256; k0 += 32) {
    bf16x8 kf[2][2];
#pragma unroll
    for (int u = 0; u < 2; ++u)
#pragma unroll
      for (int h = 0; h < 2; ++h)
        kf[u][h] = *reinterpret_cast<const bf16x8*>(Kp + (size_t)(k0 + u * 16 + lr) * DKd + h * 32 + lg * 8);

#pragma unroll
    for (int t = 0; t < 2; ++t) {
      const int Qt = qb + t * 16;
      f32x4 st[2];
#pragma unroll
      for (int u = 0; u < 2; ++u) {
        f32x4 a = {};
        a = __builtin_amdgcn_mfma_f32_16x16x32_bf16(kf[u][0], qf[t][0], a, 0, 0, 0);
        a = __builtin_amdgcn_mfma_f32_16x16x32_bf16(kf[u][1], qf[t][1], a, 0, 0, 0);
        st[u] = a;  // element: q = Qt+lr (col), k = k0+u*16+lg*4+r (row)
      }
      float p[2][4];
      if (k0 + 131 <= Qt) {            // whole step below band: pos = pls[q][0]
#pragma unroll
        for (int u = 0; u < 2; ++u)
#pragma unroll
          for (int r = 0; r < 4; ++r)
            p[u][r] = fexp2(fmaf(st[u][r], POS_C, pe0[t]));
      } else if (k0 >= Qt + 115) {     // whole step above band: pos = pls[q][200]
#pragma unroll
        for (int u = 0; u < 2; ++u)
#pragma unroll
          for (int r = 0; r < 4; ++r)
            p[u][r] = fexp2(fmaf(st[u][r], POS_C, pe200[t]));
      } else {                         // in-band: clamped gather from LDS
#pragma unroll
        for (int u = 0; u < 2; ++u) {
          const int jb = k0 + u * 16 + 100 - Qt + ldelta;
#pragma unroll
          for (int r = 0; r < 4; ++r) {
            int j = jb + r;
            j = j < 0 ? 0 : (j > 200 ? 200 : j);
            p[u][r] = fexp2(fmaf(st[u][r], POS_C, b2f(prow[t][j])));
          }
        }
      }
#pragma unroll
      for (int u = 0; u < 2; ++u)
#pragma unroll
        for (int r = 0; r < 4; ++r) psum[t] += p[u][r];
      // pack to bf16, wave-private LDS transpose (D-layout -> B-frag layout)
#pragma unroll
      for (int u = 0; u < 2; ++u) {
        uint2 pk;
        pk.x = pack2(p[u][0], p[u][1]);
        pk.y = pack2(p[u][2], p[u][3]);
        *reinterpret_cast<uint2*>(&Pw[t * 320 + lr * 20 + u * 8 + lg * 2]) = pk;
      }
    }
    // PV: A = Vt fragment, B = P fragment read back from LDS
    bf16x8 pb[2];
#pragma unroll
    for (int t = 0; t < 2; ++t)
      pb[t] = *reinterpret_cast<const bf16x8*>(&Pw[t * 320 + lr * 20 + lg * 4]);
#pragma unroll
    for (int f = 0; f < 4; ++f) {
      bf16x8 vf = *reinterpret_cast<const bf16x8*>(Vp + (size_t)(f * 16 + lr) * Lseq + k0 + lg * 8);
#pragma unroll
      for (int t = 0; t < 2; ++t)
        Oacc[t][f] = __builtin_amdgcn_mfma_f32_16x16x32_bf16(vf, pb[t], Oacc[t][f], 0, 0, 0);
    }
  }

  // ---- merge the four k-quarters (no-max partials combine by pure addition) --
  __syncthreads();   // k-loops done; pos+Pl dead -> reuse smem as Ml[3][64][34]
  float* Ml = smemf;
  if (wv) {
    float* m = Ml + ((wv - 1) * 64 + lane) * 34;
#pragma unroll
    for (int t = 0; t < 2; ++t)
#pragma unroll
      for (int f = 0; f < 4; ++f)
#pragma unroll
        for (int r = 0; r < 4; ++r) m[t * 16 + f * 4 + r] = Oacc[t][f][r];
    m[32] = psum[0];
    m[33] = psum[1];
  }
  __syncthreads();
  if (!wv) {
#pragma unroll
    for (int w2 = 0; w2 < 3; ++w2) {
      const float* m = Ml + (w2 * 64 + lane) * 34;
#pragma unroll
      for (int t = 0; t < 2; ++t) {
#pragma unroll
        for (int f = 0; f < 4; ++f)
#pragma unroll
          for (int r = 0; r < 4; ++r) Oacc[t][f][r] += m[t * 16 + f * 4 + r];
        psum[t] += m[32 + t];
      }
    }
    const int gb = bh >> 3, hh = bh & 7;
#pragma unroll
    for (int t = 0; t < 2; ++t) {
      float s = psum[t];
      s += __shfl_xor(s, 16);
      s += __shfl_xor(s, 32);
      const float inv = 1.0f / s;
      const int qg = qb + t * 16 + lr;
#pragma unroll
      for (int f = 0; f < 4; ++f) {
        uint2 ov;
        ov.x = pack2(Oacc[t][f][0] * inv, Oacc[t][f][1] * inv);
        ov.y = pack2(Oacc[t][f][2] * inv, Oacc[t][f][3] * inv);
        *reinterpret_cast<uint2*>(attnb + ((size_t)(gb * Lseq + qg)) * Dm + hh * DKd + f * 16 + lg * 4) = ov;
      }
    }
  }
}

// ---------------- row LayerNorm over D=512, bf16 input ------------------------
__global__ __launch_bounds__(256) void k_ln(const bf16_t* __restrict__ y,
                                            const float* __restrict__ g,
                                            const float* __restrict__ be,
                                            float* __restrict__ out) {
  const int row = blockIdx.x * 4 + (threadIdx.x >> 6);
  const int lane = threadIdx.x & 63;
  bf16x8 rv = *reinterpret_cast<const bf16x8*>(y + (size_t)row * Dm + lane * 8);
  float vv[8];
#pragma unroll
  for (int j = 0; j < 8; ++j) vv[j] = (float)rv[j];
  float s = 0.f, s2 = 0.f;
#pragma unroll
  for (int j = 0; j < 8; ++j) { s += vv[j]; s2 += vv[j] * vv[j]; }
  for (int mk = 1; mk < 64; mk <<= 1) {
    s += __shfl_xor(s, mk, 64);
    s2 += __shfl_xor(s2, mk, 64);
  }
  const float mu = s * (1.0f / Dm);
  const float var = s2 * (1.0f / Dm) - mu * mu;
  const float inv = rsqrtf(var + 1e-6f);
  float* op = out + (size_t)row * Dm + lane * 8;
  const float* gp = g + lane * 8;
  const float* bp = be + lane * 8;
#pragma unroll
  for (int j = 0; j < 8; ++j) op[j] = (vv[j] - mu) * inv * gp[j] + bp[j];
}

// ------------------------------------------------------------------------------
extern "C" void kernel_launch(void* const* d_in, const int* in_sizes, int n_in,
                              void* d_out, int out_size, void* d_ws, size_t ws_size,
                              hipStream_t stream) {
  const float* q   = (const float*)d_in[0];
  const float* k   = (const float*)d_in[1];
  const float* v   = (const float*)d_in[2];
  const float* Wq  = (const float*)d_in[3];
  const float* Wk  = (const float*)d_in[4];
  const float* Wv  = (const float*)d_in[5];
  const float* Wfc = (const float*)d_in[6];
  const float* rel = (const float*)d_in[7];
  const float* gam = (const float*)d_in[8];
  const float* bet = (const float*)d_in[9];

  char* ws = (char*)d_ws;
  size_t off = 0;
  auto take = [&](size_t bytes) {
    char* p = ws + off;
    off += (bytes + 255) & ~(size_t)255;
    return p;
  };
  bf16_t* wqb  = (bf16_t*)take((size_t)Dm * Dm * 2);
  bf16_t* wkb  = (bf16_t*)take((size_t)Dm * Dm * 2);
  bf16_t* wvb  = (bf16_t*)take((size_t)Dm * Dm * 2);
  bf16_t* wfcb = (bf16_t*)take((size_t)Dm * Dm * 2);
  bf16_t* relb = (bf16_t*)take((size_t)NREL * DKd * 2);
  bf16_t* qb   = (bf16_t*)take((size_t)MTOK * Dm * 2);
  bf16_t* kb   = (bf16_t*)take((size_t)MTOK * Dm * 2);
  bf16_t* vb   = (bf16_t*)take((size_t)MTOK * Dm * 2);
  bf16_t* Qhp  = (bf16_t*)take((size_t)MTOK * Dm * 2);
  bf16_t* Khp  = (bf16_t*)take((size_t)MTOK * Dm * 2);
  bf16_t* Vtp  = (bf16_t*)take((size_t)MTOK * Dm * 2);
  bf16_t* attnb= (bf16_t*)take((size_t)MTOK * Dm * 2);
  bf16_t* yb   = (bf16_t*)take((size_t)MTOK * Dm * 2);

  // 1) weights + rel cast (one launch)
  k_castw<<<dim3(Dm * Dm / 1024, 5), 256, 0, stream>>>(
      Wq, Wk, Wv, Wfc, rel, wqb, wkb, wvb, wfcb, relb);
  // 2) q/k/v cast (one launch, 8 elems/thread)
  k_castx<<<dim3(MTOK * Dm / 2048, 3), 256, 0, stream>>>(
      q, k, v, qb, kb, vb);
  // 3) projections (bf16 A path — proven fastest)
  dim3 gg(Dm / 64, MTOK / 64);
  k_gemm512<0><<<gg, 256, 0, stream>>>(qb, wqb, Qhp);
  k_gemm512<0><<<gg, 256, 0, stream>>>(kb, wkb, Khp);
  k_gemm512<1><<<gg, 256, 0, stream>>>(vb, wvb, Vtp);
  // 4) attention (posdot fused in-block; r15/r17: 84us)
  k_attn<<<dim3(2048), 256, 0, stream>>>(Qhp, Khp, Vtp, relb, attnb);
  // 5) output GEMM + residual (bf16 yb — halves fc-write + ln-read traffic)
  k_fc<<<gg, 256, 0, stream>>>(attnb, wfcb, yb, q);
  // 6) LayerNorm (bf16 input)
  k_ln<<<dim3(MTOK / 4), 256, 0, stream>>>(yb, gam, bet, (float*)d_out);
}

// Round 20
// 225.209 us; speedup vs baseline: 1.1231x; 1.0151x over previous
//
#include <hip/hip_runtime.h>
#include <hip/hip_bf16.h>

typedef __bf16 bf16_t;
typedef __bf16 bf16x8 __attribute__((ext_vector_type(8)));
typedef float f32x4 __attribute__((ext_vector_type(4)));

constexpr int Bz = 8, Lseq = 1024, Dm = 512, Hh = 8, DKd = 64;
constexpr int MTOK = Bz * Lseq;   // 8192 tokens
constexpr int NREL = 201;
constexpr int PROW = 202;         // padded LDS row (bank stride 101%32=5, coprime)

// pos pre-scale: 0.125 (1/sqrt(dk)) * log2(e), folded so p = exp2(st*C + pos)
#define POS_C 0.18033688011112042f

__device__ inline float fexp2(float x) {
#if __has_builtin(__builtin_amdgcn_exp2f)
  return __builtin_amdgcn_exp2f(x);
#else
  return exp2f(x);
#endif
}
__device__ inline float b2f(unsigned short u) {
  return __builtin_bit_cast(float, (unsigned)u << 16);
}
__device__ inline unsigned pack2(float a, float b) {
  unsigned short ua = __builtin_bit_cast(unsigned short, (bf16_t)a);
  unsigned short ub = __builtin_bit_cast(unsigned short, (bf16_t)b);
  return (unsigned)ua | ((unsigned)ub << 16);
}

// ---------------- one-launch cast of Wq,Wk,Wv,Wfc + rel ----------------------
__global__ __launch_bounds__(256) void k_castw(
    const float* __restrict__ s0, const float* __restrict__ s1,
    const float* __restrict__ s2, const float* __restrict__ s3,
    const float* __restrict__ s4, bf16_t* __restrict__ d0,
    bf16_t* __restrict__ d1, bf16_t* __restrict__ d2, bf16_t* __restrict__ d3,
    bf16_t* __restrict__ d4) {
  const int y = blockIdx.y;
  const float* s = y == 0 ? s0 : y == 1 ? s1 : y == 2 ? s2 : y == 3 ? s3 : s4;
  bf16_t* d = y == 0 ? d0 : y == 1 ? d1 : y == 2 ? d2 : y == 3 ? d3 : d4;
  const int n = y < 4 ? Dm * Dm : NREL * DKd;
  int i = (blockIdx.x * 256 + threadIdx.x) * 4;
  if (i + 3 < n) {
    float4 v = *reinterpret_cast<const float4*>(s + i);
    d[i + 0] = (bf16_t)v.x;
    d[i + 1] = (bf16_t)v.y;
    d[i + 2] = (bf16_t)v.z;
    d[i + 3] = (bf16_t)v.w;
  } else if (i < n) {
    for (; i < n; ++i) d[i] = (bf16_t)s[i];
  }
}

// ---------------- one-launch cast of q,k,v: 8 elems/thread, 16B stores --------
__global__ __launch_bounds__(256) void k_castx(
    const float* __restrict__ s0, const float* __restrict__ s1,
    const float* __restrict__ s2, bf16_t* __restrict__ d0,
    bf16_t* __restrict__ d1, bf16_t* __restrict__ d2) {
  const int y = blockIdx.y;
  const float* s = y == 0 ? s0 : y == 1 ? s1 : s2;
  bf16_t* d = y == 0 ? d0 : y == 1 ? d1 : d2;
  const int i = (blockIdx.x * 256 + threadIdx.x) * 8;
  float4 a = *reinterpret_cast<const float4*>(s + i);
  float4 b = *reinterpret_cast<const float4*>(s + i + 4);
  bf16x8 r;
  r[0] = (bf16_t)a.x; r[1] = (bf16_t)a.y; r[2] = (bf16_t)a.z; r[3] = (bf16_t)a.w;
  r[4] = (bf16_t)b.x; r[5] = (bf16_t)b.y; r[6] = (bf16_t)b.z; r[7] = (bf16_t)b.w;
  *reinterpret_cast<bf16x8*>(d + i) = r;
}

// ---------------- y = A @ W^T  (A:[8192][512] bf16, W:[512][512] bf16) --------
// MODE 0: bf16 head-major; MODE 1: bf16 head-transposed.
// MODE 0 launches with gridDim.z=2 (Q and K share layout): pure OFFSET
// arithmetic from blockIdx.z (qb/kb, wqb/wkb, Qhp/Khp contiguous in ws) —
// no runtime pointer select, so no r11-style VGPR collapse.
template <int MODE>
__global__ __launch_bounds__(256) void k_gemm512(const bf16_t* __restrict__ A,
                                                 const bf16_t* __restrict__ W,
                                                 bf16_t* __restrict__ outb) {
  const int lane = threadIdx.x & 63, w = threadIdx.x >> 6;
  const int lr = lane & 15, lg = lane >> 4;
  if (MODE == 0) {
    const size_t zo = (size_t)blockIdx.z * ((size_t)MTOK * Dm);
    A += zo;
    W += (size_t)blockIdx.z * ((size_t)Dm * Dm);
    outb += zo;
  }
  // bijective chunked XCD swizzle (nwg=1024, chunk=128)
  const int orig = blockIdx.x + blockIdx.y * 8;
  const int swz = ((orig & 7) << 7) | (orig >> 3);
  const int Rbase = (swz >> 3) * 64 + (w >> 1) * 32;
  const int Cbase = (swz & 7) * 64 + (w & 1) * 32;

  f32x4 acc[2][2] = {};
  for (int k0 = 0; k0 < Dm; k0 += 32) {
    bf16x8 af[2], wf[2];
#pragma unroll
    for (int i = 0; i < 2; ++i)
      af[i] = *reinterpret_cast<const bf16x8*>(A + (size_t)(Rbase + i * 16 + lr) * Dm + k0 + lg * 8);
#pragma unroll
    for (int j = 0; j < 2; ++j)
      wf[j] = *reinterpret_cast<const bf16x8*>(W + (size_t)(Cbase + j * 16 + lr) * Dm + k0 + lg * 8);
#pragma unroll
    for (int i = 0; i < 2; ++i)
#pragma unroll
      for (int j = 0; j < 2; ++j)
        acc[i][j] = __builtin_amdgcn_mfma_f32_16x16x32_bf16(af[i], wf[j], acc[i][j], 0, 0, 0);
  }
#pragma unroll
  for (int i = 0; i < 2; ++i)
#pragma unroll
    for (int j = 0; j < 2; ++j)
#pragma unroll
      for (int r = 0; r < 4; ++r) {
        const int gr = Rbase + i * 16 + lg * 4 + r;  // token row
        const int gc = Cbase + j * 16 + lr;          // output col
        const int bb = gr >> 10, qq = gr & 1023, hh = gc >> 6, dd = gc & 63;
        const bf16_t vv = (bf16_t)acc[i][j][r];
        if (MODE == 0)
          outb[(((size_t)(bb * Hh + hh)) * Lseq + qq) * DKd + dd] = vv;
        else
          outb[(((size_t)(bb * Hh + hh)) * DKd + dd) * Lseq + qq] = vv;
      }
}

// ---------------- fc GEMM: yb = bf16(attnb @ Wfc^T + resid) -------------------
__global__ __launch_bounds__(256) void k_fc(const bf16_t* __restrict__ A,
                                            const bf16_t* __restrict__ W,
                                            bf16_t* __restrict__ yb,
                                            const float* __restrict__ resid) {
  const int lane = threadIdx.x & 63, w = threadIdx.x >> 6;
  const int lr = lane & 15, lg = lane >> 4;
  // bijective chunked XCD swizzle (nwg=1024, chunk=128)
  const int orig = blockIdx.x + blockIdx.y * 8;
  const int swz = ((orig & 7) << 7) | (orig >> 3);
  const int Rbase = (swz >> 3) * 64 + (w >> 1) * 32;
  const int Cbase = (swz & 7) * 64 + (w & 1) * 32;

  f32x4 acc[2][2] = {};
  for (int k0 = 0; k0 < Dm; k0 += 32) {
    bf16x8 af[2], wf[2];
#pragma unroll
    for (int i = 0; i < 2; ++i)
      af[i] = *reinterpret_cast<const bf16x8*>(A + (size_t)(Rbase + i * 16 + lr) * Dm + k0 + lg * 8);
#pragma unroll
    for (int j = 0; j < 2; ++j)
      wf[j] = *reinterpret_cast<const bf16x8*>(W + (size_t)(Cbase + j * 16 + lr) * Dm + k0 + lg * 8);
#pragma unroll
    for (int i = 0; i < 2; ++i)
#pragma unroll
      for (int j = 0; j < 2; ++j)
        acc[i][j] = __builtin_amdgcn_mfma_f32_16x16x32_bf16(af[i], wf[j], acc[i][j], 0, 0, 0);
  }
#pragma unroll
  for (int i = 0; i < 2; ++i)
#pragma unroll
    for (int j = 0; j < 2; ++j)
#pragma unroll
      for (int r = 0; r < 4; ++r) {
        const int gr = Rbase + i * 16 + lg * 4 + r;
        const int gc = Cbase + j * 16 + lr;
        const size_t idx = (size_t)gr * Dm + gc;
        yb[idx] = (bf16_t)(acc[i][j][r] + resid[idx]);
      }
}

// ---------------- flash attention + fused in-block posdot (84us base) ---------
// + T5 s_setprio(1) around the per-k-step compute phase: the 4 waves/block run
// barrier-free at independent phases, the regime where setprio measured +4-7%.
__global__ __launch_bounds__(256, 4) void k_attn(const bf16_t* __restrict__ Qh,
                                                 const bf16_t* __restrict__ Kh,
                                                 const bf16_t* __restrict__ Vt,
                                                 const bf16_t* __restrict__ relb,
                                                 bf16_t* __restrict__ attnb) {
  __shared__ float smemf[6528];   // pos 12928B + Pl 10240B = 23168B; Ml 26112B

  const int tid = threadIdx.x;
  const int wv = tid >> 6, lane = tid & 63;
  const int lr = lane & 15, lg = lane >> 4;
  // bijective chunked XCD swizzle (nwg=2048, chunk=256)
  const int gid = ((blockIdx.x & 7) << 8) | (blockIdx.x >> 3);
  const int bh = gid >> 5;
  const int qb = (gid & 31) << 5;             // 32-row q tile

  unsigned short* pls = reinterpret_cast<unsigned short*>(smemf);     // [32][202]
  unsigned* Pw = reinterpret_cast<unsigned*>(smemf) + 3232 + wv * 640; // [2][16][20]

  const bf16_t* Qp = Qh + ((size_t)bh * Lseq + qb) * DKd;
  const bf16_t* Kp = Kh + (size_t)bh * Lseq * DKd;
  const bf16_t* Vp = Vt + (size_t)bh * DKd * Lseq;

  // Q fragments (dual-use: B-operand for swapped QK^T, A-operand for posdot)
  bf16x8 qf[2][2];
#pragma unroll
  for (int t = 0; t < 2; ++t)
#pragma unroll
    for (int h = 0; h < 2; ++h)
      qf[t][h] = *reinterpret_cast<const bf16x8*>(Qp + (size_t)(t * 16 + lr) * DKd + h * 32 + lg * 8);

  // ---- in-block posdot: pls[q][200-r] = POS_C * dot(Q[q], rel[r]) -----------
  for (int n = wv; n < 13; n += 4) {
    const int rr0 = n * 16 + lr;
    const int rclamp = rr0 > 200 ? 200 : rr0;
    bf16x8 rf0 = *reinterpret_cast<const bf16x8*>(relb + (size_t)rclamp * DKd + lg * 8);
    bf16x8 rf1 = *reinterpret_cast<const bf16x8*>(relb + (size_t)rclamp * DKd + 32 + lg * 8);
#pragma unroll
    for (int t = 0; t < 2; ++t) {
      f32x4 st = {};
      st = __builtin_amdgcn_mfma_f32_16x16x32_bf16(qf[t][0], rf0, st, 0, 0, 0);
      st = __builtin_amdgcn_mfma_f32_16x16x32_bf16(qf[t][1], rf1, st, 0, 0, 0);
      if (rr0 <= 200) {
#pragma unroll
        for (int r = 0; r < 4; ++r)
          pls[(t * 16 + lg * 4 + r) * PROW + (200 - rr0)] =
              __builtin_bit_cast(unsigned short, (bf16_t)(st[r] * POS_C));
      }
    }
  }
  __syncthreads();

  // per-lane pos row bases + band-edge constants (already scaled by POS_C)
  const unsigned short* prow[2] = {pls + (size_t)lr * PROW,
                                   pls + (size_t)(16 + lr) * PROW};
  float pe0[2], pe200[2];
#pragma unroll
  for (int t = 0; t < 2; ++t) {
    pe0[t] = b2f(prow[t][0]);       // k <= q-100 side
    pe200[t] = b2f(prow[t][200]);   // k >= q+100 side
  }

  f32x4 Oacc[2][4] = {};
  float psum[2] = {0.f, 0.f};
  const int ldelta = lg * 4 - lr;

  const int kbase = wv * 256;
#pragma unroll 2
  for (int k0 = kbase; k0 < kbase + 256; k0 += 32) {
    bf16x8 kf[2][2];
#pragma unroll
    for (int u = 0; u < 2; ++u)
#pragma unroll
      for (int h = 0; h < 2; ++h)
        kf[u][h] = *reinterpret_cast<const bf16x8*>(Kp + (size_t)(k0 + u * 16 + lr) * DKd + h * 32 + lg * 8);

    __builtin_amdgcn_s_setprio(1);
#pragma unroll
    for (int t = 0; t < 2; ++t) {
      const int Qt = qb + t * 16;
      f32x4 st[2];
#pragma unroll
      for (int u = 0; u < 2; ++u) {
        f32x4 a = {};
        a = __builtin_amdgcn_mfma_f32_16x16x32_bf16(kf[u][0], qf[t][0], a, 0, 0, 0);
        a = __builtin_amdgcn_mfma_f32_16x16x32_bf16(kf[u][1], qf[t][1], a, 0, 0, 0);
        st[u] = a;  // element: q = Qt+lr (col), k = k0+u*16+lg*4+r (row)
      }
      float p[2][4];
      if (k0 + 131 <= Qt) {            // whole step below band: pos = pls[q][0]
#pragma unroll
        for (int u = 0; u < 2; ++u)
#pragma unroll
          for (int r = 0; r < 4; ++r)
            p[u][r] = fexp2(fmaf(st[u][r], POS_C, pe0[t]));
      } else if (k0 >= Qt + 115) {     // whole step above band: pos = pls[q][200]
#pragma unroll
        for (int u = 0; u < 2; ++u)
#pragma unroll
          for (int r = 0; r < 4; ++r)
            p[u][r] = fexp2(fmaf(st[u][r], POS_C, pe200[t]));
      } else {                         // in-band: clamped gather from LDS
#pragma unroll
        for (int u = 0; u < 2; ++u) {
          const int jb = k0 + u * 16 + 100 - Qt + ldelta;
#pragma unroll
          for (int r = 0; r < 4; ++r) {
            int j = jb + r;
            j = j < 0 ? 0 : (j > 200 ? 200 : j);
            p[u][r] = fexp2(fmaf(st[u][r], POS_C, b2f(prow[t][j])));
          }
        }
      }
#pragma unroll
      for (int u = 0; u < 2; ++u)
#pragma unroll
        for (int r = 0; r < 4; ++r) psum[t] += p[u][r];
      // pack to bf16, wave-private LDS transpose (D-layout -> B-frag layout)
#pragma unroll
      for (int u = 0; u < 2; ++u) {
        uint2 pk;
        pk.x = pack2(p[u][0], p[u][1]);
        pk.y = pack2(p[u][2], p[u][3]);
        *reinterpret_cast<uint2*>(&Pw[t * 320 + lr * 20 + u * 8 + lg * 2]) = pk;
      }
    }
    // PV: A = Vt fragment, B = P fragment read back from LDS
    bf16x8 pb[2];
#pragma unroll
    for (int t = 0; t < 2; ++t)
      pb[t] = *reinterpret_cast<const bf16x8*>(&Pw[t * 320 + lr * 20 + lg * 4]);
#pragma unroll
    for (int f = 0; f < 4; ++f) {
      bf16x8 vf = *reinterpret_cast<const bf16x8*>(Vp + (size_t)(f * 16 + lr) * Lseq + k0 + lg * 8);
#pragma unroll
      for (int t = 0; t < 2; ++t)
        Oacc[t][f] = __builtin_amdgcn_mfma_f32_16x16x32_bf16(vf, pb[t], Oacc[t][f], 0, 0, 0);
    }
    __builtin_amdgcn_s_setprio(0);
  }

  // ---- merge the four k-quarters (no-max partials combine by pure addition) --
  __syncthreads();   // k-loops done; pos+Pl dead -> reuse smem as Ml[3][64][34]
  float* Ml = smemf;
  if (wv) {
    float* m = Ml + ((wv - 1) * 64 + lane) * 34;
#pragma unroll
    for (int t = 0; t < 2; ++t)
#pragma unroll
      for (int f = 0; f < 4; ++f)
#pragma unroll
        for (int r = 0; r < 4; ++r) m[t * 16 + f * 4 + r] = Oacc[t][f][r];
    m[32] = psum[0];
    m[33] = psum[1];
  }
  __syncthreads();
  if (!wv) {
#pragma unroll
    for (int w2 = 0; w2 < 3; ++w2) {
      const float* m = Ml + (w2 * 64 + lane) * 34;
#pragma unroll
      for (int t = 0; t < 2; ++t) {
#pragma unroll
        for (int f = 0; f < 4; ++f)
#pragma unroll
          for (int r = 0; r < 4; ++r) Oacc[t][f][r] += m[t * 16 + f * 4 + r];
        psum[t] += m[32 + t];
      }
    }
    const int gb = bh >> 3, hh = bh & 7;
#pragma unroll
    for (int t = 0; t < 2; ++t) {
      float s = psum[t];
      s += __shfl_xor(s, 16);
      s += __shfl_xor(s, 32);
      const float inv = 1.0f / s;
      const int qg = qb + t * 16 + lr;
#pragma unroll
      for (int f = 0; f < 4; ++f) {
        uint2 ov;
        ov.x = pack2(Oacc[t][f][0] * inv, Oacc[t][f][1] * inv);
        ov.y = pack2(Oacc[t][f][2] * inv, Oacc[t][f][3] * inv);
        *reinterpret_cast<uint2*>(attnb + ((size_t)(gb * Lseq + qg)) * Dm + hh * DKd + f * 16 + lg * 4) = ov;
      }
    }
  }
}

// ---------------- row LayerNorm over D=512, bf16 input ------------------------
__global__ __launch_bounds__(256) void k_ln(const bf16_t* __restrict__ y,
                                            const float* __restrict__ g,
                                            const float* __restrict__ be,
                                            float* __restrict__ out) {
  const int row = blockIdx.x * 4 + (threadIdx.x >> 6);
  const int lane = threadIdx.x & 63;
  bf16x8 rv = *reinterpret_cast<const bf16x8*>(y + (size_t)row * Dm + lane * 8);
  float vv[8];
#pragma unroll
  for (int j = 0; j < 8; ++j) vv[j] = (float)rv[j];
  float s = 0.f, s2 = 0.f;
#pragma unroll
  for (int j = 0; j < 8; ++j) { s += vv[j]; s2 += vv[j] * vv[j]; }
  for (int mk = 1; mk < 64; mk <<= 1) {
    s += __shfl_xor(s, mk, 64);
    s2 += __shfl_xor(s2, mk, 64);
  }
  const float mu = s * (1.0f / Dm);
  const float var = s2 * (1.0f / Dm) - mu * mu;
  const float inv = rsqrtf(var + 1e-6f);
  float* op = out + (size_t)row * Dm + lane * 8;
  const float* gp = g + lane * 8;
  const float* bp = be + lane * 8;
#pragma unroll
  for (int j = 0; j < 8; ++j) op[j] = (vv[j] - mu) * inv * gp[j] + bp[j];
}

// ------------------------------------------------------------------------------
extern "C" void kernel_launch(void* const* d_in, const int* in_sizes, int n_in,
                              void* d_out, int out_size, void* d_ws, size_t ws_size,
                              hipStream_t stream) {
  const float* q   = (const float*)d_in[0];
  const float* k   = (const float*)d_in[1];
  const float* v   = (const float*)d_in[2];
  const float* Wq  = (const float*)d_in[3];
  const float* Wk  = (const float*)d_in[4];
  const float* Wv  = (const float*)d_in[5];
  const float* Wfc = (const float*)d_in[6];
  const float* rel = (const float*)d_in[7];
  const float* gam = (const float*)d_in[8];
  const float* bet = (const float*)d_in[9];

  char* ws = (char*)d_ws;
  size_t off = 0;
  auto take = [&](size_t bytes) {
    char* p = ws + off;
    off += (bytes + 255) & ~(size_t)255;
    return p;
  };
  // NOTE: wqb/wkb contiguous and qb/kb contiguous and Qhp/Khp contiguous —
  // required by the z-merged MODE-0 projection launch (offset arithmetic).
  bf16_t* wqb  = (bf16_t*)take((size_t)Dm * Dm * 2);
  bf16_t* wkb  = (bf16_t*)take((size_t)Dm * Dm * 2);
  bf16_t* wvb  = (bf16_t*)take((size_t)Dm * Dm * 2);
  bf16_t* wfcb = (bf16_t*)take((size_t)Dm * Dm * 2);
  bf16_t* relb = (bf16_t*)take((size_t)NREL * DKd * 2);
  bf16_t* qb   = (bf16_t*)take((size_t)MTOK * Dm * 2);
  bf16_t* kb   = (bf16_t*)take((size_t)MTOK * Dm * 2);
  bf16_t* vb   = (bf16_t*)take((size_t)MTOK * Dm * 2);
  bf16_t* Qhp  = (bf16_t*)take((size_t)MTOK * Dm * 2);
  bf16_t* Khp  = (bf16_t*)take((size_t)MTOK * Dm * 2);
  bf16_t* Vtp  = (bf16_t*)take((size_t)MTOK * Dm * 2);
  bf16_t* attnb= (bf16_t*)take((size_t)MTOK * Dm * 2);
  bf16_t* yb   = (bf16_t*)take((size_t)MTOK * Dm * 2);

  // 1) weights + rel cast (one launch)
  k_castw<<<dim3(Dm * Dm / 1024, 5), 256, 0, stream>>>(
      Wq, Wk, Wv, Wfc, rel, wqb, wkb, wvb, wfcb, relb);
  // 2) q/k/v cast (one launch, 8 elems/thread)
  k_castx<<<dim3(MTOK * Dm / 2048, 3), 256, 0, stream>>>(
      q, k, v, qb, kb, vb);
  // 3) projections: Q+K z-merged (offset arithmetic), V separate
  k_gemm512<0><<<dim3(Dm / 64, MTOK / 64, 2), 256, 0, stream>>>(qb, wqb, Qhp);
  k_gemm512<1><<<dim3(Dm / 64, MTOK / 64), 256, 0, stream>>>(vb, wvb, Vtp);
  // 4) attention (posdot fused; + setprio around compute phase)
  k_attn<<<dim3(2048), 256, 0, stream>>>(Qhp, Khp, Vtp, relb, attnb);
  // 5) output GEMM + residual (bf16 yb)
  k_fc<<<dim3(Dm / 64, MTOK / 64), 256, 0, stream>>>(attnb, wfcb, yb, q);
  // 6) LayerNorm (bf16 input)
  k_ln<<<dim3(MTOK / 4), 256, 0, stream>>>(yb, gam, bet, (float*)d_out);
}

// Round 21
// 223.617 us; speedup vs baseline: 1.1311x; 1.0071x over previous
//
#include <hip/hip_runtime.h>
#include <hip/hip_bf16.h>

typedef __bf16 bf16_t;
typedef __bf16 bf16x8 __attribute__((ext_vector_type(8)));
typedef float f32x4 __attribute__((ext_vector_type(4)));

constexpr int Bz = 8, Lseq = 1024, Dm = 512, Hh = 8, DKd = 64;
constexpr int MTOK = Bz * Lseq;   // 8192 tokens
constexpr int NREL = 201;
constexpr int PROW = 202;         // padded LDS row (bank stride 101%32=5, coprime)

// pos pre-scale: 0.125 (1/sqrt(dk)) * log2(e), folded so p = exp2(st*C + pos)
#define POS_C 0.18033688011112042f

__device__ inline float fexp2(float x) {
#if __has_builtin(__builtin_amdgcn_exp2f)
  return __builtin_amdgcn_exp2f(x);
#else
  return exp2f(x);
#endif
}
__device__ inline float b2f(unsigned short u) {
  return __builtin_bit_cast(float, (unsigned)u << 16);
}
__device__ inline unsigned pack2(float a, float b) {
  unsigned short ua = __builtin_bit_cast(unsigned short, (bf16_t)a);
  unsigned short ub = __builtin_bit_cast(unsigned short, (bf16_t)b);
  return (unsigned)ua | ((unsigned)ub << 16);
}

// ---------------- ONE launch for ALL casts ------------------------------------
// y in {0,1,2}: q/k/v (8 elems/thread, 2048 x-blocks exactly).
// y == 3: flattened — x<1024: the 4 weight matrices (256 blocks each, 4/thread);
//         x in [1024,1037): rel table (guarded).
__global__ __launch_bounds__(256) void k_cast_all(
    const float* __restrict__ q, const float* __restrict__ k,
    const float* __restrict__ v, const float* __restrict__ w0,
    const float* __restrict__ w1, const float* __restrict__ w2,
    const float* __restrict__ w3, const float* __restrict__ rel,
    bf16_t* __restrict__ qb, bf16_t* __restrict__ kb, bf16_t* __restrict__ vb,
    bf16_t* __restrict__ d0, bf16_t* __restrict__ d1, bf16_t* __restrict__ d2,
    bf16_t* __restrict__ d3, bf16_t* __restrict__ drel) {
  const int y = blockIdx.y;
  if (y < 3) {
    const float* s = y == 0 ? q : y == 1 ? k : v;
    bf16_t* d = y == 0 ? qb : y == 1 ? kb : vb;
    const int i = (blockIdx.x * 256 + threadIdx.x) * 8;
    float4 a = *reinterpret_cast<const float4*>(s + i);
    float4 b = *reinterpret_cast<const float4*>(s + i + 4);
    bf16x8 r;
    r[0] = (bf16_t)a.x; r[1] = (bf16_t)a.y; r[2] = (bf16_t)a.z; r[3] = (bf16_t)a.w;
    r[4] = (bf16_t)b.x; r[5] = (bf16_t)b.y; r[6] = (bf16_t)b.z; r[7] = (bf16_t)b.w;
    *reinterpret_cast<bf16x8*>(d + i) = r;
  } else {
    const int x = blockIdx.x;
    if (x < 1024) {
      const int wsel = x >> 8;
      const float* s = wsel == 0 ? w0 : wsel == 1 ? w1 : wsel == 2 ? w2 : w3;
      bf16_t* d = wsel == 0 ? d0 : wsel == 1 ? d1 : wsel == 2 ? d2 : d3;
      const int i = ((x & 255) * 256 + threadIdx.x) * 4;
      float4 vv = *reinterpret_cast<const float4*>(s + i);
      d[i + 0] = (bf16_t)vv.x;
      d[i + 1] = (bf16_t)vv.y;
      d[i + 2] = (bf16_t)vv.z;
      d[i + 3] = (bf16_t)vv.w;
    } else if (x < 1037) {
      const int i = ((x - 1024) * 256 + threadIdx.x) * 4;
      if (i < NREL * DKd) {   // 12864 divisible by 4 -> exact
        float4 vv = *reinterpret_cast<const float4*>(rel + i);
        drel[i + 0] = (bf16_t)vv.x;
        drel[i + 1] = (bf16_t)vv.y;
        drel[i + 2] = (bf16_t)vv.z;
        drel[i + 3] = (bf16_t)vv.w;
      }
    }
  }
}

// ---------------- ONE launch for all three projections ------------------------
// z in {0,1,2} = Q,K,V: A/W/out via pure offset arithmetic (buffers contiguous
// in ws) — hot loop identical for all z; only the (uniform) epilogue store
// layout branches (z<2 head-major, z==2 head-transposed).
__global__ __launch_bounds__(256) void k_proj3(const bf16_t* __restrict__ A,
                                               const bf16_t* __restrict__ W,
                                               bf16_t* __restrict__ outb) {
  const int lane = threadIdx.x & 63, w = threadIdx.x >> 6;
  const int lr = lane & 15, lg = lane >> 4;
  const int z = blockIdx.z;
  const size_t zo = (size_t)z * ((size_t)MTOK * Dm);
  A += zo;
  W += (size_t)z * ((size_t)Dm * Dm);
  outb += zo;
  // bijective chunked XCD swizzle (nwg=1024, chunk=128)
  const int orig = blockIdx.x + blockIdx.y * 8;
  const int swz = ((orig & 7) << 7) | (orig >> 3);
  const int Rbase = (swz >> 3) * 64 + (w >> 1) * 32;
  const int Cbase = (swz & 7) * 64 + (w & 1) * 32;

  f32x4 acc[2][2] = {};
  for (int k0 = 0; k0 < Dm; k0 += 32) {
    bf16x8 af[2], wf[2];
#pragma unroll
    for (int i = 0; i < 2; ++i)
      af[i] = *reinterpret_cast<const bf16x8*>(A + (size_t)(Rbase + i * 16 + lr) * Dm + k0 + lg * 8);
#pragma unroll
    for (int j = 0; j < 2; ++j)
      wf[j] = *reinterpret_cast<const bf16x8*>(W + (size_t)(Cbase + j * 16 + lr) * Dm + k0 + lg * 8);
#pragma unroll
    for (int i = 0; i < 2; ++i)
#pragma unroll
      for (int j = 0; j < 2; ++j)
        acc[i][j] = __builtin_amdgcn_mfma_f32_16x16x32_bf16(af[i], wf[j], acc[i][j], 0, 0, 0);
  }
#pragma unroll
  for (int i = 0; i < 2; ++i)
#pragma unroll
    for (int j = 0; j < 2; ++j)
#pragma unroll
      for (int r = 0; r < 4; ++r) {
        const int gr = Rbase + i * 16 + lg * 4 + r;  // token row
        const int gc = Cbase + j * 16 + lr;          // output col
        const int bb = gr >> 10, qq = gr & 1023, hh = gc >> 6, dd = gc & 63;
        const bf16_t vv = (bf16_t)acc[i][j][r];
        if (z < 2)
          outb[(((size_t)(bb * Hh + hh)) * Lseq + qq) * DKd + dd] = vv;
        else
          outb[(((size_t)(bb * Hh + hh)) * DKd + dd) * Lseq + qq] = vv;
      }
}

// ---------------- fc GEMM: yb = bf16(attnb @ Wfc^T + resid) -------------------
__global__ __launch_bounds__(256) void k_fc(const bf16_t* __restrict__ A,
                                            const bf16_t* __restrict__ W,
                                            bf16_t* __restrict__ yb,
                                            const float* __restrict__ resid) {
  const int lane = threadIdx.x & 63, w = threadIdx.x >> 6;
  const int lr = lane & 15, lg = lane >> 4;
  // bijective chunked XCD swizzle (nwg=1024, chunk=128)
  const int orig = blockIdx.x + blockIdx.y * 8;
  const int swz = ((orig & 7) << 7) | (orig >> 3);
  const int Rbase = (swz >> 3) * 64 + (w >> 1) * 32;
  const int Cbase = (swz & 7) * 64 + (w & 1) * 32;

  f32x4 acc[2][2] = {};
  for (int k0 = 0; k0 < Dm; k0 += 32) {
    bf16x8 af[2], wf[2];
#pragma unroll
    for (int i = 0; i < 2; ++i)
      af[i] = *reinterpret_cast<const bf16x8*>(A + (size_t)(Rbase + i * 16 + lr) * Dm + k0 + lg * 8);
#pragma unroll
    for (int j = 0; j < 2; ++j)
      wf[j] = *reinterpret_cast<const bf16x8*>(W + (size_t)(Cbase + j * 16 + lr) * Dm + k0 + lg * 8);
#pragma unroll
    for (int i = 0; i < 2; ++i)
#pragma unroll
      for (int j = 0; j < 2; ++j)
        acc[i][j] = __builtin_amdgcn_mfma_f32_16x16x32_bf16(af[i], wf[j], acc[i][j], 0, 0, 0);
  }
#pragma unroll
  for (int i = 0; i < 2; ++i)
#pragma unroll
    for (int j = 0; j < 2; ++j)
#pragma unroll
      for (int r = 0; r < 4; ++r) {
        const int gr = Rbase + i * 16 + lg * 4 + r;
        const int gc = Cbase + j * 16 + lr;
        const size_t idx = (size_t)gr * Dm + gc;
        yb[idx] = (bf16_t)(acc[i][j][r] + resid[idx]);
      }
}

// ---------------- flash attention + fused in-block posdot (84us, stable) ------
__global__ __launch_bounds__(256, 4) void k_attn(const bf16_t* __restrict__ Qh,
                                                 const bf16_t* __restrict__ Kh,
                                                 const bf16_t* __restrict__ Vt,
                                                 const bf16_t* __restrict__ relb,
                                                 bf16_t* __restrict__ attnb) {
  __shared__ float smemf[6528];   // pos 12928B + Pl 10240B = 23168B; Ml 26112B

  const int tid = threadIdx.x;
  const int wv = tid >> 6, lane = tid & 63;
  const int lr = lane & 15, lg = lane >> 4;
  // bijective chunked XCD swizzle (nwg=2048, chunk=256)
  const int gid = ((blockIdx.x & 7) << 8) | (blockIdx.x >> 3);
  const int bh = gid >> 5;
  const int qb = (gid & 31) << 5;             // 32-row q tile

  unsigned short* pls = reinterpret_cast<unsigned short*>(smemf);     // [32][202]
  unsigned* Pw = reinterpret_cast<unsigned*>(smemf) + 3232 + wv * 640; // [2][16][20]

  const bf16_t* Qp = Qh + ((size_t)bh * Lseq + qb) * DKd;
  const bf16_t* Kp = Kh + (size_t)bh * Lseq * DKd;
  const bf16_t* Vp = Vt + (size_t)bh * DKd * Lseq;

  // Q fragments (dual-use: B-operand for swapped QK^T, A-operand for posdot)
  bf16x8 qf[2][2];
#pragma unroll
  for (int t = 0; t < 2; ++t)
#pragma unroll
    for (int h = 0; h < 2; ++h)
      qf[t][h] = *reinterpret_cast<const bf16x8*>(Qp + (size_t)(t * 16 + lr) * DKd + h * 32 + lg * 8);

  // ---- in-block posdot: pls[q][200-r] = POS_C * dot(Q[q], rel[r]) -----------
  for (int n = wv; n < 13; n += 4) {
    const int rr0 = n * 16 + lr;
    const int rclamp = rr0 > 200 ? 200 : rr0;
    bf16x8 rf0 = *reinterpret_cast<const bf16x8*>(relb + (size_t)rclamp * DKd + lg * 8);
    bf16x8 rf1 = *reinterpret_cast<const bf16x8*>(relb + (size_t)rclamp * DKd + 32 + lg * 8);
#pragma unroll
    for (int t = 0; t < 2; ++t) {
      f32x4 st = {};
      st = __builtin_amdgcn_mfma_f32_16x16x32_bf16(qf[t][0], rf0, st, 0, 0, 0);
      st = __builtin_amdgcn_mfma_f32_16x16x32_bf16(qf[t][1], rf1, st, 0, 0, 0);
      if (rr0 <= 200) {
#pragma unroll
        for (int r = 0; r < 4; ++r)
          pls[(t * 16 + lg * 4 + r) * PROW + (200 - rr0)] =
              __builtin_bit_cast(unsigned short, (bf16_t)(st[r] * POS_C));
      }
    }
  }
  __syncthreads();

  // per-lane pos row bases + band-edge constants (already scaled by POS_C)
  const unsigned short* prow[2] = {pls + (size_t)lr * PROW,
                                   pls + (size_t)(16 + lr) * PROW};
  float pe0[2], pe200[2];
#pragma unroll
  for (int t = 0; t < 2; ++t) {
    pe0[t] = b2f(prow[t][0]);       // k <= q-100 side
    pe200[t] = b2f(prow[t][200]);   // k >= q+100 side
  }

  f32x4 Oacc[2][4] = {};
  float psum[2] = {0.f, 0.f};
  const int ldelta = lg * 4 - lr;

  const int kbase = wv * 256;
#pragma unroll 2
  for (int k0 = kbase; k0 < kbase + 256; k0 += 32) {
    bf16x8 kf[2][2];
#pragma unroll
    for (int u = 0; u < 2; ++u)
#pragma unroll
      for (int h = 0; h < 2; ++h)
        kf[u][h] = *reinterpret_cast<const bf16x8*>(Kp + (size_t)(k0 + u * 16 + lr) * DKd + h * 32 + lg * 8);

    __builtin_amdgcn_s_setprio(1);
#pragma unroll
    for (int t = 0; t < 2; ++t) {
      const int Qt = qb + t * 16;
      f32x4 st[2];
#pragma unroll
      for (int u = 0; u < 2; ++u) {
        f32x4 a = {};
        a = __builtin_amdgcn_mfma_f32_16x16x32_bf16(kf[u][0], qf[t][0], a, 0, 0, 0);
        a = __builtin_amdgcn_mfma_f32_16x16x32_bf16(kf[u][1], qf[t][1], a, 0, 0, 0);
        st[u] = a;  // element: q = Qt+lr (col), k = k0+u*16+lg*4+r (row)
      }
      float p[2][4];
      if (k0 + 131 <= Qt) {            // whole step below band: pos = pls[q][0]
#pragma unroll
        for (int u = 0; u < 2; ++u)
#pragma unroll
          for (int r = 0; r < 4; ++r)
            p[u][r] = fexp2(fmaf(st[u][r], POS_C, pe0[t]));
      } else if (k0 >= Qt + 115) {     // whole step above band: pos = pls[q][200]
#pragma unroll
        for (int u = 0; u < 2; ++u)
#pragma unroll
          for (int r = 0; r < 4; ++r)
            p[u][r] = fexp2(fmaf(st[u][r], POS_C, pe200[t]));
      } else {                         // in-band: clamped gather from LDS
#pragma unroll
        for (int u = 0; u < 2; ++u) {
          const int jb = k0 + u * 16 + 100 - Qt + ldelta;
#pragma unroll
          for (int r = 0; r < 4; ++r) {
            int j = jb + r;
            j = j < 0 ? 0 : (j > 200 ? 200 : j);
            p[u][r] = fexp2(fmaf(st[u][r], POS_C, b2f(prow[t][j])));
          }
        }
      }
#pragma unroll
      for (int u = 0; u < 2; ++u)
#pragma unroll
        for (int r = 0; r < 4; ++r) psum[t] += p[u][r];
      // pack to bf16, wave-private LDS transpose (D-layout -> B-frag layout)
#pragma unroll
      for (int u = 0; u < 2; ++u) {
        uint2 pk;
        pk.x = pack2(p[u][0], p[u][1]);
        pk.y = pack2(p[u][2], p[u][3]);
        *reinterpret_cast<uint2*>(&Pw[t * 320 + lr * 20 + u * 8 + lg * 2]) = pk;
      }
    }
    // PV: A = Vt fragment, B = P fragment read back from LDS
    bf16x8 pb[2];
#pragma unroll
    for (int t = 0; t < 2; ++t)
      pb[t] = *reinterpret_cast<const bf16x8*>(&Pw[t * 320 + lr * 20 + lg * 4]);
#pragma unroll
    for (int f = 0; f < 4; ++f) {
      bf16x8 vf = *reinterpret_cast<const bf16x8*>(Vp + (size_t)(f * 16 + lr) * Lseq + k0 + lg * 8);
#pragma unroll
      for (int t = 0; t < 2; ++t)
        Oacc[t][f] = __builtin_amdgcn_mfma_f32_16x16x32_bf16(vf, pb[t], Oacc[t][f], 0, 0, 0);
    }
    __builtin_amdgcn_s_setprio(0);
  }

  // ---- merge the four k-quarters (no-max partials combine by pure addition) --
  __syncthreads();   // k-loops done; pos+Pl dead -> reuse smem as Ml[3][64][34]
  float* Ml = smemf;
  if (wv) {
    float* m = Ml + ((wv - 1) * 64 + lane) * 34;
#pragma unroll
    for (int t = 0; t < 2; ++t)
#pragma unroll
      for (int f = 0; f < 4; ++f)
#pragma unroll
        for (int r = 0; r < 4; ++r) m[t * 16 + f * 4 + r] = Oacc[t][f][r];
    m[32] = psum[0];
    m[33] = psum[1];
  }
  __syncthreads();
  if (!wv) {
#pragma unroll
    for (int w2 = 0; w2 < 3; ++w2) {
      const float* m = Ml + (w2 * 64 + lane) * 34;
#pragma unroll
      for (int t = 0; t < 2; ++t) {
#pragma unroll
        for (int f = 0; f < 4; ++f)
#pragma unroll
          for (int r = 0; r < 4; ++r) Oacc[t][f][r] += m[t * 16 + f * 4 + r];
        psum[t] += m[32 + t];
      }
    }
    const int gb = bh >> 3, hh = bh & 7;
#pragma unroll
    for (int t = 0; t < 2; ++t) {
      float s = psum[t];
      s += __shfl_xor(s, 16);
      s += __shfl_xor(s, 32);
      const float inv = 1.0f / s;
      const int qg = qb + t * 16 + lr;
#pragma unroll
      for (int f = 0; f < 4; ++f) {
        uint2 ov;
        ov.x = pack2(Oacc[t][f][0] * inv, Oacc[t][f][1] * inv);
        ov.y = pack2(Oacc[t][f][2] * inv, Oacc[t][f][3] * inv);
        *reinterpret_cast<uint2*>(attnb + ((size_t)(gb * Lseq + qg)) * Dm + hh * DKd + f * 16 + lg * 4) = ov;
      }
    }
  }
}

// ---------------- row LayerNorm over D=512, bf16 input ------------------------
__global__ __launch_bounds__(256) void k_ln(const bf16_t* __restrict__ y,
                                            const float* __restrict__ g,
                                            const float* __restrict__ be,
                                            float* __restrict__ out) {
  const int row = blockIdx.x * 4 + (threadIdx.x >> 6);
  const int lane = threadIdx.x & 63;
  bf16x8 rv = *reinterpret_cast<const bf16x8*>(y + (size_t)row * Dm + lane * 8);
  float vv[8];
#pragma unroll
  for (int j = 0; j < 8; ++j) vv[j] = (float)rv[j];
  float s = 0.f, s2 = 0.f;
#pragma unroll
  for (int j = 0; j < 8; ++j) { s += vv[j]; s2 += vv[j] * vv[j]; }
  for (int mk = 1; mk < 64; mk <<= 1) {
    s += __shfl_xor(s, mk, 64);
    s2 += __shfl_xor(s2, mk, 64);
  }
  const float mu = s * (1.0f / Dm);
  const float var = s2 * (1.0f / Dm) - mu * mu;
  const float inv = rsqrtf(var + 1e-6f);
  float* op = out + (size_t)row * Dm + lane * 8;
  const float* gp = g + lane * 8;
  const float* bp = be + lane * 8;
#pragma unroll
  for (int j = 0; j < 8; ++j) op[j] = (vv[j] - mu) * inv * gp[j] + bp[j];
}

// ------------------------------------------------------------------------------
extern "C" void kernel_launch(void* const* d_in, const int* in_sizes, int n_in,
                              void* d_out, int out_size, void* d_ws, size_t ws_size,
                              hipStream_t stream) {
  const float* q   = (const float*)d_in[0];
  const float* k   = (const float*)d_in[1];
  const float* v   = (const float*)d_in[2];
  const float* Wq  = (const float*)d_in[3];
  const float* Wk  = (const float*)d_in[4];
  const float* Wv  = (const float*)d_in[5];
  const float* Wfc = (const float*)d_in[6];
  const float* rel = (const float*)d_in[7];
  const float* gam = (const float*)d_in[8];
  const float* bet = (const float*)d_in[9];

  char* ws = (char*)d_ws;
  size_t off = 0;
  auto take = [&](size_t bytes) {
    char* p = ws + off;
    off += (bytes + 255) & ~(size_t)255;
    return p;
  };
  // NOTE: wqb/wkb/wvb contiguous, qb/kb/vb contiguous, Qhp/Khp/Vtp contiguous —
  // required by the z-merged projection launch (pure offset arithmetic).
  bf16_t* wqb  = (bf16_t*)take((size_t)Dm * Dm * 2);
  bf16_t* wkb  = (bf16_t*)take((size_t)Dm * Dm * 2);
  bf16_t* wvb  = (bf16_t*)take((size_t)Dm * Dm * 2);
  bf16_t* wfcb = (bf16_t*)take((size_t)Dm * Dm * 2);
  bf16_t* relb = (bf16_t*)take((size_t)NREL * DKd * 2);
  bf16_t* qb   = (bf16_t*)take((size_t)MTOK * Dm * 2);
  bf16_t* kb   = (bf16_t*)take((size_t)MTOK * Dm * 2);
  bf16_t* vb   = (bf16_t*)take((size_t)MTOK * Dm * 2);
  bf16_t* Qhp  = (bf16_t*)take((size_t)MTOK * Dm * 2);
  bf16_t* Khp  = (bf16_t*)take((size_t)MTOK * Dm * 2);
  bf16_t* Vtp  = (bf16_t*)take((size_t)MTOK * Dm * 2);
  bf16_t* attnb= (bf16_t*)take((size_t)MTOK * Dm * 2);
  bf16_t* yb   = (bf16_t*)take((size_t)MTOK * Dm * 2);

  // 1) ALL casts (q/k/v + 4 weights + rel) in one launch
  k_cast_all<<<dim3(2048, 4), 256, 0, stream>>>(
      q, k, v, Wq, Wk, Wv, Wfc, rel, qb, kb, vb, wqb, wkb, wvb, wfcb, relb);
  // 2) ALL projections (Q,K,V) in one z=3 launch
  k_proj3<<<dim3(Dm / 64, MTOK / 64, 3), 256, 0, stream>>>(qb, wqb, Qhp);
  // 3) attention (posdot fused in-block; stable 84us)
  k_attn<<<dim3(2048), 256, 0, stream>>>(Qhp, Khp, Vtp, relb, attnb);
  // 4) output GEMM + residual (bf16 yb)
  k_fc<<<dim3(Dm / 64, MTOK / 64), 256, 0, stream>>>(attnb, wfcb, yb, q);
  // 5) LayerNorm (bf16 input)
  k_ln<<<dim3(MTOK / 4), 256, 0, stream>>>(yb, gam, bet, (float*)d_out);
}

// Round 24
// 220.208 us; speedup vs baseline: 1.1486x; 1.0155x over previous
//
#include <hip/hip_runtime.h>
#include <hip/hip_bf16.h>

typedef __bf16 bf16_t;
typedef __bf16 bf16x8 __attribute__((ext_vector_type(8)));
typedef float f32x4 __attribute__((ext_vector_type(4)));

constexpr int Bz = 8, Lseq = 1024, Dm = 512, Hh = 8, DKd = 64;
constexpr int MTOK = Bz * Lseq;   // 8192 tokens
constexpr int NREL = 201;
constexpr int PROW = 202;         // padded LDS row (bank stride 101%32=5, coprime)

// pos pre-scale: 0.125 (1/sqrt(dk)) * log2(e), folded so p = exp2(st*C + pos)
#define POS_C 0.18033688011112042f

__device__ inline float fexp2(float x) {
#if __has_builtin(__builtin_amdgcn_exp2f)
  return __builtin_amdgcn_exp2f(x);
#else
  return exp2f(x);
#endif
}
__device__ inline float b2f(unsigned short u) {
  return __builtin_bit_cast(float, (unsigned)u << 16);
}
__device__ inline unsigned pack2(float a, float b) {
  unsigned short ua = __builtin_bit_cast(unsigned short, (bf16_t)a);
  unsigned short ub = __builtin_bit_cast(unsigned short, (bf16_t)b);
  return (unsigned)ua | ((unsigned)ub << 16);
}

// ---------------- ONE launch for ALL casts ------------------------------------
__global__ __launch_bounds__(256) void k_cast_all(
    const float* __restrict__ q, const float* __restrict__ k,
    const float* __restrict__ v, const float* __restrict__ w0,
    const float* __restrict__ w1, const float* __restrict__ w2,
    const float* __restrict__ w3, const float* __restrict__ rel,
    bf16_t* __restrict__ qb, bf16_t* __restrict__ kb, bf16_t* __restrict__ vb,
    bf16_t* __restrict__ d0, bf16_t* __restrict__ d1, bf16_t* __restrict__ d2,
    bf16_t* __restrict__ d3, bf16_t* __restrict__ drel) {
  const int y = blockIdx.y;
  if (y < 3) {
    const float* s = y == 0 ? q : y == 1 ? k : v;
    bf16_t* d = y == 0 ? qb : y == 1 ? kb : vb;
    const int i = (blockIdx.x * 256 + threadIdx.x) * 8;
    float4 a = *reinterpret_cast<const float4*>(s + i);
    float4 b = *reinterpret_cast<const float4*>(s + i + 4);
    bf16x8 r;
    r[0] = (bf16_t)a.x; r[1] = (bf16_t)a.y; r[2] = (bf16_t)a.z; r[3] = (bf16_t)a.w;
    r[4] = (bf16_t)b.x; r[5] = (bf16_t)b.y; r[6] = (bf16_t)b.z; r[7] = (bf16_t)b.w;
    *reinterpret_cast<bf16x8*>(d + i) = r;
  } else {
    const int x = blockIdx.x;
    if (x < 1024) {
      const int wsel = x >> 8;
      const float* s = wsel == 0 ? w0 : wsel == 1 ? w1 : wsel == 2 ? w2 : w3;
      bf16_t* d = wsel == 0 ? d0 : wsel == 1 ? d1 : wsel == 2 ? d2 : d3;
      const int i = ((x & 255) * 256 + threadIdx.x) * 4;
      float4 vv = *reinterpret_cast<const float4*>(s + i);
      d[i + 0] = (bf16_t)vv.x;
      d[i + 1] = (bf16_t)vv.y;
      d[i + 2] = (bf16_t)vv.z;
      d[i + 3] = (bf16_t)vv.w;
    } else if (x < 1037) {
      const int i = ((x - 1024) * 256 + threadIdx.x) * 4;
      if (i < NREL * DKd) {
        float4 vv = *reinterpret_cast<const float4*>(rel + i);
        drel[i + 0] = (bf16_t)vv.x;
        drel[i + 1] = (bf16_t)vv.y;
        drel[i + 2] = (bf16_t)vv.z;
        drel[i + 3] = (bf16_t)vv.w;
      }
    }
  }
}

// ---------------- Q+K projections (z=2, offsets), 2-deep k-prefetch -----------
__global__ __launch_bounds__(256) void k_projQK(const bf16_t* __restrict__ A,
                                                const bf16_t* __restrict__ W,
                                                bf16_t* __restrict__ outb) {
  const int lane = threadIdx.x & 63, w = threadIdx.x >> 6;
  const int lr = lane & 15, lg = lane >> 4;
  const size_t zo = (size_t)blockIdx.z * ((size_t)MTOK * Dm);
  A += zo;
  W += (size_t)blockIdx.z * ((size_t)Dm * Dm);
  outb += zo;
  // bijective chunked XCD swizzle (nwg=1024, chunk=128)
  const int orig = blockIdx.x + blockIdx.y * 8;
  const int swz = ((orig & 7) << 7) | (orig >> 3);
  const int Rbase = (swz >> 3) * 64 + (w >> 1) * 32;
  const int Cbase = (swz & 7) * 64 + (w & 1) * 32;

  f32x4 acc[2][2] = {};
  bf16x8 afA[2], wfA[2], afB[2], wfB[2];
  auto loadF = [&](bf16x8 (&af)[2], bf16x8 (&wf)[2], int k0) {
#pragma unroll
    for (int i = 0; i < 2; ++i)
      af[i] = *reinterpret_cast<const bf16x8*>(A + (size_t)(Rbase + i * 16 + lr) * Dm + k0 + lg * 8);
#pragma unroll
    for (int j = 0; j < 2; ++j)
      wf[j] = *reinterpret_cast<const bf16x8*>(W + (size_t)(Cbase + j * 16 + lr) * Dm + k0 + lg * 8);
  };
  auto domfma = [&](const bf16x8 (&af)[2], const bf16x8 (&wf)[2]) {
#pragma unroll
    for (int i = 0; i < 2; ++i)
#pragma unroll
      for (int j = 0; j < 2; ++j)
        acc[i][j] = __builtin_amdgcn_mfma_f32_16x16x32_bf16(af[i], wf[j], acc[i][j], 0, 0, 0);
  };
  loadF(afA, wfA, 0);
#pragma unroll
  for (int k0 = 0; k0 < Dm; k0 += 64) {
    loadF(afB, wfB, k0 + 32);
    domfma(afA, wfA);
    if (k0 + 64 < Dm) loadF(afA, wfA, k0 + 64);
    domfma(afB, wfB);
  }
#pragma unroll
  for (int i = 0; i < 2; ++i)
#pragma unroll
    for (int j = 0; j < 2; ++j)
#pragma unroll
      for (int r = 0; r < 4; ++r) {
        const int gr = Rbase + i * 16 + lg * 4 + r;  // token row
        const int gc = Cbase + j * 16 + lr;          // output col
        const int bb = gr >> 10, qq = gr & 1023, hh = gc >> 6, dd = gc & 63;
        outb[(((size_t)(bb * Hh + hh)) * Lseq + qq) * DKd + dd] = (bf16_t)acc[i][j][r];
      }
}

// ---------------- V projection: prefetch + LDS-transpose epilogue -------------
// Old MODE-1 store scattered 2B writes at 2KB lane stride (64 lines/instr).
// Now: stage 64x64 tile in LDS[dd][qq] (pad 72 -> 16B-aligned rows), then 256
// threads store contiguous 32B each (2x bf16x8) into Vt[dd][qq] layout.
__global__ __launch_bounds__(256) void k_projV(const bf16_t* __restrict__ A,
                                               const bf16_t* __restrict__ W,
                                               bf16_t* __restrict__ outb) {
  __shared__ bf16_t Vl[64][72];
  const int lane = threadIdx.x & 63, w = threadIdx.x >> 6;
  const int lr = lane & 15, lg = lane >> 4;
  // bijective chunked XCD swizzle (nwg=1024, chunk=128)
  const int orig = blockIdx.x + blockIdx.y * 8;
  const int swz = ((orig & 7) << 7) | (orig >> 3);
  const int Rtile = (swz >> 3) * 64;
  const int Rbase = Rtile + (w >> 1) * 32;
  const int Cbase = (swz & 7) * 64 + (w & 1) * 32;

  f32x4 acc[2][2] = {};
  bf16x8 afA[2], wfA[2], afB[2], wfB[2];
  auto loadF = [&](bf16x8 (&af)[2], bf16x8 (&wf)[2], int k0) {
#pragma unroll
    for (int i = 0; i < 2; ++i)
      af[i] = *reinterpret_cast<const bf16x8*>(A + (size_t)(Rbase + i * 16 + lr) * Dm + k0 + lg * 8);
#pragma unroll
    for (int j = 0; j < 2; ++j)
      wf[j] = *reinterpret_cast<const bf16x8*>(W + (size_t)(Cbase + j * 16 + lr) * Dm + k0 + lg * 8);
  };
  auto domfma = [&](const bf16x8 (&af)[2], const bf16x8 (&wf)[2]) {
#pragma unroll
    for (int i = 0; i < 2; ++i)
#pragma unroll
      for (int j = 0; j < 2; ++j)
        acc[i][j] = __builtin_amdgcn_mfma_f32_16x16x32_bf16(af[i], wf[j], acc[i][j], 0, 0, 0);
  };
  loadF(afA, wfA, 0);
#pragma unroll
  for (int k0 = 0; k0 < Dm; k0 += 64) {
    loadF(afB, wfB, k0 + 32);
    domfma(afA, wfA);
    if (k0 + 64 < Dm) loadF(afA, wfA, k0 + 64);
    domfma(afB, wfB);
  }
  // stage tile transposed into LDS: Vl[dd_local][qq_local]
#pragma unroll
  for (int i = 0; i < 2; ++i)
#pragma unroll
    for (int j = 0; j < 2; ++j)
#pragma unroll
      for (int r = 0; r < 4; ++r) {
        const int grl = (w >> 1) * 32 + i * 16 + lg * 4 + r;  // qq local
        const int gcl = (w & 1) * 32 + j * 16 + lr;           // dd local
        Vl[gcl][grl] = (bf16_t)acc[i][j][r];
      }
  __syncthreads();
  // cooperative coalesced store: thread -> (dd = tid/4, 16-qq chunk)
  const int tid = threadIdx.x;
  const int dd = tid >> 2, qq0 = (tid & 3) * 16;
  const int bb = Rtile >> 10, qrow = Rtile & 1023, hh = swz & 7;
  bf16_t* dst = outb + (((size_t)(bb * Hh + hh)) * DKd + dd) * Lseq + qrow + qq0;
  *reinterpret_cast<bf16x8*>(dst) = *reinterpret_cast<const bf16x8*>(&Vl[dd][qq0]);
  *reinterpret_cast<bf16x8*>(dst + 8) = *reinterpret_cast<const bf16x8*>(&Vl[dd][qq0 + 8]);
}

// ---------------- fc GEMM: yb = bf16(attnb @ Wfc^T + resid) -------------------
__global__ __launch_bounds__(256) void k_fc(const bf16_t* __restrict__ A,
                                            const bf16_t* __restrict__ W,
                                            bf16_t* __restrict__ yb,
                                            const float* __restrict__ resid) {
  const int lane = threadIdx.x & 63, w = threadIdx.x >> 6;
  const int lr = lane & 15, lg = lane >> 4;
  // bijective chunked XCD swizzle (nwg=1024, chunk=128)
  const int orig = blockIdx.x + blockIdx.y * 8;
  const int swz = ((orig & 7) << 7) | (orig >> 3);
  const int Rbase = (swz >> 3) * 64 + (w >> 1) * 32;
  const int Cbase = (swz & 7) * 64 + (w & 1) * 32;

  f32x4 acc[2][2] = {};
  for (int k0 = 0; k0 < Dm; k0 += 32) {
    bf16x8 af[2], wf[2];
#pragma unroll
    for (int i = 0; i < 2; ++i)
      af[i] = *reinterpret_cast<const bf16x8*>(A + (size_t)(Rbase + i * 16 + lr) * Dm + k0 + lg * 8);
#pragma unroll
    for (int j = 0; j < 2; ++j)
      wf[j] = *reinterpret_cast<const bf16x8*>(W + (size_t)(Cbase + j * 16 + lr) * Dm + k0 + lg * 8);
#pragma unroll
    for (int i = 0; i < 2; ++i)
#pragma unroll
      for (int j = 0; j < 2; ++j)
        acc[i][j] = __builtin_amdgcn_mfma_f32_16x16x32_bf16(af[i], wf[j], acc[i][j], 0, 0, 0);
  }
#pragma unroll
  for (int i = 0; i < 2; ++i)
#pragma unroll
    for (int j = 0; j < 2; ++j)
#pragma unroll
      for (int r = 0; r < 4; ++r) {
        const int gr = Rbase + i * 16 + lg * 4 + r;
        const int gc = Cbase + j * 16 + lr;
        const size_t idx = (size_t)gr * Dm + gc;
        yb[idx] = (bf16_t)(acc[i][j][r] + resid[idx]);
      }
}

// ---------------- flash attention + fused in-block posdot (84us, stable) ------
__global__ __launch_bounds__(256, 4) void k_attn(const bf16_t* __restrict__ Qh,
                                                 const bf16_t* __restrict__ Kh,
                                                 const bf16_t* __restrict__ Vt,
                                                 const bf16_t* __restrict__ relb,
                                                 bf16_t* __restrict__ attnb) {
  __shared__ float smemf[6528];   // pos 12928B + Pl 10240B = 23168B; Ml 26112B

  const int tid = threadIdx.x;
  const int wv = tid >> 6, lane = tid & 63;
  const int lr = lane & 15, lg = lane >> 4;
  // bijective chunked XCD swizzle (nwg=2048, chunk=256)
  const int gid = ((blockIdx.x & 7) << 8) | (blockIdx.x >> 3);
  const int bh = gid >> 5;
  const int qb = (gid & 31) << 5;             // 32-row q tile

  unsigned short* pls = reinterpret_cast<unsigned short*>(smemf);     // [32][202]
  unsigned* Pw = reinterpret_cast<unsigned*>(smemf) + 3232 + wv * 640; // [2][16][20]

  const bf16_t* Qp = Qh + ((size_t)bh * Lseq + qb) * DKd;
  const bf16_t* Kp = Kh + (size_t)bh * Lseq * DKd;
  const bf16_t* Vp = Vt + (size_t)bh * DKd * Lseq;

  // Q fragments (dual-use: B-operand for swapped QK^T, A-operand for posdot)
  bf16x8 qf[2][2];
#pragma unroll
  for (int t = 0; t < 2; ++t)
#pragma unroll
    for (int h = 0; h < 2; ++h)
      qf[t][h] = *reinterpret_cast<const bf16x8*>(Qp + (size_t)(t * 16 + lr) * DKd + h * 32 + lg * 8);

  // ---- in-block posdot: pls[q][200-r] = POS_C * dot(Q[q], rel[r]) -----------
  for (int n = wv; n < 13; n += 4) {
    const int rr0 = n * 16 + lr;
    const int rclamp = rr0 > 200 ? 200 : rr0;
    bf16x8 rf0 = *reinterpret_cast<const bf16x8*>(relb + (size_t)rclamp * DKd + lg * 8);
    bf16x8 rf1 = *reinterpret_cast<const bf16x8*>(relb + (size_t)rclamp * DKd + 32 + lg * 8);
#pragma unroll
    for (int t = 0; t < 2; ++t) {
      f32x4 st = {};
      st = __builtin_amdgcn_mfma_f32_16x16x32_bf16(qf[t][0], rf0, st, 0, 0, 0);
      st = __builtin_amdgcn_mfma_f32_16x16x32_bf16(qf[t][1], rf1, st, 0, 0, 0);
      if (rr0 <= 200) {
#pragma unroll
        for (int r = 0; r < 4; ++r)
          pls[(t * 16 + lg * 4 + r) * PROW + (200 - rr0)] =
              __builtin_bit_cast(unsigned short, (bf16_t)(st[r] * POS_C));
      }
    }
  }
  __syncthreads();

  // per-lane pos row bases + band-edge constants (already scaled by POS_C)
  const unsigned short* prow[2] = {pls + (size_t)lr * PROW,
                                   pls + (size_t)(16 + lr) * PROW};
  float pe0[2], pe200[2];
#pragma unroll
  for (int t = 0; t < 2; ++t) {
    pe0[t] = b2f(prow[t][0]);       // k <= q-100 side
    pe200[t] = b2f(prow[t][200]);   // k >= q+100 side
  }

  f32x4 Oacc[2][4] = {};
  float psum[2] = {0.f, 0.f};
  const int ldelta = lg * 4 - lr;

  const int kbase = wv * 256;
#pragma unroll 2
  for (int k0 = kbase; k0 < kbase + 256; k0 += 32) {
    bf16x8 kf[2][2];
#pragma unroll
    for (int u = 0; u < 2; ++u)
#pragma unroll
      for (int h = 0; h < 2; ++h)
        kf[u][h] = *reinterpret_cast<const bf16x8*>(Kp + (size_t)(k0 + u * 16 + lr) * DKd + h * 32 + lg * 8);

    __builtin_amdgcn_s_setprio(1);
#pragma unroll
    for (int t = 0; t < 2; ++t) {
      const int Qt = qb + t * 16;
      f32x4 st[2];
#pragma unroll
      for (int u = 0; u < 2; ++u) {
        f32x4 a = {};
        a = __builtin_amdgcn_mfma_f32_16x16x32_bf16(kf[u][0], qf[t][0], a, 0, 0, 0);
        a = __builtin_amdgcn_mfma_f32_16x16x32_bf16(kf[u][1], qf[t][1], a, 0, 0, 0);
        st[u] = a;  // element: q = Qt+lr (col), k = k0+u*16+lg*4+r (row)
      }
      float p[2][4];
      if (k0 + 131 <= Qt) {            // whole step below band: pos = pls[q][0]
#pragma unroll
        for (int u = 0; u < 2; ++u)
#pragma unroll
          for (int r = 0; r < 4; ++r)
            p[u][r] = fexp2(fmaf(st[u][r], POS_C, pe0[t]));
      } else if (k0 >= Qt + 115) {     // whole step above band: pos = pls[q][200]
#pragma unroll
        for (int u = 0; u < 2; ++u)
#pragma unroll
          for (int r = 0; r < 4; ++r)
            p[u][r] = fexp2(fmaf(st[u][r], POS_C, pe200[t]));
      } else {                         // in-band: clamped gather from LDS
#pragma unroll
        for (int u = 0; u < 2; ++u) {
          const int jb = k0 + u * 16 + 100 - Qt + ldelta;
#pragma unroll
          for (int r = 0; r < 4; ++r) {
            int j = jb + r;
            j = j < 0 ? 0 : (j > 200 ? 200 : j);
            p[u][r] = fexp2(fmaf(st[u][r], POS_C, b2f(prow[t][j])));
          }
        }
      }
#pragma unroll
      for (int u = 0; u < 2; ++u)
#pragma unroll
        for (int r = 0; r < 4; ++r) psum[t] += p[u][r];
      // pack to bf16, wave-private LDS transpose (D-layout -> B-frag layout)
#pragma unroll
      for (int u = 0; u < 2; ++u) {
        uint2 pk;
        pk.x = pack2(p[u][0], p[u][1]);
        pk.y = pack2(p[u][2], p[u][3]);
        *reinterpret_cast<uint2*>(&Pw[t * 320 + lr * 20 + u * 8 + lg * 2]) = pk;
      }
    }
    // PV: A = Vt fragment, B = P fragment read back from LDS
    bf16x8 pb[2];
#pragma unroll
    for (int t = 0; t < 2; ++t)
      pb[t] = *reinterpret_cast<const bf16x8*>(&Pw[t * 320 + lr * 20 + lg * 4]);
#pragma unroll
    for (int f = 0; f < 4; ++f) {
      bf16x8 vf = *reinterpret_cast<const bf16x8*>(Vp + (size_t)(f * 16 + lr) * Lseq + k0 + lg * 8);
#pragma unroll
      for (int t = 0; t < 2; ++t)
        Oacc[t][f] = __builtin_amdgcn_mfma_f32_16x16x32_bf16(vf, pb[t], Oacc[t][f], 0, 0, 0);
    }
    __builtin_amdgcn_s_setprio(0);
  }

  // ---- merge the four k-quarters (no-max partials combine by pure addition) --
  __syncthreads();   // k-loops done; pos+Pl dead -> reuse smem as Ml[3][64][34]
  float* Ml = smemf;
  if (wv) {
    float* m = Ml + ((wv - 1) * 64 + lane) * 34;
#pragma unroll
    for (int t = 0; t < 2; ++t)
#pragma unroll
      for (int f = 0; f < 4; ++f)
#pragma unroll
        for (int r = 0; r < 4; ++r) m[t * 16 + f * 4 + r] = Oacc[t][f][r];
    m[32] = psum[0];
    m[33] = psum[1];
  }
  __syncthreads();
  if (!wv) {
#pragma unroll
    for (int w2 = 0; w2 < 3; ++w2) {
      const float* m = Ml + (w2 * 64 + lane) * 34;
#pragma unroll
      for (int t = 0; t < 2; ++t) {
#pragma unroll
        for (int f = 0; f < 4; ++f)
#pragma unroll
          for (int r = 0; r < 4; ++r) Oacc[t][f][r] += m[t * 16 + f * 4 + r];
        psum[t] += m[32 + t];
      }
    }
    const int gb = bh >> 3, hh = bh & 7;
#pragma unroll
    for (int t = 0; t < 2; ++t) {
      float s = psum[t];
      s += __shfl_xor(s, 16);
      s += __shfl_xor(s, 32);
      const float inv = 1.0f / s;
      const int qg = qb + t * 16 + lr;
#pragma unroll
      for (int f = 0; f < 4; ++f) {
        uint2 ov;
        ov.x = pack2(Oacc[t][f][0] * inv, Oacc[t][f][1] * inv);
        ov.y = pack2(Oacc[t][f][2] * inv, Oacc[t][f][3] * inv);
        *reinterpret_cast<uint2*>(attnb + ((size_t)(gb * Lseq + qg)) * Dm + hh * DKd + f * 16 + lg * 4) = ov;
      }
    }
  }
}

// ---------------- row LayerNorm over D=512, bf16 input ------------------------
__global__ __launch_bounds__(256) void k_ln(const bf16_t* __restrict__ y,
                                            const float* __restrict__ g,
                                            const float* __restrict__ be,
                                            float* __restrict__ out) {
  const int row = blockIdx.x * 4 + (threadIdx.x >> 6);
  const int lane = threadIdx.x & 63;
  bf16x8 rv = *reinterpret_cast<const bf16x8*>(y + (size_t)row * Dm + lane * 8);
  float vv[8];
#pragma unroll
  for (int j = 0; j < 8; ++j) vv[j] = (float)rv[j];
  float s = 0.f, s2 = 0.f;
#pragma unroll
  for (int j = 0; j < 8; ++j) { s += vv[j]; s2 += vv[j] * vv[j]; }
  for (int mk = 1; mk < 64; mk <<= 1) {
    s += __shfl_xor(s, mk, 64);
    s2 += __shfl_xor(s2, mk, 64);
  }
  const float mu = s * (1.0f / Dm);
  const float var = s2 * (1.0f / Dm) - mu * mu;
  const float inv = rsqrtf(var + 1e-6f);
  float* op = out + (size_t)row * Dm + lane * 8;
  const float* gp = g + lane * 8;
  const float* bp = be + lane * 8;
#pragma unroll
  for (int j = 0; j < 8; ++j) op[j] = (vv[j] - mu) * inv * gp[j] + bp[j];
}

// ------------------------------------------------------------------------------
extern "C" void kernel_launch(void* const* d_in, const int* in_sizes, int n_in,
                              void* d_out, int out_size, void* d_ws, size_t ws_size,
                              hipStream_t stream) {
  const float* q   = (const float*)d_in[0];
  const float* k   = (const float*)d_in[1];
  const float* v   = (const float*)d_in[2];
  const float* Wq  = (const float*)d_in[3];
  const float* Wk  = (const float*)d_in[4];
  const float* Wv  = (const float*)d_in[5];
  const float* Wfc = (const float*)d_in[6];
  const float* rel = (const float*)d_in[7];
  const float* gam = (const float*)d_in[8];
  const float* bet = (const float*)d_in[9];

  char* ws = (char*)d_ws;
  size_t off = 0;
  auto take = [&](size_t bytes) {
    char* p = ws + off;
    off += (bytes + 255) & ~(size_t)255;
    return p;
  };
  // NOTE: wqb/wkb contiguous, qb/kb contiguous, Qhp/Khp contiguous —
  // required by the z=2 Q+K projection launch (pure offset arithmetic).
  bf16_t* wqb  = (bf16_t*)take((size_t)Dm * Dm * 2);
  bf16_t* wkb  = (bf16_t*)take((size_t)Dm * Dm * 2);
  bf16_t* wvb  = (bf16_t*)take((size_t)Dm * Dm * 2);
  bf16_t* wfcb = (bf16_t*)take((size_t)Dm * Dm * 2);
  bf16_t* relb = (bf16_t*)take((size_t)NREL * DKd * 2);
  bf16_t* qb   = (bf16_t*)take((size_t)MTOK * Dm * 2);
  bf16_t* kb   = (bf16_t*)take((size_t)MTOK * Dm * 2);
  bf16_t* vb   = (bf16_t*)take((size_t)MTOK * Dm * 2);
  bf16_t* Qhp  = (bf16_t*)take((size_t)MTOK * Dm * 2);
  bf16_t* Khp  = (bf16_t*)take((size_t)MTOK * Dm * 2);
  bf16_t* Vtp  = (bf16_t*)take((size_t)MTOK * Dm * 2);
  bf16_t* attnb= (bf16_t*)take((size_t)MTOK * Dm * 2);
  bf16_t* yb   = (bf16_t*)take((size_t)MTOK * Dm * 2);

  // 1) ALL casts (q/k/v + 4 weights + rel) in one launch
  k_cast_all<<<dim3(2048, 4), 256, 0, stream>>>(
      q, k, v, Wq, Wk, Wv, Wfc, rel, qb, kb, vb, wqb, wkb, wvb, wfcb, relb);
  // 2) Q+K projections (z=2, prefetch)
  k_projQK<<<dim3(8, 128, 2), 256, 0, stream>>>(qb, wqb, Qhp);
  // 3) V projection (prefetch + LDS-transpose coalesced store)
  k_projV<<<dim3(8, 128), 256, 0, stream>>>(vb, wvb, Vtp);
  // 4) attention (posdot fused in-block; stable 84us)
  k_attn<<<dim3(2048), 256, 0, stream>>>(Qhp, Khp, Vtp, relb, attnb);
  // 5) output GEMM + residual (bf16 yb)
  k_fc<<<dim3(8, 128), 256, 0, stream>>>(attnb, wfcb, yb, q);
  // 6) LayerNorm (bf16 input)
  k_ln<<<dim3(MTOK / 4), 256, 0, stream>>>(yb, gam, bet, (float*)d_out);
}

// Round 25
// 209.246 us; speedup vs baseline: 1.2088x; 1.0524x over previous
//
#include <hip/hip_runtime.h>
#include <hip/hip_bf16.h>

typedef __bf16 bf16_t;
typedef __bf16 bf16x8 __attribute__((ext_vector_type(8)));
typedef float f32x4 __attribute__((ext_vector_type(4)));

constexpr int Bz = 8, Lseq = 1024, Dm = 512, Hh = 8, DKd = 64;
constexpr int MTOK = Bz * Lseq;   // 8192 tokens
constexpr int NREL = 201;
constexpr int PROW = 202;         // padded LDS row (bank stride 101%32=5, coprime)

// pos pre-scale: 0.125 (1/sqrt(dk)) * log2(e), folded so p = exp2(st*C + pos)
#define POS_C 0.18033688011112042f

__device__ inline float fexp2(float x) {
#if __has_builtin(__builtin_amdgcn_exp2f)
  return __builtin_amdgcn_exp2f(x);
#else
  return exp2f(x);
#endif
}
__device__ inline float b2f(unsigned short u) {
  return __builtin_bit_cast(float, (unsigned)u << 16);
}
__device__ inline unsigned pack2(float a, float b) {
  unsigned short ua = __builtin_bit_cast(unsigned short, (bf16_t)a);
  unsigned short ub = __builtin_bit_cast(unsigned short, (bf16_t)b);
  return (unsigned)ua | ((unsigned)ub << 16);
}

// ---------------- ONE launch for ALL casts ------------------------------------
__global__ __launch_bounds__(256) void k_cast_all(
    const float* __restrict__ q, const float* __restrict__ k,
    const float* __restrict__ v, const float* __restrict__ w0,
    const float* __restrict__ w1, const float* __restrict__ w2,
    const float* __restrict__ w3, const float* __restrict__ rel,
    bf16_t* __restrict__ qb, bf16_t* __restrict__ kb, bf16_t* __restrict__ vb,
    bf16_t* __restrict__ d0, bf16_t* __restrict__ d1, bf16_t* __restrict__ d2,
    bf16_t* __restrict__ d3, bf16_t* __restrict__ drel) {
  const int y = blockIdx.y;
  if (y < 3) {
    const float* s = y == 0 ? q : y == 1 ? k : v;
    bf16_t* d = y == 0 ? qb : y == 1 ? kb : vb;
    const int i = (blockIdx.x * 256 + threadIdx.x) * 8;
    float4 a = *reinterpret_cast<const float4*>(s + i);
    float4 b = *reinterpret_cast<const float4*>(s + i + 4);
    bf16x8 r;
    r[0] = (bf16_t)a.x; r[1] = (bf16_t)a.y; r[2] = (bf16_t)a.z; r[3] = (bf16_t)a.w;
    r[4] = (bf16_t)b.x; r[5] = (bf16_t)b.y; r[6] = (bf16_t)b.z; r[7] = (bf16_t)b.w;
    *reinterpret_cast<bf16x8*>(d + i) = r;
  } else {
    const int x = blockIdx.x;
    if (x < 1024) {
      const int wsel = x >> 8;
      const float* s = wsel == 0 ? w0 : wsel == 1 ? w1 : wsel == 2 ? w2 : w3;
      bf16_t* d = wsel == 0 ? d0 : wsel == 1 ? d1 : wsel == 2 ? d2 : d3;
      const int i = ((x & 255) * 256 + threadIdx.x) * 4;
      float4 vv = *reinterpret_cast<const float4*>(s + i);
      d[i + 0] = (bf16_t)vv.x;
      d[i + 1] = (bf16_t)vv.y;
      d[i + 2] = (bf16_t)vv.z;
      d[i + 3] = (bf16_t)vv.w;
    } else if (x < 1037) {
      const int i = ((x - 1024) * 256 + threadIdx.x) * 4;
      if (i < NREL * DKd) {
        float4 vv = *reinterpret_cast<const float4*>(rel + i);
        drel[i + 0] = (bf16_t)vv.x;
        drel[i + 1] = (bf16_t)vv.y;
        drel[i + 2] = (bf16_t)vv.z;
        drel[i + 3] = (bf16_t)vv.w;
      }
    }
  }
}

// ---------------- Q+K projections: 128x64 block tile, 2-deep prefetch ---------
// 4 waves x (32 rows x 64 cols) each: per k-step 6 loads -> 8 MFMA (ratio 1.33
// vs 1.0 at 64x64), 2x independent MFMA chains; W panel L1-shared by 4 waves.
// Grid 8x64x2 = 1024 blocks (4/CU). z = Q/K via pure offset arithmetic.
__global__ __launch_bounds__(256) void k_projQK(const bf16_t* __restrict__ A,
                                                const bf16_t* __restrict__ W,
                                                bf16_t* __restrict__ outb) {
  const int lane = threadIdx.x & 63, w = threadIdx.x >> 6;
  const int lr = lane & 15, lg = lane >> 4;
  const size_t zo = (size_t)blockIdx.z * ((size_t)MTOK * Dm);
  A += zo;
  W += (size_t)blockIdx.z * ((size_t)Dm * Dm);
  outb += zo;
  // bijective chunked XCD swizzle (nwg=512, chunk=64)
  const int orig = blockIdx.x + blockIdx.y * 8;
  const int swz = ((orig & 7) << 6) | (orig >> 3);
  const int Rbase = (swz >> 3) * 128 + w * 32;   // wave-private 32 rows
  const int Cbase = (swz & 7) * 64;              // block-shared 64 cols

  f32x4 acc[2][4] = {};
  bf16x8 afA[2], wfA[4], afB[2], wfB[4];
  auto loadF = [&](bf16x8 (&af)[2], bf16x8 (&wf)[4], int k0) {
#pragma unroll
    for (int i = 0; i < 2; ++i)
      af[i] = *reinterpret_cast<const bf16x8*>(A + (size_t)(Rbase + i * 16 + lr) * Dm + k0 + lg * 8);
#pragma unroll
    for (int j = 0; j < 4; ++j)
      wf[j] = *reinterpret_cast<const bf16x8*>(W + (size_t)(Cbase + j * 16 + lr) * Dm + k0 + lg * 8);
  };
  auto domfma = [&](const bf16x8 (&af)[2], const bf16x8 (&wf)[4]) {
#pragma unroll
    for (int i = 0; i < 2; ++i)
#pragma unroll
      for (int j = 0; j < 4; ++j)
        acc[i][j] = __builtin_amdgcn_mfma_f32_16x16x32_bf16(af[i], wf[j], acc[i][j], 0, 0, 0);
  };
  loadF(afA, wfA, 0);
#pragma unroll
  for (int k0 = 0; k0 < Dm; k0 += 64) {
    loadF(afB, wfB, k0 + 32);
    domfma(afA, wfA);
    if (k0 + 64 < Dm) loadF(afA, wfA, k0 + 64);
    domfma(afB, wfB);
  }
#pragma unroll
  for (int i = 0; i < 2; ++i)
#pragma unroll
    for (int j = 0; j < 4; ++j)
#pragma unroll
      for (int r = 0; r < 4; ++r) {
        const int gr = Rbase + i * 16 + lg * 4 + r;  // token row
        const int gc = Cbase + j * 16 + lr;          // output col
        const int bb = gr >> 10, qq = gr & 1023, hh = gc >> 6, dd = gc & 63;
        outb[(((size_t)(bb * Hh + hh)) * Lseq + qq) * DKd + dd] = (bf16_t)acc[i][j][r];
      }
}

// ---------------- V projection: prefetch + LDS-transpose epilogue -------------
__global__ __launch_bounds__(256) void k_projV(const bf16_t* __restrict__ A,
                                               const bf16_t* __restrict__ W,
                                               bf16_t* __restrict__ outb) {
  __shared__ bf16_t Vl[64][72];
  const int lane = threadIdx.x & 63, w = threadIdx.x >> 6;
  const int lr = lane & 15, lg = lane >> 4;
  // bijective chunked XCD swizzle (nwg=1024, chunk=128)
  const int orig = blockIdx.x + blockIdx.y * 8;
  const int swz = ((orig & 7) << 7) | (orig >> 3);
  const int Rtile = (swz >> 3) * 64;
  const int Rbase = Rtile + (w >> 1) * 32;
  const int Cbase = (swz & 7) * 64 + (w & 1) * 32;

  f32x4 acc[2][2] = {};
  bf16x8 afA[2], wfA[2], afB[2], wfB[2];
  auto loadF = [&](bf16x8 (&af)[2], bf16x8 (&wf)[2], int k0) {
#pragma unroll
    for (int i = 0; i < 2; ++i)
      af[i] = *reinterpret_cast<const bf16x8*>(A + (size_t)(Rbase + i * 16 + lr) * Dm + k0 + lg * 8);
#pragma unroll
    for (int j = 0; j < 2; ++j)
      wf[j] = *reinterpret_cast<const bf16x8*>(W + (size_t)(Cbase + j * 16 + lr) * Dm + k0 + lg * 8);
  };
  auto domfma = [&](const bf16x8 (&af)[2], const bf16x8 (&wf)[2]) {
#pragma unroll
    for (int i = 0; i < 2; ++i)
#pragma unroll
      for (int j = 0; j < 2; ++j)
        acc[i][j] = __builtin_amdgcn_mfma_f32_16x16x32_bf16(af[i], wf[j], acc[i][j], 0, 0, 0);
  };
  loadF(afA, wfA, 0);
#pragma unroll
  for (int k0 = 0; k0 < Dm; k0 += 64) {
    loadF(afB, wfB, k0 + 32);
    domfma(afA, wfA);
    if (k0 + 64 < Dm) loadF(afA, wfA, k0 + 64);
    domfma(afB, wfB);
  }
  // stage tile transposed into LDS: Vl[dd_local][qq_local]
#pragma unroll
  for (int i = 0; i < 2; ++i)
#pragma unroll
    for (int j = 0; j < 2; ++j)
#pragma unroll
      for (int r = 0; r < 4; ++r) {
        const int grl = (w >> 1) * 32 + i * 16 + lg * 4 + r;  // qq local
        const int gcl = (w & 1) * 32 + j * 16 + lr;           // dd local
        Vl[gcl][grl] = (bf16_t)acc[i][j][r];
      }
  __syncthreads();
  // cooperative coalesced store: thread -> (dd = tid/4, 16-qq chunk)
  const int tid = threadIdx.x;
  const int dd = tid >> 2, qq0 = (tid & 3) * 16;
  const int bb = Rtile >> 10, qrow = Rtile & 1023, hh = swz & 7;
  bf16_t* dst = outb + (((size_t)(bb * Hh + hh)) * DKd + dd) * Lseq + qrow + qq0;
  *reinterpret_cast<bf16x8*>(dst) = *reinterpret_cast<const bf16x8*>(&Vl[dd][qq0]);
  *reinterpret_cast<bf16x8*>(dst + 8) = *reinterpret_cast<const bf16x8*>(&Vl[dd][qq0 + 8]);
}

// ---------------- fc GEMM: yb = bf16(attnb @ Wfc^T + resid) -------------------
__global__ __launch_bounds__(256) void k_fc(const bf16_t* __restrict__ A,
                                            const bf16_t* __restrict__ W,
                                            bf16_t* __restrict__ yb,
                                            const float* __restrict__ resid) {
  const int lane = threadIdx.x & 63, w = threadIdx.x >> 6;
  const int lr = lane & 15, lg = lane >> 4;
  // bijective chunked XCD swizzle (nwg=1024, chunk=128)
  const int orig = blockIdx.x + blockIdx.y * 8;
  const int swz = ((orig & 7) << 7) | (orig >> 3);
  const int Rbase = (swz >> 3) * 64 + (w >> 1) * 32;
  const int Cbase = (swz & 7) * 64 + (w & 1) * 32;

  f32x4 acc[2][2] = {};
  for (int k0 = 0; k0 < Dm; k0 += 32) {
    bf16x8 af[2], wf[2];
#pragma unroll
    for (int i = 0; i < 2; ++i)
      af[i] = *reinterpret_cast<const bf16x8*>(A + (size_t)(Rbase + i * 16 + lr) * Dm + k0 + lg * 8);
#pragma unroll
    for (int j = 0; j < 2; ++j)
      wf[j] = *reinterpret_cast<const bf16x8*>(W + (size_t)(Cbase + j * 16 + lr) * Dm + k0 + lg * 8);
#pragma unroll
    for (int i = 0; i < 2; ++i)
#pragma unroll
      for (int j = 0; j < 2; ++j)
        acc[i][j] = __builtin_amdgcn_mfma_f32_16x16x32_bf16(af[i], wf[j], acc[i][j], 0, 0, 0);
  }
#pragma unroll
  for (int i = 0; i < 2; ++i)
#pragma unroll
    for (int j = 0; j < 2; ++j)
#pragma unroll
      for (int r = 0; r < 4; ++r) {
        const int gr = Rbase + i * 16 + lg * 4 + r;
        const int gc = Cbase + j * 16 + lr;
        const size_t idx = (size_t)gr * Dm + gc;
        yb[idx] = (bf16_t)(acc[i][j][r] + resid[idx]);
      }
}

// ---------------- flash attention + fused in-block posdot (84us, stable) ------
__global__ __launch_bounds__(256, 4) void k_attn(const bf16_t* __restrict__ Qh,
                                                 const bf16_t* __restrict__ Kh,
                                                 const bf16_t* __restrict__ Vt,
                                                 const bf16_t* __restrict__ relb,
                                                 bf16_t* __restrict__ attnb) {
  __shared__ float smemf[6528];   // pos 12928B + Pl 10240B = 23168B; Ml 26112B

  const int tid = threadIdx.x;
  const int wv = tid >> 6, lane = tid & 63;
  const int lr = lane & 15, lg = lane >> 4;
  // bijective chunked XCD swizzle (nwg=2048, chunk=256)
  const int gid = ((blockIdx.x & 7) << 8) | (blockIdx.x >> 3);
  const int bh = gid >> 5;
  const int qb = (gid & 31) << 5;             // 32-row q tile

  unsigned short* pls = reinterpret_cast<unsigned short*>(smemf);     // [32][202]
  unsigned* Pw = reinterpret_cast<unsigned*>(smemf) + 3232 + wv * 640; // [2][16][20]

  const bf16_t* Qp = Qh + ((size_t)bh * Lseq + qb) * DKd;
  const bf16_t* Kp = Kh + (size_t)bh * Lseq * DKd;
  const bf16_t* Vp = Vt + (size_t)bh * DKd * Lseq;

  // Q fragments (dual-use: B-operand for swapped QK^T, A-operand for posdot)
  bf16x8 qf[2][2];
#pragma unroll
  for (int t = 0; t < 2; ++t)
#pragma unroll
    for (int h = 0; h < 2; ++h)
      qf[t][h] = *reinterpret_cast<const bf16x8*>(Qp + (size_t)(t * 16 + lr) * DKd + h * 32 + lg * 8);

  // ---- in-block posdot: pls[q][200-r] = POS_C * dot(Q[q], rel[r]) -----------
  for (int n = wv; n < 13; n += 4) {
    const int rr0 = n * 16 + lr;
    const int rclamp = rr0 > 200 ? 200 : rr0;
    bf16x8 rf0 = *reinterpret_cast<const bf16x8*>(relb + (size_t)rclamp * DKd + lg * 8);
    bf16x8 rf1 = *reinterpret_cast<const bf16x8*>(relb + (size_t)rclamp * DKd + 32 + lg * 8);
#pragma unroll
    for (int t = 0; t < 2; ++t) {
      f32x4 st = {};
      st = __builtin_amdgcn_mfma_f32_16x16x32_bf16(qf[t][0], rf0, st, 0, 0, 0);
      st = __builtin_amdgcn_mfma_f32_16x16x32_bf16(qf[t][1], rf1, st, 0, 0, 0);
      if (rr0 <= 200) {
#pragma unroll
        for (int r = 0; r < 4; ++r)
          pls[(t * 16 + lg * 4 + r) * PROW + (200 - rr0)] =
              __builtin_bit_cast(unsigned short, (bf16_t)(st[r] * POS_C));
      }
    }
  }
  __syncthreads();

  // per-lane pos row bases + band-edge constants (already scaled by POS_C)
  const unsigned short* prow[2] = {pls + (size_t)lr * PROW,
                                   pls + (size_t)(16 + lr) * PROW};
  float pe0[2], pe200[2];
#pragma unroll
  for (int t = 0; t < 2; ++t) {
    pe0[t] = b2f(prow[t][0]);       // k <= q-100 side
    pe200[t] = b2f(prow[t][200]);   // k >= q+100 side
  }

  f32x4 Oacc[2][4] = {};
  float psum[2] = {0.f, 0.f};
  const int ldelta = lg * 4 - lr;

  const int kbase = wv * 256;
#pragma unroll 2
  for (int k0 = kbase; k0 < kbase + 256; k0 += 32) {
    bf16x8 kf[2][2];
#pragma unroll
    for (int u = 0; u < 2; ++u)
#pragma unroll
      for (int h = 0; h < 2; ++h)
        kf[u][h] = *reinterpret_cast<const bf16x8*>(Kp + (size_t)(k0 + u * 16 + lr) * DKd + h * 32 + lg * 8);

    __builtin_amdgcn_s_setprio(1);
#pragma unroll
    for (int t = 0; t < 2; ++t) {
      const int Qt = qb + t * 16;
      f32x4 st[2];
#pragma unroll
      for (int u = 0; u < 2; ++u) {
        f32x4 a = {};
        a = __builtin_amdgcn_mfma_f32_16x16x32_bf16(kf[u][0], qf[t][0], a, 0, 0, 0);
        a = __builtin_amdgcn_mfma_f32_16x16x32_bf16(kf[u][1], qf[t][1], a, 0, 0, 0);
        st[u] = a;  // element: q = Qt+lr (col), k = k0+u*16+lg*4+r (row)
      }
      float p[2][4];
      if (k0 + 131 <= Qt) {            // whole step below band: pos = pls[q][0]
#pragma unroll
        for (int u = 0; u < 2; ++u)
#pragma unroll
          for (int r = 0; r < 4; ++r)
            p[u][r] = fexp2(fmaf(st[u][r], POS_C, pe0[t]));
      } else if (k0 >= Qt + 115) {     // whole step above band: pos = pls[q][200]
#pragma unroll
        for (int u = 0; u < 2; ++u)
#pragma unroll
          for (int r = 0; r < 4; ++r)
            p[u][r] = fexp2(fmaf(st[u][r], POS_C, pe200[t]));
      } else {                         // in-band: clamped gather from LDS
#pragma unroll
        for (int u = 0; u < 2; ++u) {
          const int jb = k0 + u * 16 + 100 - Qt + ldelta;
#pragma unroll
          for (int r = 0; r < 4; ++r) {
            int j = jb + r;
            j = j < 0 ? 0 : (j > 200 ? 200 : j);
            p[u][r] = fexp2(fmaf(st[u][r], POS_C, b2f(prow[t][j])));
          }
        }
      }
#pragma unroll
      for (int u = 0; u < 2; ++u)
#pragma unroll
        for (int r = 0; r < 4; ++r) psum[t] += p[u][r];
      // pack to bf16, wave-private LDS transpose (D-layout -> B-frag layout)
#pragma unroll
      for (int u = 0; u < 2; ++u) {
        uint2 pk;
        pk.x = pack2(p[u][0], p[u][1]);
        pk.y = pack2(p[u][2], p[u][3]);
        *reinterpret_cast<uint2*>(&Pw[t * 320 + lr * 20 + u * 8 + lg * 2]) = pk;
      }
    }
    // PV: A = Vt fragment, B = P fragment read back from LDS
    bf16x8 pb[2];
#pragma unroll
    for (int t = 0; t < 2; ++t)
      pb[t] = *reinterpret_cast<const bf16x8*>(&Pw[t * 320 + lr * 20 + lg * 4]);
#pragma unroll
    for (int f = 0; f < 4; ++f) {
      bf16x8 vf = *reinterpret_cast<const bf16x8*>(Vp + (size_t)(f * 16 + lr) * Lseq + k0 + lg * 8);
#pragma unroll
      for (int t = 0; t < 2; ++t)
        Oacc[t][f] = __builtin_amdgcn_mfma_f32_16x16x32_bf16(vf, pb[t], Oacc[t][f], 0, 0, 0);
    }
    __builtin_amdgcn_s_setprio(0);
  }

  // ---- merge the four k-quarters (no-max partials combine by pure addition) --
  __syncthreads();   // k-loops done; pos+Pl dead -> reuse smem as Ml[3][64][34]
  float* Ml = smemf;
  if (wv) {
    float* m = Ml + ((wv - 1) * 64 + lane) * 34;
#pragma unroll
    for (int t = 0; t < 2; ++t)
#pragma unroll
      for (int f = 0; f < 4; ++f)
#pragma unroll
        for (int r = 0; r < 4; ++r) m[t * 16 + f * 4 + r] = Oacc[t][f][r];
    m[32] = psum[0];
    m[33] = psum[1];
  }
  __syncthreads();
  if (!wv) {
#pragma unroll
    for (int w2 = 0; w2 < 3; ++w2) {
      const float* m = Ml + (w2 * 64 + lane) * 34;
#pragma unroll
      for (int t = 0; t < 2; ++t) {
#pragma unroll
        for (int f = 0; f < 4; ++f)
#pragma unroll
          for (int r = 0; r < 4; ++r) Oacc[t][f][r] += m[t * 16 + f * 4 + r];
        psum[t] += m[32 + t];
      }
    }
    const int gb = bh >> 3, hh = bh & 7;
#pragma unroll
    for (int t = 0; t < 2; ++t) {
      float s = psum[t];
      s += __shfl_xor(s, 16);
      s += __shfl_xor(s, 32);
      const float inv = 1.0f / s;
      const int qg = qb + t * 16 + lr;
#pragma unroll
      for (int f = 0; f < 4; ++f) {
        uint2 ov;
        ov.x = pack2(Oacc[t][f][0] * inv, Oacc[t][f][1] * inv);
        ov.y = pack2(Oacc[t][f][2] * inv, Oacc[t][f][3] * inv);
        *reinterpret_cast<uint2*>(attnb + ((size_t)(gb * Lseq + qg)) * Dm + hh * DKd + f * 16 + lg * 4) = ov;
      }
    }
  }
}

// ---------------- row LayerNorm over D=512, bf16 input ------------------------
__global__ __launch_bounds__(256) void k_ln(const bf16_t* __restrict__ y,
                                            const float* __restrict__ g,
                                            const float* __restrict__ be,
                                            float* __restrict__ out) {
  const int row = blockIdx.x * 4 + (threadIdx.x >> 6);
  const int lane = threadIdx.x & 63;
  bf16x8 rv = *reinterpret_cast<const bf16x8*>(y + (size_t)row * Dm + lane * 8);
  float vv[8];
#pragma unroll
  for (int j = 0; j < 8; ++j) vv[j] = (float)rv[j];
  float s = 0.f, s2 = 0.f;
#pragma unroll
  for (int j = 0; j < 8; ++j) { s += vv[j]; s2 += vv[j] * vv[j]; }
  for (int mk = 1; mk < 64; mk <<= 1) {
    s += __shfl_xor(s, mk, 64);
    s2 += __shfl_xor(s2, mk, 64);
  }
  const float mu = s * (1.0f / Dm);
  const float var = s2 * (1.0f / Dm) - mu * mu;
  const float inv = rsqrtf(var + 1e-6f);
  float* op = out + (size_t)row * Dm + lane * 8;
  const float* gp = g + lane * 8;
  const float* bp = be + lane * 8;
#pragma unroll
  for (int j = 0; j < 8; ++j) op[j] = (vv[j] - mu) * inv * gp[j] + bp[j];
}

// ------------------------------------------------------------------------------
extern "C" void kernel_launch(void* const* d_in, const int* in_sizes, int n_in,
                              void* d_out, int out_size, void* d_ws, size_t ws_size,
                              hipStream_t stream) {
  const float* q   = (const float*)d_in[0];
  const float* k   = (const float*)d_in[1];
  const float* v   = (const float*)d_in[2];
  const float* Wq  = (const float*)d_in[3];
  const float* Wk  = (const float*)d_in[4];
  const float* Wv  = (const float*)d_in[5];
  const float* Wfc = (const float*)d_in[6];
  const float* rel = (const float*)d_in[7];
  const float* gam = (const float*)d_in[8];
  const float* bet = (const float*)d_in[9];

  char* ws = (char*)d_ws;
  size_t off = 0;
  auto take = [&](size_t bytes) {
    char* p = ws + off;
    off += (bytes + 255) & ~(size_t)255;
    return p;
  };
  // NOTE: wqb/wkb contiguous, qb/kb contiguous, Qhp/Khp contiguous —
  // required by the z=2 Q+K projection launch (pure offset arithmetic).
  bf16_t* wqb  = (bf16_t*)take((size_t)Dm * Dm * 2);
  bf16_t* wkb  = (bf16_t*)take((size_t)Dm * Dm * 2);
  bf16_t* wvb  = (bf16_t*)take((size_t)Dm * Dm * 2);
  bf16_t* wfcb = (bf16_t*)take((size_t)Dm * Dm * 2);
  bf16_t* relb = (bf16_t*)take((size_t)NREL * DKd * 2);
  bf16_t* qb   = (bf16_t*)take((size_t)MTOK * Dm * 2);
  bf16_t* kb   = (bf16_t*)take((size_t)MTOK * Dm * 2);
  bf16_t* vb   = (bf16_t*)take((size_t)MTOK * Dm * 2);
  bf16_t* Qhp  = (bf16_t*)take((size_t)MTOK * Dm * 2);
  bf16_t* Khp  = (bf16_t*)take((size_t)MTOK * Dm * 2);
  bf16_t* Vtp  = (bf16_t*)take((size_t)MTOK * Dm * 2);
  bf16_t* attnb= (bf16_t*)take((size_t)MTOK * Dm * 2);
  bf16_t* yb   = (bf16_t*)take((size_t)MTOK * Dm * 2);

  // 1) ALL casts (q/k/v + 4 weights + rel) in one launch
  k_cast_all<<<dim3(2048, 4), 256, 0, stream>>>(
      q, k, v, Wq, Wk, Wv, Wfc, rel, qb, kb, vb, wqb, wkb, wvb, wfcb, relb);
  // 2) Q+K projections (128x64 tile, z=2, prefetch)
  k_projQK<<<dim3(8, 64, 2), 256, 0, stream>>>(qb, wqb, Qhp);
  // 3) V projection (prefetch + LDS-transpose coalesced store)
  k_projV<<<dim3(8, 128), 256, 0, stream>>>(vb, wvb, Vtp);
  // 4) attention (posdot fused in-block; stable 84us)
  k_attn<<<dim3(2048), 256, 0, stream>>>(Qhp, Khp, Vtp, relb, attnb);
  // 5) output GEMM + residual (bf16 yb)
  k_fc<<<dim3(8, 128), 256, 0, stream>>>(attnb, wfcb, yb, q);
  // 6) LayerNorm (bf16 input)
  k_ln<<<dim3(MTOK / 4), 256, 0, stream>>>(yb, gam, bet, (float*)d_out);
}

// Round 26
// 198.811 us; speedup vs baseline: 1.2723x; 1.0525x over previous
//
#include <hip/hip_runtime.h>
#include <hip/hip_bf16.h>

typedef __bf16 bf16_t;
typedef __bf16 bf16x8 __attribute__((ext_vector_type(8)));
typedef float f32x4 __attribute__((ext_vector_type(4)));

constexpr int Bz = 8, Lseq = 1024, Dm = 512, Hh = 8, DKd = 64;
constexpr int MTOK = Bz * Lseq;   // 8192 tokens
constexpr int NREL = 201;
constexpr int PROW = 202;         // padded LDS row (bank stride 101%32=5, coprime)

// pos pre-scale: 0.125 (1/sqrt(dk)) * log2(e), folded so p = exp2(st*C + pos)
#define POS_C 0.18033688011112042f

__device__ inline float fexp2(float x) {
#if __has_builtin(__builtin_amdgcn_exp2f)
  return __builtin_amdgcn_exp2f(x);
#else
  return exp2f(x);
#endif
}
__device__ inline float b2f(unsigned short u) {
  return __builtin_bit_cast(float, (unsigned)u << 16);
}
__device__ inline unsigned pack2(float a, float b) {
  unsigned short ua = __builtin_bit_cast(unsigned short, (bf16_t)a);
  unsigned short ub = __builtin_bit_cast(unsigned short, (bf16_t)b);
  return (unsigned)ua | ((unsigned)ub << 16);
}

// ---------------- ONE launch for ALL casts ------------------------------------
__global__ __launch_bounds__(256) void k_cast_all(
    const float* __restrict__ q, const float* __restrict__ k,
    const float* __restrict__ v, const float* __restrict__ w0,
    const float* __restrict__ w1, const float* __restrict__ w2,
    const float* __restrict__ w3, const float* __restrict__ rel,
    bf16_t* __restrict__ qb, bf16_t* __restrict__ kb, bf16_t* __restrict__ vb,
    bf16_t* __restrict__ d0, bf16_t* __restrict__ d1, bf16_t* __restrict__ d2,
    bf16_t* __restrict__ d3, bf16_t* __restrict__ drel) {
  const int y = blockIdx.y;
  if (y < 3) {
    const float* s = y == 0 ? q : y == 1 ? k : v;
    bf16_t* d = y == 0 ? qb : y == 1 ? kb : vb;
    const int i = (blockIdx.x * 256 + threadIdx.x) * 8;
    float4 a = *reinterpret_cast<const float4*>(s + i);
    float4 b = *reinterpret_cast<const float4*>(s + i + 4);
    bf16x8 r;
    r[0] = (bf16_t)a.x; r[1] = (bf16_t)a.y; r[2] = (bf16_t)a.z; r[3] = (bf16_t)a.w;
    r[4] = (bf16_t)b.x; r[5] = (bf16_t)b.y; r[6] = (bf16_t)b.z; r[7] = (bf16_t)b.w;
    *reinterpret_cast<bf16x8*>(d + i) = r;
  } else {
    const int x = blockIdx.x;
    if (x < 1024) {
      const int wsel = x >> 8;
      const float* s = wsel == 0 ? w0 : wsel == 1 ? w1 : wsel == 2 ? w2 : w3;
      bf16_t* d = wsel == 0 ? d0 : wsel == 1 ? d1 : wsel == 2 ? d2 : d3;
      const int i = ((x & 255) * 256 + threadIdx.x) * 4;
      float4 vv = *reinterpret_cast<const float4*>(s + i);
      d[i + 0] = (bf16_t)vv.x;
      d[i + 1] = (bf16_t)vv.y;
      d[i + 2] = (bf16_t)vv.z;
      d[i + 3] = (bf16_t)vv.w;
    } else if (x < 1037) {
      const int i = ((x - 1024) * 256 + threadIdx.x) * 4;
      if (i < NREL * DKd) {
        float4 vv = *reinterpret_cast<const float4*>(rel + i);
        drel[i + 0] = (bf16_t)vv.x;
        drel[i + 1] = (bf16_t)vv.y;
        drel[i + 2] = (bf16_t)vv.z;
        drel[i + 3] = (bf16_t)vv.w;
      }
    }
  }
}

// ---------------- Q+K projections: 128x64 block tile, 2-deep prefetch ---------
// (r25-measured win: ratio 1.33, 2x MFMA chains, W panel L1-shared by 4 waves)
__global__ __launch_bounds__(256) void k_projQK(const bf16_t* __restrict__ A,
                                                const bf16_t* __restrict__ W,
                                                bf16_t* __restrict__ outb) {
  const int lane = threadIdx.x & 63, w = threadIdx.x >> 6;
  const int lr = lane & 15, lg = lane >> 4;
  const size_t zo = (size_t)blockIdx.z * ((size_t)MTOK * Dm);
  A += zo;
  W += (size_t)blockIdx.z * ((size_t)Dm * Dm);
  outb += zo;
  // bijective chunked XCD swizzle (nwg=512, chunk=64)
  const int orig = blockIdx.x + blockIdx.y * 8;
  const int swz = ((orig & 7) << 6) | (orig >> 3);
  const int Rbase = (swz >> 3) * 128 + w * 32;   // wave-private 32 rows
  const int Cbase = (swz & 7) * 64;              // block-shared 64 cols

  f32x4 acc[2][4] = {};
  bf16x8 afA[2], wfA[4], afB[2], wfB[4];
  auto loadF = [&](bf16x8 (&af)[2], bf16x8 (&wf)[4], int k0) {
#pragma unroll
    for (int i = 0; i < 2; ++i)
      af[i] = *reinterpret_cast<const bf16x8*>(A + (size_t)(Rbase + i * 16 + lr) * Dm + k0 + lg * 8);
#pragma unroll
    for (int j = 0; j < 4; ++j)
      wf[j] = *reinterpret_cast<const bf16x8*>(W + (size_t)(Cbase + j * 16 + lr) * Dm + k0 + lg * 8);
  };
  auto domfma = [&](const bf16x8 (&af)[2], const bf16x8 (&wf)[4]) {
#pragma unroll
    for (int i = 0; i < 2; ++i)
#pragma unroll
      for (int j = 0; j < 4; ++j)
        acc[i][j] = __builtin_amdgcn_mfma_f32_16x16x32_bf16(af[i], wf[j], acc[i][j], 0, 0, 0);
  };
  loadF(afA, wfA, 0);
#pragma unroll
  for (int k0 = 0; k0 < Dm; k0 += 64) {
    loadF(afB, wfB, k0 + 32);
    domfma(afA, wfA);
    if (k0 + 64 < Dm) loadF(afA, wfA, k0 + 64);
    domfma(afB, wfB);
  }
#pragma unroll
  for (int i = 0; i < 2; ++i)
#pragma unroll
    for (int j = 0; j < 4; ++j)
#pragma unroll
      for (int r = 0; r < 4; ++r) {
        const int gr = Rbase + i * 16 + lg * 4 + r;  // token row
        const int gc = Cbase + j * 16 + lr;          // output col
        const int bb = gr >> 10, qq = gr & 1023, hh = gc >> 6, dd = gc & 63;
        outb[(((size_t)(bb * Hh + hh)) * Lseq + qq) * DKd + dd] = (bf16_t)acc[i][j][r];
      }
}

// ---------------- V projection: 128x64 tile + prefetch + LDS-transpose --------
// Tile [128 qq][64 dd]; stage into Vl[64 dd][136] (rows 16B-aligned), then
// 256 threads store 64B contiguous each into Vt[dd][qq].
__global__ __launch_bounds__(256) void k_projV(const bf16_t* __restrict__ A,
                                               const bf16_t* __restrict__ W,
                                               bf16_t* __restrict__ outb) {
  __shared__ bf16_t Vl[64][136];
  const int lane = threadIdx.x & 63, w = threadIdx.x >> 6;
  const int lr = lane & 15, lg = lane >> 4;
  // bijective chunked XCD swizzle (nwg=512, chunk=64)
  const int orig = blockIdx.x + blockIdx.y * 8;
  const int swz = ((orig & 7) << 6) | (orig >> 3);
  const int Rtile = (swz >> 3) * 128;            // 1024%128==0: no batch cross
  const int Rbase = Rtile + w * 32;
  const int Cbase = (swz & 7) * 64;

  f32x4 acc[2][4] = {};
  bf16x8 afA[2], wfA[4], afB[2], wfB[4];
  auto loadF = [&](bf16x8 (&af)[2], bf16x8 (&wf)[4], int k0) {
#pragma unroll
    for (int i = 0; i < 2; ++i)
      af[i] = *reinterpret_cast<const bf16x8*>(A + (size_t)(Rbase + i * 16 + lr) * Dm + k0 + lg * 8);
#pragma unroll
    for (int j = 0; j < 4; ++j)
      wf[j] = *reinterpret_cast<const bf16x8*>(W + (size_t)(Cbase + j * 16 + lr) * Dm + k0 + lg * 8);
  };
  auto domfma = [&](const bf16x8 (&af)[2], const bf16x8 (&wf)[4]) {
#pragma unroll
    for (int i = 0; i < 2; ++i)
#pragma unroll
      for (int j = 0; j < 4; ++j)
        acc[i][j] = __builtin_amdgcn_mfma_f32_16x16x32_bf16(af[i], wf[j], acc[i][j], 0, 0, 0);
  };
  loadF(afA, wfA, 0);
#pragma unroll
  for (int k0 = 0; k0 < Dm; k0 += 64) {
    loadF(afB, wfB, k0 + 32);
    domfma(afA, wfA);
    if (k0 + 64 < Dm) loadF(afA, wfA, k0 + 64);
    domfma(afB, wfB);
  }
  // stage tile transposed into LDS: Vl[dd_local][qq_local]
#pragma unroll
  for (int i = 0; i < 2; ++i)
#pragma unroll
    for (int j = 0; j < 4; ++j)
#pragma unroll
      for (int r = 0; r < 4; ++r) {
        const int grl = w * 32 + i * 16 + lg * 4 + r;  // qq local 0..127
        const int gcl = j * 16 + lr;                   // dd local 0..63
        Vl[gcl][grl] = (bf16_t)acc[i][j][r];
      }
  __syncthreads();
  // cooperative coalesced store: thread -> (dd = tid/4, 32-qq chunk = 64B)
  const int tid = threadIdx.x;
  const int dd = tid >> 2, qq0 = (tid & 3) * 32;
  const int bb = Rtile >> 10, qrow = Rtile & 1023, hh = swz & 7;
  bf16_t* dst = outb + (((size_t)(bb * Hh + hh)) * DKd + dd) * Lseq + qrow + qq0;
#pragma unroll
  for (int c = 0; c < 4; ++c)
    *reinterpret_cast<bf16x8*>(dst + c * 8) =
        *reinterpret_cast<const bf16x8*>(&Vl[dd][qq0 + c * 8]);
}

// ---------------- fc GEMM: 128x64 tile + prefetch, bf16 out + resid -----------
__global__ __launch_bounds__(256) void k_fc(const bf16_t* __restrict__ A,
                                            const bf16_t* __restrict__ W,
                                            bf16_t* __restrict__ yb,
                                            const float* __restrict__ resid) {
  const int lane = threadIdx.x & 63, w = threadIdx.x >> 6;
  const int lr = lane & 15, lg = lane >> 4;
  // bijective chunked XCD swizzle (nwg=512, chunk=64)
  const int orig = blockIdx.x + blockIdx.y * 8;
  const int swz = ((orig & 7) << 6) | (orig >> 3);
  const int Rbase = (swz >> 3) * 128 + w * 32;
  const int Cbase = (swz & 7) * 64;

  f32x4 acc[2][4] = {};
  bf16x8 afA[2], wfA[4], afB[2], wfB[4];
  auto loadF = [&](bf16x8 (&af)[2], bf16x8 (&wf)[4], int k0) {
#pragma unroll
    for (int i = 0; i < 2; ++i)
      af[i] = *reinterpret_cast<const bf16x8*>(A + (size_t)(Rbase + i * 16 + lr) * Dm + k0 + lg * 8);
#pragma unroll
    for (int j = 0; j < 4; ++j)
      wf[j] = *reinterpret_cast<const bf16x8*>(W + (size_t)(Cbase + j * 16 + lr) * Dm + k0 + lg * 8);
  };
  auto domfma = [&](const bf16x8 (&af)[2], const bf16x8 (&wf)[4]) {
#pragma unroll
    for (int i = 0; i < 2; ++i)
#pragma unroll
      for (int j = 0; j < 4; ++j)
        acc[i][j] = __builtin_amdgcn_mfma_f32_16x16x32_bf16(af[i], wf[j], acc[i][j], 0, 0, 0);
  };
  loadF(afA, wfA, 0);
#pragma unroll
  for (int k0 = 0; k0 < Dm; k0 += 64) {
    loadF(afB, wfB, k0 + 32);
    domfma(afA, wfA);
    if (k0 + 64 < Dm) loadF(afA, wfA, k0 + 64);
    domfma(afB, wfB);
  }
#pragma unroll
  for (int i = 0; i < 2; ++i)
#pragma unroll
    for (int j = 0; j < 4; ++j)
#pragma unroll
      for (int r = 0; r < 4; ++r) {
        const int gr = Rbase + i * 16 + lg * 4 + r;
        const int gc = Cbase + j * 16 + lr;
        const size_t idx = (size_t)gr * Dm + gc;
        yb[idx] = (bf16_t)(acc[i][j][r] + resid[idx]);
      }
}

// ---------------- flash attention + fused in-block posdot (84us, stable) ------
__global__ __launch_bounds__(256, 4) void k_attn(const bf16_t* __restrict__ Qh,
                                                 const bf16_t* __restrict__ Kh,
                                                 const bf16_t* __restrict__ Vt,
                                                 const bf16_t* __restrict__ relb,
                                                 bf16_t* __restrict__ attnb) {
  __shared__ float smemf[6528];   // pos 12928B + Pl 10240B = 23168B; Ml 26112B

  const int tid = threadIdx.x;
  const int wv = tid >> 6, lane = tid & 63;
  const int lr = lane & 15, lg = lane >> 4;
  // bijective chunked XCD swizzle (nwg=2048, chunk=256)
  const int gid = ((blockIdx.x & 7) << 8) | (blockIdx.x >> 3);
  const int bh = gid >> 5;
  const int qb = (gid & 31) << 5;             // 32-row q tile

  unsigned short* pls = reinterpret_cast<unsigned short*>(smemf);     // [32][202]
  unsigned* Pw = reinterpret_cast<unsigned*>(smemf) + 3232 + wv * 640; // [2][16][20]

  const bf16_t* Qp = Qh + ((size_t)bh * Lseq + qb) * DKd;
  const bf16_t* Kp = Kh + (size_t)bh * Lseq * DKd;
  const bf16_t* Vp = Vt + (size_t)bh * DKd * Lseq;

  // Q fragments (dual-use: B-operand for swapped QK^T, A-operand for posdot)
  bf16x8 qf[2][2];
#pragma unroll
  for (int t = 0; t < 2; ++t)
#pragma unroll
    for (int h = 0; h < 2; ++h)
      qf[t][h] = *reinterpret_cast<const bf16x8*>(Qp + (size_t)(t * 16 + lr) * DKd + h * 32 + lg * 8);

  // ---- in-block posdot: pls[q][200-r] = POS_C * dot(Q[q], rel[r]) -----------
  for (int n = wv; n < 13; n += 4) {
    const int rr0 = n * 16 + lr;
    const int rclamp = rr0 > 200 ? 200 : rr0;
    bf16x8 rf0 = *reinterpret_cast<const bf16x8*>(relb + (size_t)rclamp * DKd + lg * 8);
    bf16x8 rf1 = *reinterpret_cast<const bf16x8*>(relb + (size_t)rclamp * DKd + 32 + lg * 8);
#pragma unroll
    for (int t = 0; t < 2; ++t) {
      f32x4 st = {};
      st = __builtin_amdgcn_mfma_f32_16x16x32_bf16(qf[t][0], rf0, st, 0, 0, 0);
      st = __builtin_amdgcn_mfma_f32_16x16x32_bf16(qf[t][1], rf1, st, 0, 0, 0);
      if (rr0 <= 200) {
#pragma unroll
        for (int r = 0; r < 4; ++r)
          pls[(t * 16 + lg * 4 + r) * PROW + (200 - rr0)] =
              __builtin_bit_cast(unsigned short, (bf16_t)(st[r] * POS_C));
      }
    }
  }
  __syncthreads();

  // per-lane pos row bases + band-edge constants (already scaled by POS_C)
  const unsigned short* prow[2] = {pls + (size_t)lr * PROW,
                                   pls + (size_t)(16 + lr) * PROW};
  float pe0[2], pe200[2];
#pragma unroll
  for (int t = 0; t < 2; ++t) {
    pe0[t] = b2f(prow[t][0]);       // k <= q-100 side
    pe200[t] = b2f(prow[t][200]);   // k >= q+100 side
  }

  f32x4 Oacc[2][4] = {};
  float psum[2] = {0.f, 0.f};
  const int ldelta = lg * 4 - lr;

  const int kbase = wv * 256;
#pragma unroll 2
  for (int k0 = kbase; k0 < kbase + 256; k0 += 32) {
    bf16x8 kf[2][2];
#pragma unroll
    for (int u = 0; u < 2; ++u)
#pragma unroll
      for (int h = 0; h < 2; ++h)
        kf[u][h] = *reinterpret_cast<const bf16x8*>(Kp + (size_t)(k0 + u * 16 + lr) * DKd + h * 32 + lg * 8);

    __builtin_amdgcn_s_setprio(1);
#pragma unroll
    for (int t = 0; t < 2; ++t) {
      const int Qt = qb + t * 16;
      f32x4 st[2];
#pragma unroll
      for (int u = 0; u < 2; ++u) {
        f32x4 a = {};
        a = __builtin_amdgcn_mfma_f32_16x16x32_bf16(kf[u][0], qf[t][0], a, 0, 0, 0);
        a = __builtin_amdgcn_mfma_f32_16x16x32_bf16(kf[u][1], qf[t][1], a, 0, 0, 0);
        st[u] = a;  // element: q = Qt+lr (col), k = k0+u*16+lg*4+r (row)
      }
      float p[2][4];
      if (k0 + 131 <= Qt) {            // whole step below band: pos = pls[q][0]
#pragma unroll
        for (int u = 0; u < 2; ++u)
#pragma unroll
          for (int r = 0; r < 4; ++r)
            p[u][r] = fexp2(fmaf(st[u][r], POS_C, pe0[t]));
      } else if (k0 >= Qt + 115) {     // whole step above band: pos = pls[q][200]
#pragma unroll
        for (int u = 0; u < 2; ++u)
#pragma unroll
          for (int r = 0; r < 4; ++r)
            p[u][r] = fexp2(fmaf(st[u][r], POS_C, pe200[t]));
      } else {                         // in-band: clamped gather from LDS
#pragma unroll
        for (int u = 0; u < 2; ++u) {
          const int jb = k0 + u * 16 + 100 - Qt + ldelta;
#pragma unroll
          for (int r = 0; r < 4; ++r) {
            int j = jb + r;
            j = j < 0 ? 0 : (j > 200 ? 200 : j);
            p[u][r] = fexp2(fmaf(st[u][r], POS_C, b2f(prow[t][j])));
          }
        }
      }
#pragma unroll
      for (int u = 0; u < 2; ++u)
#pragma unroll
        for (int r = 0; r < 4; ++r) psum[t] += p[u][r];
      // pack to bf16, wave-private LDS transpose (D-layout -> B-frag layout)
#pragma unroll
      for (int u = 0; u < 2; ++u) {
        uint2 pk;
        pk.x = pack2(p[u][0], p[u][1]);
        pk.y = pack2(p[u][2], p[u][3]);
        *reinterpret_cast<uint2*>(&Pw[t * 320 + lr * 20 + u * 8 + lg * 2]) = pk;
      }
    }
    // PV: A = Vt fragment, B = P fragment read back from LDS
    bf16x8 pb[2];
#pragma unroll
    for (int t = 0; t < 2; ++t)
      pb[t] = *reinterpret_cast<const bf16x8*>(&Pw[t * 320 + lr * 20 + lg * 4]);
#pragma unroll
    for (int f = 0; f < 4; ++f) {
      bf16x8 vf = *reinterpret_cast<const bf16x8*>(Vp + (size_t)(f * 16 + lr) * Lseq + k0 + lg * 8);
#pragma unroll
      for (int t = 0; t < 2; ++t)
        Oacc[t][f] = __builtin_amdgcn_mfma_f32_16x16x32_bf16(vf, pb[t], Oacc[t][f], 0, 0, 0);
    }
    __builtin_amdgcn_s_setprio(0);
  }

  // ---- merge the four k-quarters (no-max partials combine by pure addition) --
  __syncthreads();   // k-loops done; pos+Pl dead -> reuse smem as Ml[3][64][34]
  float* Ml = smemf;
  if (wv) {
    float* m = Ml + ((wv - 1) * 64 + lane) * 34;
#pragma unroll
    for (int t = 0; t < 2; ++t)
#pragma unroll
      for (int f = 0; f < 4; ++f)
#pragma unroll
        for (int r = 0; r < 4; ++r) m[t * 16 + f * 4 + r] = Oacc[t][f][r];
    m[32] = psum[0];
    m[33] = psum[1];
  }
  __syncthreads();
  if (!wv) {
#pragma unroll
    for (int w2 = 0; w2 < 3; ++w2) {
      const float* m = Ml + (w2 * 64 + lane) * 34;
#pragma unroll
      for (int t = 0; t < 2; ++t) {
#pragma unroll
        for (int f = 0; f < 4; ++f)
#pragma unroll
          for (int r = 0; r < 4; ++r) Oacc[t][f][r] += m[t * 16 + f * 4 + r];
        psum[t] += m[32 + t];
      }
    }
    const int gb = bh >> 3, hh = bh & 7;
#pragma unroll
    for (int t = 0; t < 2; ++t) {
      float s = psum[t];
      s += __shfl_xor(s, 16);
      s += __shfl_xor(s, 32);
      const float inv = 1.0f / s;
      const int qg = qb + t * 16 + lr;
#pragma unroll
      for (int f = 0; f < 4; ++f) {
        uint2 ov;
        ov.x = pack2(Oacc[t][f][0] * inv, Oacc[t][f][1] * inv);
        ov.y = pack2(Oacc[t][f][2] * inv, Oacc[t][f][3] * inv);
        *reinterpret_cast<uint2*>(attnb + ((size_t)(gb * Lseq + qg)) * Dm + hh * DKd + f * 16 + lg * 4) = ov;
      }
    }
  }
}

// ---------------- row LayerNorm over D=512, bf16 input ------------------------
__global__ __launch_bounds__(256) void k_ln(const bf16_t* __restrict__ y,
                                            const float* __restrict__ g,
                                            const float* __restrict__ be,
                                            float* __restrict__ out) {
  const int row = blockIdx.x * 4 + (threadIdx.x >> 6);
  const int lane = threadIdx.x & 63;
  bf16x8 rv = *reinterpret_cast<const bf16x8*>(y + (size_t)row * Dm + lane * 8);
  float vv[8];
#pragma unroll
  for (int j = 0; j < 8; ++j) vv[j] = (float)rv[j];
  float s = 0.f, s2 = 0.f;
#pragma unroll
  for (int j = 0; j < 8; ++j) { s += vv[j]; s2 += vv[j] * vv[j]; }
  for (int mk = 1; mk < 64; mk <<= 1) {
    s += __shfl_xor(s, mk, 64);
    s2 += __shfl_xor(s2, mk, 64);
  }
  const float mu = s * (1.0f / Dm);
  const float var = s2 * (1.0f / Dm) - mu * mu;
  const float inv = rsqrtf(var + 1e-6f);
  float* op = out + (size_t)row * Dm + lane * 8;
  const float* gp = g + lane * 8;
  const float* bp = be + lane * 8;
#pragma unroll
  for (int j = 0; j < 8; ++j) op[j] = (vv[j] - mu) * inv * gp[j] + bp[j];
}

// ------------------------------------------------------------------------------
extern "C" void kernel_launch(void* const* d_in, const int* in_sizes, int n_in,
                              void* d_out, int out_size, void* d_ws, size_t ws_size,
                              hipStream_t stream) {
  const float* q   = (const float*)d_in[0];
  const float* k   = (const float*)d_in[1];
  const float* v   = (const float*)d_in[2];
  const float* Wq  = (const float*)d_in[3];
  const float* Wk  = (const float*)d_in[4];
  const float* Wv  = (const float*)d_in[5];
  const float* Wfc = (const float*)d_in[6];
  const float* rel = (const float*)d_in[7];
  const float* gam = (const float*)d_in[8];
  const float* bet = (const float*)d_in[9];

  char* ws = (char*)d_ws;
  size_t off = 0;
  auto take = [&](size_t bytes) {
    char* p = ws + off;
    off += (bytes + 255) & ~(size_t)255;
    return p;
  };
  // NOTE: wqb/wkb contiguous, qb/kb contiguous, Qhp/Khp contiguous —
  // required by the z=2 Q+K projection launch (pure offset arithmetic).
  bf16_t* wqb  = (bf16_t*)take((size_t)Dm * Dm * 2);
  bf16_t* wkb  = (bf16_t*)take((size_t)Dm * Dm * 2);
  bf16_t* wvb  = (bf16_t*)take((size_t)Dm * Dm * 2);
  bf16_t* wfcb = (bf16_t*)take((size_t)Dm * Dm * 2);
  bf16_t* relb = (bf16_t*)take((size_t)NREL * DKd * 2);
  bf16_t* qb   = (bf16_t*)take((size_t)MTOK * Dm * 2);
  bf16_t* kb   = (bf16_t*)take((size_t)MTOK * Dm * 2);
  bf16_t* vb   = (bf16_t*)take((size_t)MTOK * Dm * 2);
  bf16_t* Qhp  = (bf16_t*)take((size_t)MTOK * Dm * 2);
  bf16_t* Khp  = (bf16_t*)take((size_t)MTOK * Dm * 2);
  bf16_t* Vtp  = (bf16_t*)take((size_t)MTOK * Dm * 2);
  bf16_t* attnb= (bf16_t*)take((size_t)MTOK * Dm * 2);
  bf16_t* yb   = (bf16_t*)take((size_t)MTOK * Dm * 2);

  // 1) ALL casts (q/k/v + 4 weights + rel) in one launch
  k_cast_all<<<dim3(2048, 4), 256, 0, stream>>>(
      q, k, v, Wq, Wk, Wv, Wfc, rel, qb, kb, vb, wqb, wkb, wvb, wfcb, relb);
  // 2) Q+K projections (128x64 tile, z=2, prefetch)
  k_projQK<<<dim3(8, 64, 2), 256, 0, stream>>>(qb, wqb, Qhp);
  // 3) V projection (128x64 tile, prefetch + LDS-transpose coalesced store)
  k_projV<<<dim3(8, 64), 256, 0, stream>>>(vb, wvb, Vtp);
  // 4) attention (posdot fused in-block; stable 84us)
  k_attn<<<dim3(2048), 256, 0, stream>>>(Qhp, Khp, Vtp, relb, attnb);
  // 5) output GEMM + residual (128x64 tile, bf16 yb)
  k_fc<<<dim3(8, 64), 256, 0, stream>>>(attnb, wfcb, yb, q);
  // 6) LayerNorm (bf16 input)
  k_ln<<<dim3(MTOK / 4), 256, 0, stream>>>(yb, gam, bet, (float*)d_out);
}

// Round 27
// 175.836 us; speedup vs baseline: 1.4385x; 1.1307x over previous
//
#include <hip/hip_runtime.h>
#include <hip/hip_bf16.h>

typedef __bf16 bf16_t;
typedef __bf16 bf16x8 __attribute__((ext_vector_type(8)));
typedef float f32x4 __attribute__((ext_vector_type(4)));

constexpr int Bz = 8, Lseq = 1024, Dm = 512, Hh = 8, DKd = 64;
constexpr int MTOK = Bz * Lseq;   // 8192 tokens
constexpr int NREL = 201;
constexpr int PROW = 202;         // padded LDS row (bank stride 101%32=5, coprime)

// pos pre-scale: 0.125 (1/sqrt(dk)) * log2(e), folded so p = exp2(st*C + pos)
#define POS_C 0.18033688011112042f

__device__ inline float fexp2(float x) {
#if __has_builtin(__builtin_amdgcn_exp2f)
  return __builtin_amdgcn_exp2f(x);
#else
  return exp2f(x);
#endif
}
__device__ inline float b2f(unsigned short u) {
  return __builtin_bit_cast(float, (unsigned)u << 16);
}
__device__ inline unsigned pack2(float a, float b) {
  unsigned short ua = __builtin_bit_cast(unsigned short, (bf16_t)a);
  unsigned short ub = __builtin_bit_cast(unsigned short, (bf16_t)b);
  return (unsigned)ua | ((unsigned)ub << 16);
}

// ---------------- ONE launch for ALL casts ------------------------------------
__global__ __launch_bounds__(256) void k_cast_all(
    const float* __restrict__ q, const float* __restrict__ k,
    const float* __restrict__ v, const float* __restrict__ w0,
    const float* __restrict__ w1, const float* __restrict__ w2,
    const float* __restrict__ w3, const float* __restrict__ rel,
    bf16_t* __restrict__ qb, bf16_t* __restrict__ kb, bf16_t* __restrict__ vb,
    bf16_t* __restrict__ d0, bf16_t* __restrict__ d1, bf16_t* __restrict__ d2,
    bf16_t* __restrict__ d3, bf16_t* __restrict__ drel) {
  const int y = blockIdx.y;
  if (y < 3) {
    const float* s = y == 0 ? q : y == 1 ? k : v;
    bf16_t* d = y == 0 ? qb : y == 1 ? kb : vb;
    const int i = (blockIdx.x * 256 + threadIdx.x) * 8;
    float4 a = *reinterpret_cast<const float4*>(s + i);
    float4 b = *reinterpret_cast<const float4*>(s + i + 4);
    bf16x8 r;
    r[0] = (bf16_t)a.x; r[1] = (bf16_t)a.y; r[2] = (bf16_t)a.z; r[3] = (bf16_t)a.w;
    r[4] = (bf16_t)b.x; r[5] = (bf16_t)b.y; r[6] = (bf16_t)b.z; r[7] = (bf16_t)b.w;
    *reinterpret_cast<bf16x8*>(d + i) = r;
  } else {
    const int x = blockIdx.x;
    if (x < 1024) {
      const int wsel = x >> 8;
      const float* s = wsel == 0 ? w0 : wsel == 1 ? w1 : wsel == 2 ? w2 : w3;
      bf16_t* d = wsel == 0 ? d0 : wsel == 1 ? d1 : wsel == 2 ? d2 : d3;
      const int i = ((x & 255) * 256 + threadIdx.x) * 4;
      float4 vv = *reinterpret_cast<const float4*>(s + i);
      d[i + 0] = (bf16_t)vv.x;
      d[i + 1] = (bf16_t)vv.y;
      d[i + 2] = (bf16_t)vv.z;
      d[i + 3] = (bf16_t)vv.w;
    } else if (x < 1037) {
      const int i = ((x - 1024) * 256 + threadIdx.x) * 4;
      if (i < NREL * DKd) {
        float4 vv = *reinterpret_cast<const float4*>(rel + i);
        drel[i + 0] = (bf16_t)vv.x;
        drel[i + 1] = (bf16_t)vv.y;
        drel[i + 2] = (bf16_t)vv.z;
        drel[i + 3] = (bf16_t)vv.w;
      }
    }
  }
}

// ---------------- Q+K projections: 256x64 block tile, 2-deep prefetch ---------
// 4 waves x (64 rows x 64 cols): per k-step 8 loads -> 16 MFMA (ratio 2.0),
// 4x independent MFMA chains; W panel L1-shared. ~140 VGPR, no cap.
__global__ __launch_bounds__(256) void k_projQK(const bf16_t* __restrict__ A,
                                                const bf16_t* __restrict__ W,
                                                bf16_t* __restrict__ outb) {
  const int lane = threadIdx.x & 63, w = threadIdx.x >> 6;
  const int lr = lane & 15, lg = lane >> 4;
  const size_t zo = (size_t)blockIdx.z * ((size_t)MTOK * Dm);
  A += zo;
  W += (size_t)blockIdx.z * ((size_t)Dm * Dm);
  outb += zo;
  // bijective chunked XCD swizzle (nwg=256, chunk=32)
  const int orig = blockIdx.x + blockIdx.y * 8;
  const int swz = ((orig & 7) << 5) | (orig >> 3);
  const int Rbase = (swz >> 3) * 256 + w * 64;   // wave-private 64 rows
  const int Cbase = (swz & 7) * 64;              // block-shared 64 cols

  f32x4 acc[4][4] = {};
  bf16x8 afA[4], wfA[4], afB[4], wfB[4];
  auto loadF = [&](bf16x8 (&af)[4], bf16x8 (&wf)[4], int k0) {
#pragma unroll
    for (int i = 0; i < 4; ++i)
      af[i] = *reinterpret_cast<const bf16x8*>(A + (size_t)(Rbase + i * 16 + lr) * Dm + k0 + lg * 8);
#pragma unroll
    for (int j = 0; j < 4; ++j)
      wf[j] = *reinterpret_cast<const bf16x8*>(W + (size_t)(Cbase + j * 16 + lr) * Dm + k0 + lg * 8);
  };
  auto domfma = [&](const bf16x8 (&af)[4], const bf16x8 (&wf)[4]) {
#pragma unroll
    for (int i = 0; i < 4; ++i)
#pragma unroll
      for (int j = 0; j < 4; ++j)
        acc[i][j] = __builtin_amdgcn_mfma_f32_16x16x32_bf16(af[i], wf[j], acc[i][j], 0, 0, 0);
  };
  loadF(afA, wfA, 0);
#pragma unroll
  for (int k0 = 0; k0 < Dm; k0 += 64) {
    loadF(afB, wfB, k0 + 32);
    domfma(afA, wfA);
    if (k0 + 64 < Dm) loadF(afA, wfA, k0 + 64);
    domfma(afB, wfB);
  }
#pragma unroll
  for (int i = 0; i < 4; ++i)
#pragma unroll
    for (int j = 0; j < 4; ++j)
#pragma unroll
      for (int r = 0; r < 4; ++r) {
        const int gr = Rbase + i * 16 + lg * 4 + r;  // token row
        const int gc = Cbase + j * 16 + lr;          // output col
        const int bb = gr >> 10, qq = gr & 1023, hh = gc >> 6, dd = gc & 63;
        outb[(((size_t)(bb * Hh + hh)) * Lseq + qq) * DKd + dd] = (bf16_t)acc[i][j][r];
      }
}

// ---------------- V projection: 256x64 tile + prefetch + LDS-transpose --------
// Tile [256 qq][64 dd]; stage into Vl[64 dd][264] (2-way bank alias = free),
// then 256 threads store 128B contiguous each into Vt[dd][qq].
__global__ __launch_bounds__(256) void k_projV(const bf16_t* __restrict__ A,
                                               const bf16_t* __restrict__ W,
                                               bf16_t* __restrict__ outb) {
  __shared__ bf16_t Vl[64][264];
  const int lane = threadIdx.x & 63, w = threadIdx.x >> 6;
  const int lr = lane & 15, lg = lane >> 4;
  // bijective chunked XCD swizzle (nwg=256, chunk=32)
  const int orig = blockIdx.x + blockIdx.y * 8;
  const int swz = ((orig & 7) << 5) | (orig >> 3);
  const int Rtile = (swz >> 3) * 256;            // 1024%256==0: no batch cross
  const int Rbase = Rtile + w * 64;
  const int Cbase = (swz & 7) * 64;

  f32x4 acc[4][4] = {};
  bf16x8 afA[4], wfA[4], afB[4], wfB[4];
  auto loadF = [&](bf16x8 (&af)[4], bf16x8 (&wf)[4], int k0) {
#pragma unroll
    for (int i = 0; i < 4; ++i)
      af[i] = *reinterpret_cast<const bf16x8*>(A + (size_t)(Rbase + i * 16 + lr) * Dm + k0 + lg * 8);
#pragma unroll
    for (int j = 0; j < 4; ++j)
      wf[j] = *reinterpret_cast<const bf16x8*>(W + (size_t)(Cbase + j * 16 + lr) * Dm + k0 + lg * 8);
  };
  auto domfma = [&](const bf16x8 (&af)[4], const bf16x8 (&wf)[4]) {
#pragma unroll
    for (int i = 0; i < 4; ++i)
#pragma unroll
      for (int j = 0; j < 4; ++j)
        acc[i][j] = __builtin_amdgcn_mfma_f32_16x16x32_bf16(af[i], wf[j], acc[i][j], 0, 0, 0);
  };
  loadF(afA, wfA, 0);
#pragma unroll
  for (int k0 = 0; k0 < Dm; k0 += 64) {
    loadF(afB, wfB, k0 + 32);
    domfma(afA, wfA);
    if (k0 + 64 < Dm) loadF(afA, wfA, k0 + 64);
    domfma(afB, wfB);
  }
  // stage tile transposed into LDS: Vl[dd_local][qq_local]
#pragma unroll
  for (int i = 0; i < 4; ++i)
#pragma unroll
    for (int j = 0; j < 4; ++j)
#pragma unroll
      for (int r = 0; r < 4; ++r) {
        const int grl = w * 64 + i * 16 + lg * 4 + r;  // qq local 0..255
        const int gcl = j * 16 + lr;                   // dd local 0..63
        Vl[gcl][grl] = (bf16_t)acc[i][j][r];
      }
  __syncthreads();
  // cooperative coalesced store: thread -> (dd = tid/4, 64-qq chunk = 128B)
  const int tid = threadIdx.x;
  const int dd = tid >> 2, qq0 = (tid & 3) * 64;
  const int bb = Rtile >> 10, qrow = Rtile & 1023, hh = swz & 7;
  bf16_t* dst = outb + (((size_t)(bb * Hh + hh)) * DKd + dd) * Lseq + qrow + qq0;
#pragma unroll
  for (int c = 0; c < 8; ++c)
    *reinterpret_cast<bf16x8*>(dst + c * 8) =
        *reinterpret_cast<const bf16x8*>(&Vl[dd][qq0 + c * 8]);
}

// ---------------- fc GEMM: 256x64 tile + prefetch, bf16 out + resid -----------
__global__ __launch_bounds__(256) void k_fc(const bf16_t* __restrict__ A,
                                            const bf16_t* __restrict__ W,
                                            bf16_t* __restrict__ yb,
                                            const float* __restrict__ resid) {
  const int lane = threadIdx.x & 63, w = threadIdx.x >> 6;
  const int lr = lane & 15, lg = lane >> 4;
  // bijective chunked XCD swizzle (nwg=256, chunk=32)
  const int orig = blockIdx.x + blockIdx.y * 8;
  const int swz = ((orig & 7) << 5) | (orig >> 3);
  const int Rbase = (swz >> 3) * 256 + w * 64;
  const int Cbase = (swz & 7) * 64;

  f32x4 acc[4][4] = {};
  bf16x8 afA[4], wfA[4], afB[4], wfB[4];
  auto loadF = [&](bf16x8 (&af)[4], bf16x8 (&wf)[4], int k0) {
#pragma unroll
    for (int i = 0; i < 4; ++i)
      af[i] = *reinterpret_cast<const bf16x8*>(A + (size_t)(Rbase + i * 16 + lr) * Dm + k0 + lg * 8);
#pragma unroll
    for (int j = 0; j < 4; ++j)
      wf[j] = *reinterpret_cast<const bf16x8*>(W + (size_t)(Cbase + j * 16 + lr) * Dm + k0 + lg * 8);
  };
  auto domfma = [&](const bf16x8 (&af)[4], const bf16x8 (&wf)[4]) {
#pragma unroll
    for (int i = 0; i < 4; ++i)
#pragma unroll
      for (int j = 0; j < 4; ++j)
        acc[i][j] = __builtin_amdgcn_mfma_f32_16x16x32_bf16(af[i], wf[j], acc[i][j], 0, 0, 0);
  };
  loadF(afA, wfA, 0);
#pragma unroll
  for (int k0 = 0; k0 < Dm; k0 += 64) {
    loadF(afB, wfB, k0 + 32);
    domfma(afA, wfA);
    if (k0 + 64 < Dm) loadF(afA, wfA, k0 + 64);
    domfma(afB, wfB);
  }
#pragma unroll
  for (int i = 0; i < 4; ++i)
#pragma unroll
    for (int j = 0; j < 4; ++j)
#pragma unroll
      for (int r = 0; r < 4; ++r) {
        const int gr = Rbase + i * 16 + lg * 4 + r;
        const int gc = Cbase + j * 16 + lr;
        const size_t idx = (size_t)gr * Dm + gc;
        yb[idx] = (bf16_t)(acc[i][j][r] + resid[idx]);
      }
}

// ---------------- flash attention + fused in-block posdot (84us, stable) ------
__global__ __launch_bounds__(256, 4) void k_attn(const bf16_t* __restrict__ Qh,
                                                 const bf16_t* __restrict__ Kh,
                                                 const bf16_t* __restrict__ Vt,
                                                 const bf16_t* __restrict__ relb,
                                                 bf16_t* __restrict__ attnb) {
  __shared__ float smemf[6528];   // pos 12928B + Pl 10240B = 23168B; Ml 26112B

  const int tid = threadIdx.x;
  const int wv = tid >> 6, lane = tid & 63;
  const int lr = lane & 15, lg = lane >> 4;
  // bijective chunked XCD swizzle (nwg=2048, chunk=256)
  const int gid = ((blockIdx.x & 7) << 8) | (blockIdx.x >> 3);
  const int bh = gid >> 5;
  const int qb = (gid & 31) << 5;             // 32-row q tile

  unsigned short* pls = reinterpret_cast<unsigned short*>(smemf);     // [32][202]
  unsigned* Pw = reinterpret_cast<unsigned*>(smemf) + 3232 + wv * 640; // [2][16][20]

  const bf16_t* Qp = Qh + ((size_t)bh * Lseq + qb) * DKd;
  const bf16_t* Kp = Kh + (size_t)bh * Lseq * DKd;
  const bf16_t* Vp = Vt + (size_t)bh * DKd * Lseq;

  // Q fragments (dual-use: B-operand for swapped QK^T, A-operand for posdot)
  bf16x8 qf[2][2];
#pragma unroll
  for (int t = 0; t < 2; ++t)
#pragma unroll
    for (int h = 0; h < 2; ++h)
      qf[t][h] = *reinterpret_cast<const bf16x8*>(Qp + (size_t)(t * 16 + lr) * DKd + h * 32 + lg * 8);

  // ---- in-block posdot: pls[q][200-r] = POS_C * dot(Q[q], rel[r]) -----------
  for (int n = wv; n < 13; n += 4) {
    const int rr0 = n * 16 + lr;
    const int rclamp = rr0 > 200 ? 200 : rr0;
    bf16x8 rf0 = *reinterpret_cast<const bf16x8*>(relb + (size_t)rclamp * DKd + lg * 8);
    bf16x8 rf1 = *reinterpret_cast<const bf16x8*>(relb + (size_t)rclamp * DKd + 32 + lg * 8);
#pragma unroll
    for (int t = 0; t < 2; ++t) {
      f32x4 st = {};
      st = __builtin_amdgcn_mfma_f32_16x16x32_bf16(qf[t][0], rf0, st, 0, 0, 0);
      st = __builtin_amdgcn_mfma_f32_16x16x32_bf16(qf[t][1], rf1, st, 0, 0, 0);
      if (rr0 <= 200) {
#pragma unroll
        for (int r = 0; r < 4; ++r)
          pls[(t * 16 + lg * 4 + r) * PROW + (200 - rr0)] =
              __builtin_bit_cast(unsigned short, (bf16_t)(st[r] * POS_C));
      }
    }
  }
  __syncthreads();

  // per-lane pos row bases + band-edge constants (already scaled by POS_C)
  const unsigned short* prow[2] = {pls + (size_t)lr * PROW,
                                   pls + (size_t)(16 + lr) * PROW};
  float pe0[2], pe200[2];
#pragma unroll
  for (int t = 0; t < 2; ++t) {
    pe0[t] = b2f(prow[t][0]);       // k <= q-100 side
    pe200[t] = b2f(prow[t][200]);   // k >= q+100 side
  }

  f32x4 Oacc[2][4] = {};
  float psum[2] = {0.f, 0.f};
  const int ldelta = lg * 4 - lr;

  const int kbase = wv * 256;
#pragma unroll 2
  for (int k0 = kbase; k0 < kbase + 256; k0 += 32) {
    bf16x8 kf[2][2];
#pragma unroll
    for (int u = 0; u < 2; ++u)
#pragma unroll
      for (int h = 0; h < 2; ++h)
        kf[u][h] = *reinterpret_cast<const bf16x8*>(Kp + (size_t)(k0 + u * 16 + lr) * DKd + h * 32 + lg * 8);

    __builtin_amdgcn_s_setprio(1);
#pragma unroll
    for (int t = 0; t < 2; ++t) {
      const int Qt = qb + t * 16;
      f32x4 st[2];
#pragma unroll
      for (int u = 0; u < 2; ++u) {
        f32x4 a = {};
        a = __builtin_amdgcn_mfma_f32_16x16x32_bf16(kf[u][0], qf[t][0], a, 0, 0, 0);
        a = __builtin_amdgcn_mfma_f32_16x16x32_bf16(kf[u][1], qf[t][1], a, 0, 0, 0);
        st[u] = a;  // element: q = Qt+lr (col), k = k0+u*16+lg*4+r (row)
      }
      float p[2][4];
      if (k0 + 131 <= Qt) {            // whole step below band: pos = pls[q][0]
#pragma unroll
        for (int u = 0; u < 2; ++u)
#pragma unroll
          for (int r = 0; r < 4; ++r)
            p[u][r] = fexp2(fmaf(st[u][r], POS_C, pe0[t]));
      } else if (k0 >= Qt + 115) {     // whole step above band: pos = pls[q][200]
#pragma unroll
        for (int u = 0; u < 2; ++u)
#pragma unroll
          for (int r = 0; r < 4; ++r)
            p[u][r] = fexp2(fmaf(st[u][r], POS_C, pe200[t]));
      } else {                         // in-band: clamped gather from LDS
#pragma unroll
        for (int u = 0; u < 2; ++u) {
          const int jb = k0 + u * 16 + 100 - Qt + ldelta;
#pragma unroll
          for (int r = 0; r < 4; ++r) {
            int j = jb + r;
            j = j < 0 ? 0 : (j > 200 ? 200 : j);
            p[u][r] = fexp2(fmaf(st[u][r], POS_C, b2f(prow[t][j])));
          }
        }
      }
#pragma unroll
      for (int u = 0; u < 2; ++u)
#pragma unroll
        for (int r = 0; r < 4; ++r) psum[t] += p[u][r];
      // pack to bf16, wave-private LDS transpose (D-layout -> B-frag layout)
#pragma unroll
      for (int u = 0; u < 2; ++u) {
        uint2 pk;
        pk.x = pack2(p[u][0], p[u][1]);
        pk.y = pack2(p[u][2], p[u][3]);
        *reinterpret_cast<uint2*>(&Pw[t * 320 + lr * 20 + u * 8 + lg * 2]) = pk;
      }
    }
    // PV: A = Vt fragment, B = P fragment read back from LDS
    bf16x8 pb[2];
#pragma unroll
    for (int t = 0; t < 2; ++t)
      pb[t] = *reinterpret_cast<const bf16x8*>(&Pw[t * 320 + lr * 20 + lg * 4]);
#pragma unroll
    for (int f = 0; f < 4; ++f) {
      bf16x8 vf = *reinterpret_cast<const bf16x8*>(Vp + (size_t)(f * 16 + lr) * Lseq + k0 + lg * 8);
#pragma unroll
      for (int t = 0; t < 2; ++t)
        Oacc[t][f] = __builtin_amdgcn_mfma_f32_16x16x32_bf16(vf, pb[t], Oacc[t][f], 0, 0, 0);
    }
    __builtin_amdgcn_s_setprio(0);
  }

  // ---- merge the four k-quarters (no-max partials combine by pure addition) --
  __syncthreads();   // k-loops done; pos+Pl dead -> reuse smem as Ml[3][64][34]
  float* Ml = smemf;
  if (wv) {
    float* m = Ml + ((wv - 1) * 64 + lane) * 34;
#pragma unroll
    for (int t = 0; t < 2; ++t)
#pragma unroll
      for (int f = 0; f < 4; ++f)
#pragma unroll
        for (int r = 0; r < 4; ++r) m[t * 16 + f * 4 + r] = Oacc[t][f][r];
    m[32] = psum[0];
    m[33] = psum[1];
  }
  __syncthreads();
  if (!wv) {
#pragma unroll
    for (int w2 = 0; w2 < 3; ++w2) {
      const float* m = Ml + (w2 * 64 + lane) * 34;
#pragma unroll
      for (int t = 0; t < 2; ++t) {
#pragma unroll
        for (int f = 0; f < 4; ++f)
#pragma unroll
          for (int r = 0; r < 4; ++r) Oacc[t][f][r] += m[t * 16 + f * 4 + r];
        psum[t] += m[32 + t];
      }
    }
    const int gb = bh >> 3, hh = bh & 7;
#pragma unroll
    for (int t = 0; t < 2; ++t) {
      float s = psum[t];
      s += __shfl_xor(s, 16);
      s += __shfl_xor(s, 32);
      const float inv = 1.0f / s;
      const int qg = qb + t * 16 + lr;
#pragma unroll
      for (int f = 0; f < 4; ++f) {
        uint2 ov;
        ov.x = pack2(Oacc[t][f][0] * inv, Oacc[t][f][1] * inv);
        ov.y = pack2(Oacc[t][f][2] * inv, Oacc[t][f][3] * inv);
        *reinterpret_cast<uint2*>(attnb + ((size_t)(gb * Lseq + qg)) * Dm + hh * DKd + f * 16 + lg * 4) = ov;
      }
    }
  }
}

// ---------------- row LayerNorm over D=512, bf16 input ------------------------
__global__ __launch_bounds__(256) void k_ln(const bf16_t* __restrict__ y,
                                            const float* __restrict__ g,
                                            const float* __restrict__ be,
                                            float* __restrict__ out) {
  const int row = blockIdx.x * 4 + (threadIdx.x >> 6);
  const int lane = threadIdx.x & 63;
  bf16x8 rv = *reinterpret_cast<const bf16x8*>(y + (size_t)row * Dm + lane * 8);
  float vv[8];
#pragma unroll
  for (int j = 0; j < 8; ++j) vv[j] = (float)rv[j];
  float s = 0.f, s2 = 0.f;
#pragma unroll
  for (int j = 0; j < 8; ++j) { s += vv[j]; s2 += vv[j] * vv[j]; }
  for (int mk = 1; mk < 64; mk <<= 1) {
    s += __shfl_xor(s, mk, 64);
    s2 += __shfl_xor(s2, mk, 64);
  }
  const float mu = s * (1.0f / Dm);
  const float var = s2 * (1.0f / Dm) - mu * mu;
  const float inv = rsqrtf(var + 1e-6f);
  float* op = out + (size_t)row * Dm + lane * 8;
  const float* gp = g + lane * 8;
  const float* bp = be + lane * 8;
#pragma unroll
  for (int j = 0; j < 8; ++j) op[j] = (vv[j] - mu) * inv * gp[j] + bp[j];
}

// ------------------------------------------------------------------------------
extern "C" void kernel_launch(void* const* d_in, const int* in_sizes, int n_in,
                              void* d_out, int out_size, void* d_ws, size_t ws_size,
                              hipStream_t stream) {
  const float* q   = (const float*)d_in[0];
  const float* k   = (const float*)d_in[1];
  const float* v   = (const float*)d_in[2];
  const float* Wq  = (const float*)d_in[3];
  const float* Wk  = (const float*)d_in[4];
  const float* Wv  = (const float*)d_in[5];
  const float* Wfc = (const float*)d_in[6];
  const float* rel = (const float*)d_in[7];
  const float* gam = (const float*)d_in[8];
  const float* bet = (const float*)d_in[9];

  char* ws = (char*)d_ws;
  size_t off = 0;
  auto take = [&](size_t bytes) {
    char* p = ws + off;
    off += (bytes + 255) & ~(size_t)255;
    return p;
  };
  // NOTE: wqb/wkb contiguous, qb/kb contiguous, Qhp/Khp contiguous —
  // required by the z=2 Q+K projection launch (pure offset arithmetic).
  bf16_t* wqb  = (bf16_t*)take((size_t)Dm * Dm * 2);
  bf16_t* wkb  = (bf16_t*)take((size_t)Dm * Dm * 2);
  bf16_t* wvb  = (bf16_t*)take((size_t)Dm * Dm * 2);
  bf16_t* wfcb = (bf16_t*)take((size_t)Dm * Dm * 2);
  bf16_t* relb = (bf16_t*)take((size_t)NREL * DKd * 2);
  bf16_t* qb   = (bf16_t*)take((size_t)MTOK * Dm * 2);
  bf16_t* kb   = (bf16_t*)take((size_t)MTOK * Dm * 2);
  bf16_t* vb   = (bf16_t*)take((size_t)MTOK * Dm * 2);
  bf16_t* Qhp  = (bf16_t*)take((size_t)MTOK * Dm * 2);
  bf16_t* Khp  = (bf16_t*)take((size_t)MTOK * Dm * 2);
  bf16_t* Vtp  = (bf16_t*)take((size_t)MTOK * Dm * 2);
  bf16_t* attnb= (bf16_t*)take((size_t)MTOK * Dm * 2);
  bf16_t* yb   = (bf16_t*)take((size_t)MTOK * Dm * 2);

  // 1) ALL casts (q/k/v + 4 weights + rel) in one launch
  k_cast_all<<<dim3(2048, 4), 256, 0, stream>>>(
      q, k, v, Wq, Wk, Wv, Wfc, rel, qb, kb, vb, wqb, wkb, wvb, wfcb, relb);
  // 2) Q+K projections (256x64 tile, z=2, prefetch)
  k_projQK<<<dim3(8, 32, 2), 256, 0, stream>>>(qb, wqb, Qhp);
  // 3) V projection (256x64 tile, prefetch + LDS-transpose coalesced store)
  k_projV<<<dim3(8, 32), 256, 0, stream>>>(vb, wvb, Vtp);
  // 4) attention (posdot fused in-block; stable 84us)
  k_attn<<<dim3(2048), 256, 0, stream>>>(Qhp, Khp, Vtp, relb, attnb);
  // 5) output GEMM + residual (256x64 tile, bf16 yb)
  k_fc<<<dim3(8, 32), 256, 0, stream>>>(attnb, wfcb, yb, q);
  // 6) LayerNorm (bf16 input)
  k_ln<<<dim3(MTOK / 4), 256, 0, stream>>>(yb, gam, bet, (float*)d_out);
}

// Round 28
// 170.390 us; speedup vs baseline: 1.4845x; 1.0320x over previous
//
#include <hip/hip_runtime.h>
#include <hip/hip_bf16.h>

typedef __bf16 bf16_t;
typedef __bf16 bf16x8 __attribute__((ext_vector_type(8)));
typedef float f32x4 __attribute__((ext_vector_type(4)));

constexpr int Bz = 8, Lseq = 1024, Dm = 512, Hh = 8, DKd = 64;
constexpr int MTOK = Bz * Lseq;   // 8192 tokens
constexpr int NREL = 201;
constexpr int PROW = 202;         // padded LDS row (bank stride 101%32=5, coprime)

// pos pre-scale: 0.125 (1/sqrt(dk)) * log2(e), folded so p = exp2(st*C + pos)
#define POS_C 0.18033688011112042f

__device__ inline float fexp2(float x) {
#if __has_builtin(__builtin_amdgcn_exp2f)
  return __builtin_amdgcn_exp2f(x);
#else
  return exp2f(x);
#endif
}
__device__ inline float b2f(unsigned short u) {
  return __builtin_bit_cast(float, (unsigned)u << 16);
}
__device__ inline unsigned pack2(float a, float b) {
  unsigned short ua = __builtin_bit_cast(unsigned short, (bf16_t)a);
  unsigned short ub = __builtin_bit_cast(unsigned short, (bf16_t)b);
  return (unsigned)ua | ((unsigned)ub << 16);
}

// ---------------- ONE launch for ALL casts ------------------------------------
__global__ __launch_bounds__(256) void k_cast_all(
    const float* __restrict__ q, const float* __restrict__ k,
    const float* __restrict__ v, const float* __restrict__ w0,
    const float* __restrict__ w1, const float* __restrict__ w2,
    const float* __restrict__ w3, const float* __restrict__ rel,
    bf16_t* __restrict__ qb, bf16_t* __restrict__ kb, bf16_t* __restrict__ vb,
    bf16_t* __restrict__ d0, bf16_t* __restrict__ d1, bf16_t* __restrict__ d2,
    bf16_t* __restrict__ d3, bf16_t* __restrict__ drel) {
  const int y = blockIdx.y;
  if (y < 3) {
    const float* s = y == 0 ? q : y == 1 ? k : v;
    bf16_t* d = y == 0 ? qb : y == 1 ? kb : vb;
    const int i = (blockIdx.x * 256 + threadIdx.x) * 8;
    float4 a = *reinterpret_cast<const float4*>(s + i);
    float4 b = *reinterpret_cast<const float4*>(s + i + 4);
    bf16x8 r;
    r[0] = (bf16_t)a.x; r[1] = (bf16_t)a.y; r[2] = (bf16_t)a.z; r[3] = (bf16_t)a.w;
    r[4] = (bf16_t)b.x; r[5] = (bf16_t)b.y; r[6] = (bf16_t)b.z; r[7] = (bf16_t)b.w;
    *reinterpret_cast<bf16x8*>(d + i) = r;
  } else {
    const int x = blockIdx.x;
    if (x < 1024) {
      const int wsel = x >> 8;
      const float* s = wsel == 0 ? w0 : wsel == 1 ? w1 : wsel == 2 ? w2 : w3;
      bf16_t* d = wsel == 0 ? d0 : wsel == 1 ? d1 : wsel == 2 ? d2 : d3;
      const int i = ((x & 255) * 256 + threadIdx.x) * 4;
      float4 vv = *reinterpret_cast<const float4*>(s + i);
      d[i + 0] = (bf16_t)vv.x;
      d[i + 1] = (bf16_t)vv.y;
      d[i + 2] = (bf16_t)vv.z;
      d[i + 3] = (bf16_t)vv.w;
    } else if (x < 1037) {
      const int i = ((x - 1024) * 256 + threadIdx.x) * 4;
      if (i < NREL * DKd) {
        float4 vv = *reinterpret_cast<const float4*>(rel + i);
        drel[i + 0] = (bf16_t)vv.x;
        drel[i + 1] = (bf16_t)vv.y;
        drel[i + 2] = (bf16_t)vv.z;
        drel[i + 3] = (bf16_t)vv.w;
      }
    }
  }
}

// ---------------- ALL projections: one z=3 launch, 256x64 tile, prefetch ------
// z in {0,1,2} = Q,K,V via pure offset arithmetic (qb/kb/vb, wqb/wkb/wvb,
// Qhp/Khp/Vtp contiguous in ws). Identical main loop (ratio 2.0, 16 MFMA
// chains/wave); only the UNIFORM epilogue branches: z<2 head-major store,
// z==2 LDS-transpose coalesced store. 768 blocks = 3/CU machine fill.
__global__ __launch_bounds__(256) void k_proj3(const bf16_t* __restrict__ A,
                                               const bf16_t* __restrict__ W,
                                               bf16_t* __restrict__ outb) {
  __shared__ bf16_t Vl[64][264];   // used only by z==2 path
  const int lane = threadIdx.x & 63, w = threadIdx.x >> 6;
  const int lr = lane & 15, lg = lane >> 4;
  const int z = blockIdx.z;
  const size_t zo = (size_t)z * ((size_t)MTOK * Dm);
  A += zo;
  W += (size_t)z * ((size_t)Dm * Dm);
  outb += zo;
  // bijective chunked XCD swizzle (nwg=256, chunk=32)
  const int orig = blockIdx.x + blockIdx.y * 8;
  const int swz = ((orig & 7) << 5) | (orig >> 3);
  const int Rtile = (swz >> 3) * 256;            // 1024%256==0: no batch cross
  const int Rbase = Rtile + w * 64;              // wave-private 64 rows
  const int Cbase = (swz & 7) * 64;              // block-shared 64 cols

  f32x4 acc[4][4] = {};
  bf16x8 afA[4], wfA[4], afB[4], wfB[4];
  auto loadF = [&](bf16x8 (&af)[4], bf16x8 (&wf)[4], int k0) {
#pragma unroll
    for (int i = 0; i < 4; ++i)
      af[i] = *reinterpret_cast<const bf16x8*>(A + (size_t)(Rbase + i * 16 + lr) * Dm + k0 + lg * 8);
#pragma unroll
    for (int j = 0; j < 4; ++j)
      wf[j] = *reinterpret_cast<const bf16x8*>(W + (size_t)(Cbase + j * 16 + lr) * Dm + k0 + lg * 8);
  };
  auto domfma = [&](const bf16x8 (&af)[4], const bf16x8 (&wf)[4]) {
#pragma unroll
    for (int i = 0; i < 4; ++i)
#pragma unroll
      for (int j = 0; j < 4; ++j)
        acc[i][j] = __builtin_amdgcn_mfma_f32_16x16x32_bf16(af[i], wf[j], acc[i][j], 0, 0, 0);
  };
  loadF(afA, wfA, 0);
#pragma unroll
  for (int k0 = 0; k0 < Dm; k0 += 64) {
    loadF(afB, wfB, k0 + 32);
    domfma(afA, wfA);
    if (k0 + 64 < Dm) loadF(afA, wfA, k0 + 64);
    domfma(afB, wfB);
  }

  if (z < 2) {
    // Q/K: head-major store
#pragma unroll
    for (int i = 0; i < 4; ++i)
#pragma unroll
      for (int j = 0; j < 4; ++j)
#pragma unroll
        for (int r = 0; r < 4; ++r) {
          const int gr = Rbase + i * 16 + lg * 4 + r;  // token row
          const int gc = Cbase + j * 16 + lr;          // output col
          const int bb = gr >> 10, qq = gr & 1023, hh = gc >> 6, dd = gc & 63;
          outb[(((size_t)(bb * Hh + hh)) * Lseq + qq) * DKd + dd] = (bf16_t)acc[i][j][r];
        }
  } else {
    // V: stage tile transposed into LDS: Vl[dd_local][qq_local]
#pragma unroll
    for (int i = 0; i < 4; ++i)
#pragma unroll
      for (int j = 0; j < 4; ++j)
#pragma unroll
        for (int r = 0; r < 4; ++r) {
          const int grl = w * 64 + i * 16 + lg * 4 + r;  // qq local 0..255
          const int gcl = j * 16 + lr;                   // dd local 0..63
          Vl[gcl][grl] = (bf16_t)acc[i][j][r];
        }
    __syncthreads();
    // cooperative coalesced store: thread -> (dd = tid/4, 64-qq chunk = 128B)
    const int tid = threadIdx.x;
    const int dd = tid >> 2, qq0 = (tid & 3) * 64;
    const int bb = Rtile >> 10, qrow = Rtile & 1023, hh = swz & 7;
    bf16_t* dst = outb + (((size_t)(bb * Hh + hh)) * DKd + dd) * Lseq + qrow + qq0;
#pragma unroll
    for (int c = 0; c < 8; ++c)
      *reinterpret_cast<bf16x8*>(dst + c * 8) =
          *reinterpret_cast<const bf16x8*>(&Vl[dd][qq0 + c * 8]);
  }
}

// ---------------- fc GEMM: 256x64 tile + prefetch, bf16 out + resid -----------
__global__ __launch_bounds__(256) void k_fc(const bf16_t* __restrict__ A,
                                            const bf16_t* __restrict__ W,
                                            bf16_t* __restrict__ yb,
                                            const float* __restrict__ resid) {
  const int lane = threadIdx.x & 63, w = threadIdx.x >> 6;
  const int lr = lane & 15, lg = lane >> 4;
  // bijective chunked XCD swizzle (nwg=256, chunk=32)
  const int orig = blockIdx.x + blockIdx.y * 8;
  const int swz = ((orig & 7) << 5) | (orig >> 3);
  const int Rbase = (swz >> 3) * 256 + w * 64;
  const int Cbase = (swz & 7) * 64;

  f32x4 acc[4][4] = {};
  bf16x8 afA[4], wfA[4], afB[4], wfB[4];
  auto loadF = [&](bf16x8 (&af)[4], bf16x8 (&wf)[4], int k0) {
#pragma unroll
    for (int i = 0; i < 4; ++i)
      af[i] = *reinterpret_cast<const bf16x8*>(A + (size_t)(Rbase + i * 16 + lr) * Dm + k0 + lg * 8);
#pragma unroll
    for (int j = 0; j < 4; ++j)
      wf[j] = *reinterpret_cast<const bf16x8*>(W + (size_t)(Cbase + j * 16 + lr) * Dm + k0 + lg * 8);
  };
  auto domfma = [&](const bf16x8 (&af)[4], const bf16x8 (&wf)[4]) {
#pragma unroll
    for (int i = 0; i < 4; ++i)
#pragma unroll
      for (int j = 0; j < 4; ++j)
        acc[i][j] = __builtin_amdgcn_mfma_f32_16x16x32_bf16(af[i], wf[j], acc[i][j], 0, 0, 0);
  };
  loadF(afA, wfA, 0);
#pragma unroll
  for (int k0 = 0; k0 < Dm; k0 += 64) {
    loadF(afB, wfB, k0 + 32);
    domfma(afA, wfA);
    if (k0 + 64 < Dm) loadF(afA, wfA, k0 + 64);
    domfma(afB, wfB);
  }
#pragma unroll
  for (int i = 0; i < 4; ++i)
#pragma unroll
    for (int j = 0; j < 4; ++j)
#pragma unroll
      for (int r = 0; r < 4; ++r) {
        const int gr = Rbase + i * 16 + lg * 4 + r;
        const int gc = Cbase + j * 16 + lr;
        const size_t idx = (size_t)gr * Dm + gc;
        yb[idx] = (bf16_t)(acc[i][j][r] + resid[idx]);
      }
}

// ---------------- flash attention + fused in-block posdot (84us, stable) ------
__global__ __launch_bounds__(256, 4) void k_attn(const bf16_t* __restrict__ Qh,
                                                 const bf16_t* __restrict__ Kh,
                                                 const bf16_t* __restrict__ Vt,
                                                 const bf16_t* __restrict__ relb,
                                                 bf16_t* __restrict__ attnb) {
  __shared__ float smemf[6528];   // pos 12928B + Pl 10240B = 23168B; Ml 26112B

  const int tid = threadIdx.x;
  const int wv = tid >> 6, lane = tid & 63;
  const int lr = lane & 15, lg = lane >> 4;
  // bijective chunked XCD swizzle (nwg=2048, chunk=256)
  const int gid = ((blockIdx.x & 7) << 8) | (blockIdx.x >> 3);
  const int bh = gid >> 5;
  const int qb = (gid & 31) << 5;             // 32-row q tile

  unsigned short* pls = reinterpret_cast<unsigned short*>(smemf);     // [32][202]
  unsigned* Pw = reinterpret_cast<unsigned*>(smemf) + 3232 + wv * 640; // [2][16][20]

  const bf16_t* Qp = Qh + ((size_t)bh * Lseq + qb) * DKd;
  const bf16_t* Kp = Kh + (size_t)bh * Lseq * DKd;
  const bf16_t* Vp = Vt + (size_t)bh * DKd * Lseq;

  // Q fragments (dual-use: B-operand for swapped QK^T, A-operand for posdot)
  bf16x8 qf[2][2];
#pragma unroll
  for (int t = 0; t < 2; ++t)
#pragma unroll
    for (int h = 0; h < 2; ++h)
      qf[t][h] = *reinterpret_cast<const bf16x8*>(Qp + (size_t)(t * 16 + lr) * DKd + h * 32 + lg * 8);

  // ---- in-block posdot: pls[q][200-r] = POS_C * dot(Q[q], rel[r]) -----------
  for (int n = wv; n < 13; n += 4) {
    const int rr0 = n * 16 + lr;
    const int rclamp = rr0 > 200 ? 200 : rr0;
    bf16x8 rf0 = *reinterpret_cast<const bf16x8*>(relb + (size_t)rclamp * DKd + lg * 8);
    bf16x8 rf1 = *reinterpret_cast<const bf16x8*>(relb + (size_t)rclamp * DKd + 32 + lg * 8);
#pragma unroll
    for (int t = 0; t < 2; ++t) {
      f32x4 st = {};
      st = __builtin_amdgcn_mfma_f32_16x16x32_bf16(qf[t][0], rf0, st, 0, 0, 0);
      st = __builtin_amdgcn_mfma_f32_16x16x32_bf16(qf[t][1], rf1, st, 0, 0, 0);
      if (rr0 <= 200) {
#pragma unroll
        for (int r = 0; r < 4; ++r)
          pls[(t * 16 + lg * 4 + r) * PROW + (200 - rr0)] =
              __builtin_bit_cast(unsigned short, (bf16_t)(st[r] * POS_C));
      }
    }
  }
  __syncthreads();

  // per-lane pos row bases + band-edge constants (already scaled by POS_C)
  const unsigned short* prow[2] = {pls + (size_t)lr * PROW,
                                   pls + (size_t)(16 + lr) * PROW};
  float pe0[2], pe200[2];
#pragma unroll
  for (int t = 0; t < 2; ++t) {
    pe0[t] = b2f(prow[t][0]);       // k <= q-100 side
    pe200[t] = b2f(prow[t][200]);   // k >= q+100 side
  }

  f32x4 Oacc[2][4] = {};
  float psum[2] = {0.f, 0.f};
  const int ldelta = lg * 4 - lr;

  const int kbase = wv * 256;
#pragma unroll 2
  for (int k0 = kbase; k0 < kbase + 256; k0 += 32) {
    bf16x8 kf[2][2];
#pragma unroll
    for (int u = 0; u < 2; ++u)
#pragma unroll
      for (int h = 0; h < 2; ++h)
        kf[u][h] = *reinterpret_cast<const bf16x8*>(Kp + (size_t)(k0 + u * 16 + lr) * DKd + h * 32 + lg * 8);

    __builtin_amdgcn_s_setprio(1);
#pragma unroll
    for (int t = 0; t < 2; ++t) {
      const int Qt = qb + t * 16;
      f32x4 st[2];
#pragma unroll
      for (int u = 0; u < 2; ++u) {
        f32x4 a = {};
        a = __builtin_amdgcn_mfma_f32_16x16x32_bf16(kf[u][0], qf[t][0], a, 0, 0, 0);
        a = __builtin_amdgcn_mfma_f32_16x16x32_bf16(kf[u][1], qf[t][1], a, 0, 0, 0);
        st[u] = a;  // element: q = Qt+lr (col), k = k0+u*16+lg*4+r (row)
      }
      float p[2][4];
      if (k0 + 131 <= Qt) {            // whole step below band: pos = pls[q][0]
#pragma unroll
        for (int u = 0; u < 2; ++u)
#pragma unroll
          for (int r = 0; r < 4; ++r)
            p[u][r] = fexp2(fmaf(st[u][r], POS_C, pe0[t]));
      } else if (k0 >= Qt + 115) {     // whole step above band: pos = pls[q][200]
#pragma unroll
        for (int u = 0; u < 2; ++u)
#pragma unroll
          for (int r = 0; r < 4; ++r)
            p[u][r] = fexp2(fmaf(st[u][r], POS_C, pe200[t]));
      } else {                         // in-band: clamped gather from LDS
#pragma unroll
        for (int u = 0; u < 2; ++u) {
          const int jb = k0 + u * 16 + 100 - Qt + ldelta;
#pragma unroll
          for (int r = 0; r < 4; ++r) {
            int j = jb + r;
            j = j < 0 ? 0 : (j > 200 ? 200 : j);
            p[u][r] = fexp2(fmaf(st[u][r], POS_C, b2f(prow[t][j])));
          }
        }
      }
#pragma unroll
      for (int u = 0; u < 2; ++u)
#pragma unroll
        for (int r = 0; r < 4; ++r) psum[t] += p[u][r];
      // pack to bf16, wave-private LDS transpose (D-layout -> B-frag layout)
#pragma unroll
      for (int u = 0; u < 2; ++u) {
        uint2 pk;
        pk.x = pack2(p[u][0], p[u][1]);
        pk.y = pack2(p[u][2], p[u][3]);
        *reinterpret_cast<uint2*>(&Pw[t * 320 + lr * 20 + u * 8 + lg * 2]) = pk;
      }
    }
    // PV: A = Vt fragment, B = P fragment read back from LDS
    bf16x8 pb[2];
#pragma unroll
    for (int t = 0; t < 2; ++t)
      pb[t] = *reinterpret_cast<const bf16x8*>(&Pw[t * 320 + lr * 20 + lg * 4]);
#pragma unroll
    for (int f = 0; f < 4; ++f) {
      bf16x8 vf = *reinterpret_cast<const bf16x8*>(Vp + (size_t)(f * 16 + lr) * Lseq + k0 + lg * 8);
#pragma unroll
      for (int t = 0; t < 2; ++t)
        Oacc[t][f] = __builtin_amdgcn_mfma_f32_16x16x32_bf16(vf, pb[t], Oacc[t][f], 0, 0, 0);
    }
    __builtin_amdgcn_s_setprio(0);
  }

  // ---- merge the four k-quarters (no-max partials combine by pure addition) --
  __syncthreads();   // k-loops done; pos+Pl dead -> reuse smem as Ml[3][64][34]
  float* Ml = smemf;
  if (wv) {
    float* m = Ml + ((wv - 1) * 64 + lane) * 34;
#pragma unroll
    for (int t = 0; t < 2; ++t)
#pragma unroll
      for (int f = 0; f < 4; ++f)
#pragma unroll
        for (int r = 0; r < 4; ++r) m[t * 16 + f * 4 + r] = Oacc[t][f][r];
    m[32] = psum[0];
    m[33] = psum[1];
  }
  __syncthreads();
  if (!wv) {
#pragma unroll
    for (int w2 = 0; w2 < 3; ++w2) {
      const float* m = Ml + (w2 * 64 + lane) * 34;
#pragma unroll
      for (int t = 0; t < 2; ++t) {
#pragma unroll
        for (int f = 0; f < 4; ++f)
#pragma unroll
          for (int r = 0; r < 4; ++r) Oacc[t][f][r] += m[t * 16 + f * 4 + r];
        psum[t] += m[32 + t];
      }
    }
    const int gb = bh >> 3, hh = bh & 7;
#pragma unroll
    for (int t = 0; t < 2; ++t) {
      float s = psum[t];
      s += __shfl_xor(s, 16);
      s += __shfl_xor(s, 32);
      const float inv = 1.0f / s;
      const int qg = qb + t * 16 + lr;
#pragma unroll
      for (int f = 0; f < 4; ++f) {
        uint2 ov;
        ov.x = pack2(Oacc[t][f][0] * inv, Oacc[t][f][1] * inv);
        ov.y = pack2(Oacc[t][f][2] * inv, Oacc[t][f][3] * inv);
        *reinterpret_cast<uint2*>(attnb + ((size_t)(gb * Lseq + qg)) * Dm + hh * DKd + f * 16 + lg * 4) = ov;
      }
    }
  }
}

// ---------------- row LayerNorm over D=512, bf16 input ------------------------
__global__ __launch_bounds__(256) void k_ln(const bf16_t* __restrict__ y,
                                            const float* __restrict__ g,
                                            const float* __restrict__ be,
                                            float* __restrict__ out) {
  const int row = blockIdx.x * 4 + (threadIdx.x >> 6);
  const int lane = threadIdx.x & 63;
  bf16x8 rv = *reinterpret_cast<const bf16x8*>(y + (size_t)row * Dm + lane * 8);
  float vv[8];
#pragma unroll
  for (int j = 0; j < 8; ++j) vv[j] = (float)rv[j];
  float s = 0.f, s2 = 0.f;
#pragma unroll
  for (int j = 0; j < 8; ++j) { s += vv[j]; s2 += vv[j] * vv[j]; }
  for (int mk = 1; mk < 64; mk <<= 1) {
    s += __shfl_xor(s, mk, 64);
    s2 += __shfl_xor(s2, mk, 64);
  }
  const float mu = s * (1.0f / Dm);
  const float var = s2 * (1.0f / Dm) - mu * mu;
  const float inv = rsqrtf(var + 1e-6f);
  float* op = out + (size_t)row * Dm + lane * 8;
  const float* gp = g + lane * 8;
  const float* bp = be + lane * 8;
#pragma unroll
  for (int j = 0; j < 8; ++j) op[j] = (vv[j] - mu) * inv * gp[j] + bp[j];
}

// ------------------------------------------------------------------------------
extern "C" void kernel_launch(void* const* d_in, const int* in_sizes, int n_in,
                              void* d_out, int out_size, void* d_ws, size_t ws_size,
                              hipStream_t stream) {
  const float* q   = (const float*)d_in[0];
  const float* k   = (const float*)d_in[1];
  const float* v   = (const float*)d_in[2];
  const float* Wq  = (const float*)d_in[3];
  const float* Wk  = (const float*)d_in[4];
  const float* Wv  = (const float*)d_in[5];
  const float* Wfc = (const float*)d_in[6];
  const float* rel = (const float*)d_in[7];
  const float* gam = (const float*)d_in[8];
  const float* bet = (const float*)d_in[9];

  char* ws = (char*)d_ws;
  size_t off = 0;
  auto take = [&](size_t bytes) {
    char* p = ws + off;
    off += (bytes + 255) & ~(size_t)255;
    return p;
  };
  // NOTE: wqb/wkb/wvb contiguous, qb/kb/vb contiguous, Qhp/Khp/Vtp contiguous —
  // required by the z=3 projection launch (pure offset arithmetic).
  bf16_t* wqb  = (bf16_t*)take((size_t)Dm * Dm * 2);
  bf16_t* wkb  = (bf16_t*)take((size_t)Dm * Dm * 2);
  bf16_t* wvb  = (bf16_t*)take((size_t)Dm * Dm * 2);
  bf16_t* wfcb = (bf16_t*)take((size_t)Dm * Dm * 2);
  bf16_t* relb = (bf16_t*)take((size_t)NREL * DKd * 2);
  bf16_t* qb   = (bf16_t*)take((size_t)MTOK * Dm * 2);
  bf16_t* kb   = (bf16_t*)take((size_t)MTOK * Dm * 2);
  bf16_t* vb   = (bf16_t*)take((size_t)MTOK * Dm * 2);
  bf16_t* Qhp  = (bf16_t*)take((size_t)MTOK * Dm * 2);
  bf16_t* Khp  = (bf16_t*)take((size_t)MTOK * Dm * 2);
  bf16_t* Vtp  = (bf16_t*)take((size_t)MTOK * Dm * 2);
  bf16_t* attnb= (bf16_t*)take((size_t)MTOK * Dm * 2);
  bf16_t* yb   = (bf16_t*)take((size_t)MTOK * Dm * 2);

  // 1) ALL casts (q/k/v + 4 weights + rel) in one launch
  k_cast_all<<<dim3(2048, 4), 256, 0, stream>>>(
      q, k, v, Wq, Wk, Wv, Wfc, rel, qb, kb, vb, wqb, wkb, wvb, wfcb, relb);
  // 2) ALL projections (Q,K,V) in one z=3 launch (256x64 tile, prefetch)
  k_proj3<<<dim3(8, 32, 3), 256, 0, stream>>>(qb, wqb, Qhp);
  // 3) attention (posdot fused in-block; stable 84us)
  k_attn<<<dim3(2048), 256, 0, stream>>>(Qhp, Khp, Vtp, relb, attnb);
  // 4) output GEMM + residual (256x64 tile, bf16 yb)
  k_fc<<<dim3(8, 32), 256, 0, stream>>>(attnb, wfcb, yb, q);
  // 5) LayerNorm (bf16 input)
  k_ln<<<dim3(MTOK / 4), 256, 0, stream>>>(yb, gam, bet, (float*)d_out);
}